// Round 3
// baseline (9858.891 us; speedup 1.0000x reference)
//
#include <hip/hip_runtime.h>
#include <hip/hip_bf16.h>
#include <math.h>

typedef __hip_bfloat16 bf16;

#define W3J_TOTAL 3436
#define CH 8192   // edge chunk size for transient buffers

struct TripleT { int l1, l2, l3, off; };
constexpr TripleT TRS[34] = {
  {0,0,0,0},{0,1,1,1},{0,2,2,10},{0,3,3,35},
  {1,0,1,84},{1,1,0,93},{1,1,1,102},{1,1,2,129},{1,2,1,174},{1,2,2,219},
  {1,2,3,294},{1,3,2,399},{1,3,3,504},
  {2,0,2,651},{2,1,1,676},{2,1,2,721},{2,1,3,796},{2,2,0,901},{2,2,1,926},
  {2,2,2,1001},{2,2,3,1126},{2,3,1,1301},{2,3,2,1406},{2,3,3,1581},
  {3,0,3,1826},{3,1,2,1875},{3,1,3,1980},{3,2,1,2127},{3,2,2,2232},
  {3,2,3,2407},{3,3,0,2652},{3,3,1,2701},{3,3,2,2848},{3,3,3,3093}
};
__constant__ int TRI_dev[34][4] = {
  {0,0,0,0},{0,1,1,1},{0,2,2,10},{0,3,3,35},
  {1,0,1,84},{1,1,0,93},{1,1,1,102},{1,1,2,129},{1,2,1,174},{1,2,2,219},
  {1,2,3,294},{1,3,2,399},{1,3,3,504},
  {2,0,2,651},{2,1,1,676},{2,1,2,721},{2,1,3,796},{2,2,0,901},{2,2,1,926},
  {2,2,2,1001},{2,2,3,1126},{2,3,1,1301},{2,3,2,1406},{2,3,3,1581},
  {3,0,3,1826},{3,1,2,1875},{3,1,3,1980},{3,2,1,2127},{3,2,2,2232},
  {3,2,3,2407},{3,3,0,2652},{3,3,1,2701},{3,3,2,2848},{3,3,3,3093}
};
constexpr int LOFFC[4] = {0,1,4,9};
constexpr int LOFK[16] = {0,1,1,1,2,2,2,2,2,3,3,3,3,3,3,3};
constexpr float TNORMC[4] = {0.5f, 0.33333333333333333f, 0.30151134457776363f, 0.31622776601683794f};

// ---------------- conversion helpers ----------------
__device__ inline float toF(float x){ return x; }
__device__ inline float toF(bf16 x){ return __bfloat162float(x); }
__device__ inline void stC(float* p, float v){ *p = v; }
__device__ inline void stC(bf16* p, float v){ *p = __float2bfloat16(v); }

// ---------------- W3J (real CG) computed on device ----------------
struct cplx { double re, im; };
__device__ inline cplx cmul(cplx a, cplx b){ return {a.re*b.re - a.im*b.im, a.re*b.im + a.im*b.re}; }

__device__ double su2cg(int j1,int j2,int j3,int m1,int m2,int m3){
  if (m1+m2 != m3) return 0.0;
  const double F[11] = {1.,1.,2.,6.,24.,120.,720.,5040.,40320.,362880.,3628800.};
  double pref = sqrt((double)(2*j3+1) * F[j1+j2-j3]*F[j1-j2+j3]*F[-j1+j2+j3]/F[j1+j2+j3+1]
              * F[j3+m3]*F[j3-m3]*F[j1-m1]*F[j1+m1]*F[j2-m2]*F[j2+m2]);
  int kmin = max(0, max(j2-j3-m1, j1-j3+m2));
  int kmax = min(j1+j2-j3, min(j1-m1, j2+m2));
  double s = 0.0;
  for (int k=kmin;k<=kmax;k++){
    double t = 1.0/(F[k]*F[j1+j2-j3-k]*F[j1-m1-k]*F[j2+m2-k]*F[j3-j2+m1+k]*F[j3-j1-m2+k]);
    s += (k&1) ? -t : t;
  }
  return pref*s;
}

__device__ cplx qelem(int l, int i, int j){
  int m = i - l;
  const double is2 = 0.70710678118654752440;
  double re=0.0, im=0.0;
  if (m < 0){
    if (j == l - m) re = is2;
    else if (j == l + m) im = -is2;
  } else if (m == 0){
    if (j == l) re = 1.0;
  } else {
    double sgn = (m & 1) ? -1.0 : 1.0;
    if (j == l + m) re = sgn*is2;
    else if (j == l - m) im = sgn*is2;
  }
  cplx r;
  switch (l & 3){
    case 0: r = {re, im}; break;
    case 1: r = {im, -re}; break;
    case 2: r = {-re, -im}; break;
    default: r = {-im, re}; break;
  }
  return r;
}

__global__ __launch_bounds__(256) void w3j_kernel(float* __restrict__ w3j){
  const int tr = blockIdx.x;
  const int l1 = TRI_dev[tr][0], l2 = TRI_dev[tr][1], l3 = TRI_dev[tr][2], off = TRI_dev[tr][3];
  const int n1 = 2*l1+1, n2 = 2*l2+1, n3 = 2*l3+1;
  const int nel = n1*n2*n3;
  __shared__ double cg[343];
  __shared__ double cr[343];
  __shared__ double ciA[343];
  __shared__ double redr[256];
  __shared__ double redi[256];
  const int tid = threadIdx.x;
  for (int i=tid;i<nel;i+=256){
    int c = i % n3; int b = (i/n3) % n2; int a = i/(n3*n2);
    cg[i] = su2cg(l1,l2,l3, a-l1, b-l2, c-l3);
  }
  __syncthreads();
  for (int i=tid;i<nel;i+=256){
    int k = i % n3; int j = (i/n3) % n2; int ii = i/(n3*n2);
    double sre=0, sim=0;
    for (int a=0;a<n1;a++){
      cplx q1 = qelem(l1, ii, a);
      if (q1.re==0.0 && q1.im==0.0) continue;
      for (int b=0;b<n2;b++){
        cplx q2 = qelem(l2, j, b);
        if (q2.re==0.0 && q2.im==0.0) continue;
        cplx q12 = cmul(q1,q2);
        for (int c=0;c<n3;c++){
          double g = cg[(a*n2 + b)*n3 + c];
          if (g == 0.0) continue;
          cplx q3 = qelem(l3, k, c);
          q3.im = -q3.im;
          cplx q = cmul(q12, q3);
          sre += q.re*g; sim += q.im*g;
        }
      }
    }
    cr[i]=sre; ciA[i]=sim;
  }
  __syncthreads();
  double sr=0, si=0;
  for (int i=tid;i<nel;i+=256){ sr += cr[i]*cr[i]; si += ciA[i]*ciA[i]; }
  redr[tid]=sr; redi[tid]=si;
  __syncthreads();
  for (int o2=128;o2>0;o2>>=1){
    if (tid<o2){ redr[tid]+=redr[tid+o2]; redi[tid]+=redi[tid+o2]; }
    __syncthreads();
  }
  __shared__ double sscale; __shared__ int spick;
  if (tid==0){
    int pick = (redr[0] >= redi[0]) ? 0 : 1;
    double nn = sqrt(pick ? redi[0] : redr[0]);
    spick = pick; sscale = 1.0/nn;
  }
  __syncthreads();
  for (int i=tid;i<nel;i+=256)
    w3j[off+i] = (float)((spick ? ciA[i] : cr[i]) * sscale);
}

// ---------------- edge geometry: rb, Y, cut, feat40 (all fp32) ----------------
__global__ __launch_bounds__(256) void edge_init(
    const float* __restrict__ vec, const float* __restrict__ na,
    const int* __restrict__ snd, const int* __restrict__ rcv,
    float* __restrict__ feat, float* __restrict__ Y, float* __restrict__ cutb, int E)
{
  int e = blockIdx.x*256 + threadIdx.x;
  if (e >= E) return;
  float vx = vec[(size_t)e*3], vy = vec[(size_t)e*3+1], vz = vec[(size_t)e*3+2];
  float d = sqrtf(vx*vx + vy*vy + vz*vz);
  float inv = 1.f/(d + 1e-9f);
  float x = vx*inv, y = vy*inv, z = vz*inv;
  float dc = d * 0.4f;               // d / 2.5
  float dci = 1.f/(dc + 1e-9f);
  float* f = feat + (size_t)e*40;
  #pragma unroll
  for (int k=1;k<=8;k++)
    f[k-1] = 1.41421356237309515f * sinf(dc * 3.14159265358979323846f * k) * dci;
  int s = snd[e], r = rcv[e];
  #pragma unroll
  for (int i=0;i<16;i++) f[8+i]  = na[(size_t)s*16+i];
  #pragma unroll
  for (int i=0;i<16;i++) f[24+i] = na[(size_t)r*16+i];
  float cv = 0.f;
  if (dc < 1.f){
    float d2 = dc*dc; float d6 = d2*d2*d2; float d7 = d6*dc; float d8 = d7*dc;
    cv = 1.f - 28.f*d6 + 48.f*d7 - 21.f*d8;
  }
  cutb[e] = cv;
  float* Ye = Y + (size_t)e*16;
  const float s3=1.7320508075688772f, s5=2.2360679774997896f, s15=3.8729833462074170f;
  Ye[0] = 1.f;
  Ye[1] = s3*y; Ye[2] = s3*z; Ye[3] = s3*x;
  Ye[4] = s15*x*y; Ye[5] = s15*y*z; Ye[6] = 0.5f*s5*(3.f*z*z-1.f);
  Ye[7] = s15*x*z; Ye[8] = 0.5f*s15*(x*x - y*y);
  const float c1=2.0916500663351889f, c2=10.246950765959598f, c3=1.6201851746019649f, c4=1.3228756555322954f;
  Ye[9]  = c1*y*(3.f*x*x - y*y);
  Ye[10] = c2*x*y*z;
  Ye[11] = c3*y*(5.f*z*z - 1.f);
  Ye[12] = c4*z*(5.f*z*z - 3.f);
  Ye[13] = c3*x*(5.f*z*z - 1.f);
  Ye[14] = 0.5f*c2*z*(x*x - y*y);
  Ye[15] = c1*x*(x*x - 3.f*y*y);
}

// ---------------- generic tiled GEMM: C = act(scale * [A|A2] @ W) (*cut) --------
template<typename TA, typename TC, bool SILU, bool CUT>
__global__ __launch_bounds__(256) void gemm_t(
    const TA* __restrict__ A, int lda, int K1,
    const float* __restrict__ A2, int lda2, int a2s,
    const float* __restrict__ W, int ldw,
    TC* __restrict__ C, int ldc,
    const float* __restrict__ cutv,
    int N, int K, float scale)
{
  __shared__ float As[16][129];
  __shared__ float Ws[16][65];
  const int tid = threadIdx.x;
  const int row0 = blockIdx.x * 128;
  const int col0 = blockIdx.y * 64;
  const int ty = tid & 15;
  const int tx = tid >> 4;
  float acc[8][4] = {};
  for (int k0 = 0; k0 < K; k0 += 16) {
    #pragma unroll
    for (int i = 0; i < 8; i++) {        // A tile 128x16
      int idx = tid + i*256;
      int r = idx >> 4, kk = idx & 15;
      int k = k0 + kk;
      float v = 0.f;
      int grow = row0 + r;
      if (k < K1)      v = toF(A[(size_t)grow*lda + k]);
      else if (k < K)  v = A2[(size_t)grow*lda2 + (size_t)(k-K1)*a2s];
      As[kk][r] = v;
    }
    #pragma unroll
    for (int i = 0; i < 4; i++) {        // W tile 16x64
      int idx = tid + i*256;
      int kk = idx >> 6, c = idx & 63;
      int k = k0 + kk;
      float v = 0.f;
      if (k < K && (col0 + c) < N) v = W[(size_t)k*ldw + col0 + c];
      Ws[kk][c] = v;
    }
    __syncthreads();
    #pragma unroll
    for (int kk = 0; kk < 16; kk++) {
      float a[8], b[4];
      #pragma unroll
      for (int i=0;i<8;i++) a[i] = As[kk][ty + 16*i];
      #pragma unroll
      for (int j=0;j<4;j++) b[j] = Ws[kk][tx + 16*j];
      #pragma unroll
      for (int i=0;i<8;i++)
        #pragma unroll
        for (int j=0;j<4;j++) acc[i][j] += a[i]*b[j];
    }
    __syncthreads();
  }
  #pragma unroll
  for (int i=0;i<8;i++) {
    int r = row0 + ty + 16*i;
    float cm = CUT ? cutv[r] : 1.f;
    #pragma unroll
    for (int j=0;j<4;j++) {
      int c = col0 + tx + 16*j;
      if (c < N) {
        float v = acc[i][j] * scale;
        if (SILU) v = v / (1.f + __expf(-v));
        if (CUT)  v *= cm;
        stC(&C[(size_t)r*ldc + c], v);
      }
    }
  }
}

// ---------------- V init (chunk): V[e][m][kk] = wi[e][l(kk)*32+m] * Y[e][kk] ----
__global__ __launch_bounds__(256) void vbuild(
    const float* __restrict__ wi, const float* __restrict__ Y,
    bf16* __restrict__ V, int count)
{
  size_t t = (size_t)blockIdx.x*256 + threadIdx.x;
  if (t >= (size_t)count*512) return;
  int e = (int)(t >> 9); int j = (int)(t & 511);
  int m = j >> 4, kk = j & 15;
  int l = (kk>=9)?3:((kk>=4)?2:((kk>=1)?1:0));
  V[t] = __float2bfloat16(wi[(size_t)e*128 + l*32 + m] * Y[(size_t)e*16 + kk]);
}

// ---------------- zero fill ----------------
__global__ __launch_bounds__(256) void zerok(float* __restrict__ p, size_t n){
  size_t t = (size_t)blockIdx.x*256 + threadIdx.x;
  if (t < n) p[t] = 0.f;
}

// ---------------- segment_sum scatter: node_env[r][m][kk] += w[e][m]*Y[e][kk] ---
__global__ __launch_bounds__(256) void scatter_env(
    const float* __restrict__ w, const float* __restrict__ Y,
    const int* __restrict__ rcv, float* __restrict__ nenv, int E)
{
  size_t t = (size_t)blockIdx.x*256 + threadIdx.x;
  if (t >= (size_t)E*512) return;
  int e = (int)(t >> 9); int j = (int)(t & 511);
  int m = j >> 4, kk = j & 15;
  float val = w[(size_t)e*32 + m] * Y[(size_t)e*16 + kk];
  atomicAdd(&nenv[(size_t)rcv[e]*512 + j], val);
}

// ---------------- tensor product (chunk, fully unrolled CG contraction) ---------
// T (chunk-local, fp32), t0 (chunk-local slice of T[:,:,0], fp32)
__global__ __launch_bounds__(256) void tp_kernel(
    const float* __restrict__ nenv, const int* __restrict__ senders,
    const bf16* __restrict__ V, const float* __restrict__ w3j,
    float* __restrict__ T, float* __restrict__ t0, int count)
{
  __shared__ float w3s[W3J_TOTAL];
  for (int i = threadIdx.x; i < W3J_TOTAL; i += 256) w3s[i] = w3j[i];
  __syncthreads();
  int t = blockIdx.x*256 + threadIdx.x;
  int e = t >> 5, m = t & 31;
  if (e >= count) return;
  int s = senders[e];
  float env[16], v[16], acc[16];
  const float* ne = nenv + (size_t)s*512 + m*16;
  const bf16* ve = V + (size_t)t*16;
  #pragma unroll
  for (int k=0;k<16;k++) env[k] = ne[k] * 0.25f;   // 1/sqrt(AVG_NEIGH=16)
  #pragma unroll
  for (int k=0;k<16;k++) v[k] = __bfloat162float(ve[k]);
  #pragma unroll
  for (int k=0;k<16;k++) acc[k] = 0.f;
  #pragma unroll
  for (int tr=0; tr<34; ++tr) {
    const int l1 = TRS[tr].l1, l2 = TRS[tr].l2, l3 = TRS[tr].l3, o = TRS[tr].off;
    const int n1 = 2*l1+1, n2 = 2*l2+1, n3 = 2*l3+1;
    #pragma unroll
    for (int k1=0;k1<n1;k1++) {
      #pragma unroll
      for (int k2=0;k2<n2;k2++) {
        float p = env[LOFFC[l1]+k1] * v[LOFFC[l2]+k2];
        #pragma unroll
        for (int k3=0;k3<n3;k3++)
          acc[LOFFC[l3]+k3] += w3s[o + (k1*n2+k2)*n3 + k3] * p;
      }
    }
  }
  float* te = T + (size_t)t*16;
  #pragma unroll
  for (int k=0;k<16;k++) te[k] = acc[k] * TNORMC[LOFK[k]];
  t0[(size_t)e*32 + m] = acc[0] * TNORMC[0];
}

// ---- V mix (chunk): V'[e][n][kk] = (1/sqrt(32)) sum_m T[e][m][kk]*wm[l][m][n] --
__global__ __launch_bounds__(256) void mixk(
    const float* __restrict__ T, const float* __restrict__ wm,
    bf16* __restrict__ V, int count)
{
  size_t t = (size_t)blockIdx.x*256 + threadIdx.x;
  if (t >= (size_t)count*512) return;
  int e = (int)(t >> 9); int j = (int)(t & 511);
  int n = j >> 4, kk = j & 15;
  int l = (kk>=9)?3:((kk>=4)?2:((kk>=1)?1:0));
  const float* tb = T + (size_t)e*512 + kk;
  const float* wb = wm + l*1024 + n;
  float s = 0.f;
  #pragma unroll
  for (int m=0;m<32;m++) s += tb[m*16] * wb[m*32];
  V[t] = __float2bfloat16(s * 0.17677669529663689f);   // 1/sqrt(32)
}

// ---------------- output: out[e] = (1/sqrt(512)) * dot(x[e], wout) --------------
template<typename TX>
__global__ __launch_bounds__(256) void out_kernel(
    const TX* __restrict__ x, const float* __restrict__ wout,
    float* __restrict__ out, int E)
{
  int gw = (blockIdx.x*256 + threadIdx.x) >> 6;
  int lane = threadIdx.x & 63;
  if (gw >= E) return;
  float s = 0.f;
  const TX* xr = x + (size_t)gw*512;
  #pragma unroll
  for (int k=lane; k<512; k+=64) s += toF(xr[k])*wout[k];
  #pragma unroll
  for (int off=32; off; off>>=1) s += __shfl_down(s, off);
  if (lane == 0) out[gw] = s * 0.044194173824159216f; // 1/sqrt(512)
}

// ---------------- workspace sizing ----------------
static inline size_t alup(size_t b){ return (b + 255) & ~(size_t)255; }
static size_t need_bytes(int E, int N, size_t txs){
  size_t s = 0;
  s += alup(4096*4);                    // w3j
  s += alup((size_t)E*16*4);            // Yb
  s += alup((size_t)E*4);               // cutb
  s += alup((size_t)E*32*4);            // wbuf
  s += alup((size_t)E*32*4);            // t0b
  s += alup((size_t)N*512*4);           // nenv
  s += alup((size_t)E*40*4);            // feat
  s += alup((size_t)CH*512*4);          // chunk buffer
  s += alup((size_t)E*512*2);           // Vb (bf16)
  s += alup((size_t)E*512*txs);         // xb
  return s;
}

// ---------------- full pipeline, templated on latent storage dtype --------------
template<typename TX>
static void run_all(const float* node_attrs, const float* vectors, const float* we0,
                    const float* we1, const float* winit, const float* wenv,
                    const float* wlat0, const float* wlat1, const float* wmix,
                    const float* wout, const int* senders, const int* receivers,
                    float* out, int E, int N, char* base, hipStream_t stream)
{
  size_t off = 0;
  auto carve = [&](size_t b) -> char* { char* p = base + off; off += alup(b); return p; };
  float* w3j  = (float*)carve(4096*4);
  float* Yb   = (float*)carve((size_t)E*16*4);
  float* cutb = (float*)carve((size_t)E*4);
  float* wbuf = (float*)carve((size_t)E*32*4);
  float* t0b  = (float*)carve((size_t)E*32*4);
  float* nenv = (float*)carve((size_t)N*512*4);
  float* feat = (float*)carve((size_t)E*40*4);
  float* cbuf = (float*)carve((size_t)CH*512*4);   // shared: h / T / wi per chunk
  bf16*  Vb   = (bf16*) carve((size_t)E*512*2);
  TX*    xb   = (TX*)   carve((size_t)E*512*sizeof(TX));

  const float rs40  = 0.15811388300841897f;  // 1/sqrt(40)
  const float rs512 = 0.044194173824159216f; // 1/sqrt(512)
  const float rs544 = 0.042874646285627205f; // 1/sqrt(544)

  dim3 blk(256);
  w3j_kernel<<<34, blk, 0, stream>>>(w3j);
  edge_init<<<E/256, blk, 0, stream>>>(vectors, node_attrs, senders, receivers, feat, Yb, cutb, E);

  // edge embedding MLP + V init, chunked (h and wi live only in cbuf)
  for (int c0 = 0; c0 < E; c0 += CH) {
    gemm_t<float,float,true,false><<<dim3(CH/128, 8), blk, 0, stream>>>(
        feat + (size_t)c0*40, 40, 40, nullptr, 0, 0, we0, 512, cbuf, 512, nullptr, 512, 40, rs40);
    gemm_t<float,TX,false,true><<<dim3(CH/128, 8), blk, 0, stream>>>(
        cbuf, 512, 512, nullptr, 0, 0, we1, 512, xb + (size_t)c0*512, 512, cutb + c0, 512, 512, rs512);
    gemm_t<TX,float,false,false><<<dim3(CH/128, 2), blk, 0, stream>>>(
        xb + (size_t)c0*512, 512, 512, nullptr, 0, 0, winit, 128, cbuf, 128, nullptr, 128, 512, rs512);
    vbuild<<<(CH*512)/256, blk, 0, stream>>>(cbuf, Yb + (size_t)c0*16, Vb + (size_t)c0*512, CH);
  }

  for (int layer = 0; layer < 2; ++layer) {
    const float* wenv_l  = wenv  + (size_t)layer*512*32;
    const float* wlat0_l = wlat0 + (size_t)layer*544*512;
    const float* wlat1_l = wlat1 + (size_t)layer*512*512;
    const float* wmix_l  = wmix  + (size_t)layer*4*32*32;

    gemm_t<TX,float,false,false><<<dim3(E/128, 1), blk, 0, stream>>>(
        xb, 512, 512, nullptr, 0, 0, wenv_l, 32, wbuf, 32, nullptr, 32, 512, rs512);
    zerok<<<(int)(((size_t)N*512)/256), blk, 0, stream>>>(nenv, (size_t)N*512);
    scatter_env<<<(int)(((size_t)E*512)/256), blk, 0, stream>>>(wbuf, Yb, receivers, nenv, E);

    for (int c0 = 0; c0 < E; c0 += CH) {
      // T (into cbuf) + t0 slice
      tp_kernel<<<(CH*32)/256, blk, 0, stream>>>(
          nenv, senders + c0, Vb + (size_t)c0*512, w3j, cbuf, t0b + (size_t)c0*32, CH);
      // V' = T @ wmix (skip on last layer: V is dead afterwards)
      if (layer + 1 < 2)
        mixk<<<(CH*512)/256, blk, 0, stream>>>(cbuf, wmix_l, Vb + (size_t)c0*512, CH);
      // latent MLP: [x | t0](544) -> h(512, into cbuf) silu -> x(512) * cut
      gemm_t<TX,float,true,false><<<dim3(CH/128, 8), blk, 0, stream>>>(
          xb + (size_t)c0*512, 512, 512, t0b + (size_t)c0*32, 32, 1,
          wlat0_l, 512, cbuf, 512, nullptr, 512, 544, rs544);
      gemm_t<float,TX,false,true><<<dim3(CH/128, 8), blk, 0, stream>>>(
          cbuf, 512, 512, nullptr, 0, 0, wlat1_l, 512, xb + (size_t)c0*512, 512,
          cutb + c0, 512, 512, rs512);
    }
  }

  out_kernel<TX><<<E/4, blk, 0, stream>>>(xb, wout, out, E);
}

// ---------------- launch ----------------
extern "C" void kernel_launch(void* const* d_in, const int* in_sizes, int n_in,
                              void* d_out, int out_size, void* d_ws, size_t ws_size,
                              hipStream_t stream)
{
  const float* node_attrs = (const float*)d_in[0];
  const float* vectors    = (const float*)d_in[1];
  const float* we0        = (const float*)d_in[2];
  const float* we1        = (const float*)d_in[3];
  const float* winit      = (const float*)d_in[4];
  const float* wenv       = (const float*)d_in[5];
  const float* wlat0      = (const float*)d_in[6];
  const float* wlat1      = (const float*)d_in[7];
  const float* wmix       = (const float*)d_in[8];
  const float* wout       = (const float*)d_in[9];
  const int*   senders    = (const int*)d_in[10];
  const int*   receivers  = (const int*)d_in[11];
  float* out = (float*)d_out;
  const int E = in_sizes[1] / 3;
  const int N = in_sizes[0] / 16;

  // Tier selection on actual ws_size (host-side, deterministic, graph-safe):
  if (need_bytes(E, N, sizeof(float)) <= ws_size) {
    run_all<float>(node_attrs, vectors, we0, we1, winit, wenv, wlat0, wlat1, wmix,
                   wout, senders, receivers, out, E, N, (char*)d_ws, stream);
  } else if (need_bytes(E, N, sizeof(bf16)) <= ws_size) {
    run_all<bf16>(node_attrs, vectors, we0, we1, winit, wenv, wlat0, wlat1, wmix,
                  wout, senders, receivers, out, E, N, (char*)d_ws, stream);
  }
  // else: ws too small for any tier -> clean no-op (diagnostic zeros)
}

// Round 4
// 3215.932 us; speedup vs baseline: 3.0656x; 3.0656x over previous
//
#include <hip/hip_runtime.h>
#include <math.h>

typedef __attribute__((ext_vector_type(8))) short s8v;   // 8 bf16 (4 VGPR)
typedef __attribute__((ext_vector_type(4))) float f4v;   // MFMA acc

#define W3J_TOTAL 3436
#define CH 8192

struct TripleT { int l1, l2, l3, off; };
constexpr TripleT TRS[34] = {
  {0,0,0,0},{0,1,1,1},{0,2,2,10},{0,3,3,35},
  {1,0,1,84},{1,1,0,93},{1,1,1,102},{1,1,2,129},{1,2,1,174},{1,2,2,219},
  {1,2,3,294},{1,3,2,399},{1,3,3,504},
  {2,0,2,651},{2,1,1,676},{2,1,2,721},{2,1,3,796},{2,2,0,901},{2,2,1,926},
  {2,2,2,1001},{2,2,3,1126},{2,3,1,1301},{2,3,2,1406},{2,3,3,1581},
  {3,0,3,1826},{3,1,2,1875},{3,1,3,1980},{3,2,1,2127},{3,2,2,2232},
  {3,2,3,2407},{3,3,0,2652},{3,3,1,2701},{3,3,2,2848},{3,3,3,3093}
};
__constant__ int TRI_dev[34][4] = {
  {0,0,0,0},{0,1,1,1},{0,2,2,10},{0,3,3,35},
  {1,0,1,84},{1,1,0,93},{1,1,1,102},{1,1,2,129},{1,2,1,174},{1,2,2,219},
  {1,2,3,294},{1,3,2,399},{1,3,3,504},
  {2,0,2,651},{2,1,1,676},{2,1,2,721},{2,1,3,796},{2,2,0,901},{2,2,1,926},
  {2,2,2,1001},{2,2,3,1126},{2,3,1,1301},{2,3,2,1406},{2,3,3,1581},
  {3,0,3,1826},{3,1,2,1875},{3,1,3,1980},{3,2,1,2127},{3,2,2,2232},
  {3,2,3,2407},{3,3,0,2652},{3,3,1,2701},{3,3,2,2848},{3,3,3,3093}
};
constexpr int LOFFC[4] = {0,1,4,9};
constexpr int LOFK[16] = {0,1,1,1,2,2,2,2,2,3,3,3,3,3,3,3};
constexpr float TNORMC[4] = {0.5f, 0.33333333333333333f, 0.30151134457776363f, 0.31622776601683794f};

// ---------------- bf16 bit helpers ----------------
__device__ inline float b2f(unsigned short u){ return __uint_as_float(((unsigned)u)<<16); }
__device__ inline unsigned short f2b(float f){
  unsigned u = __float_as_uint(f);
  return (unsigned short)((u + 0x7FFFu + ((u>>16)&1u)) >> 16);   // RNE
}
__device__ inline void stC(float* p, float v){ *p = v; }
__device__ inline void stC(unsigned short* p, float v){ *p = f2b(v); }

// ---------------- W3J (real CG) computed on device ----------------
struct cplx { double re, im; };
__device__ inline cplx cmul(cplx a, cplx b){ return {a.re*b.re - a.im*b.im, a.re*b.im + a.im*b.re}; }

__device__ double su2cg(int j1,int j2,int j3,int m1,int m2,int m3){
  if (m1+m2 != m3) return 0.0;
  const double F[11] = {1.,1.,2.,6.,24.,120.,720.,5040.,40320.,362880.,3628800.};
  double pref = sqrt((double)(2*j3+1) * F[j1+j2-j3]*F[j1-j2+j3]*F[-j1+j2+j3]/F[j1+j2+j3+1]
              * F[j3+m3]*F[j3-m3]*F[j1-m1]*F[j1+m1]*F[j2-m2]*F[j2+m2]);
  int kmin = max(0, max(j2-j3-m1, j1-j3+m2));
  int kmax = min(j1+j2-j3, min(j1-m1, j2+m2));
  double s = 0.0;
  for (int k=kmin;k<=kmax;k++){
    double t = 1.0/(F[k]*F[j1+j2-j3-k]*F[j1-m1-k]*F[j2+m2-k]*F[j3-j2+m1+k]*F[j3-j1-m2+k]);
    s += (k&1) ? -t : t;
  }
  return pref*s;
}

__device__ cplx qelem(int l, int i, int j){
  int m = i - l;
  const double is2 = 0.70710678118654752440;
  double re=0.0, im=0.0;
  if (m < 0){
    if (j == l - m) re = is2;
    else if (j == l + m) im = -is2;
  } else if (m == 0){
    if (j == l) re = 1.0;
  } else {
    double sgn = (m & 1) ? -1.0 : 1.0;
    if (j == l + m) re = sgn*is2;
    else if (j == l - m) im = sgn*is2;
  }
  cplx r;
  switch (l & 3){
    case 0: r = {re, im}; break;
    case 1: r = {im, -re}; break;
    case 2: r = {-re, -im}; break;
    default: r = {-im, re}; break;
  }
  return r;
}

__global__ __launch_bounds__(256) void w3j_kernel(float* __restrict__ w3j){
  const int tr = blockIdx.x;
  const int l1 = TRI_dev[tr][0], l2 = TRI_dev[tr][1], l3 = TRI_dev[tr][2], off = TRI_dev[tr][3];
  const int n1 = 2*l1+1, n2 = 2*l2+1, n3 = 2*l3+1;
  const int nel = n1*n2*n3;
  __shared__ double cg[343];
  __shared__ double cr[343];
  __shared__ double ciA[343];
  __shared__ double redr[256];
  __shared__ double redi[256];
  const int tid = threadIdx.x;
  for (int i=tid;i<nel;i+=256){
    int c = i % n3; int b = (i/n3) % n2; int a = i/(n3*n2);
    cg[i] = su2cg(l1,l2,l3, a-l1, b-l2, c-l3);
  }
  __syncthreads();
  for (int i=tid;i<nel;i+=256){
    int k = i % n3; int j = (i/n3) % n2; int ii = i/(n3*n2);
    double sre=0, sim=0;
    for (int a=0;a<n1;a++){
      cplx q1 = qelem(l1, ii, a);
      if (q1.re==0.0 && q1.im==0.0) continue;
      for (int b=0;b<n2;b++){
        cplx q2 = qelem(l2, j, b);
        if (q2.re==0.0 && q2.im==0.0) continue;
        cplx q12 = cmul(q1,q2);
        for (int c=0;c<n3;c++){
          double g = cg[(a*n2 + b)*n3 + c];
          if (g == 0.0) continue;
          cplx q3 = qelem(l3, k, c);
          q3.im = -q3.im;
          cplx q = cmul(q12, q3);
          sre += q.re*g; sim += q.im*g;
        }
      }
    }
    cr[i]=sre; ciA[i]=sim;
  }
  __syncthreads();
  double sr=0, si=0;
  for (int i=tid;i<nel;i+=256){ sr += cr[i]*cr[i]; si += ciA[i]*ciA[i]; }
  redr[tid]=sr; redi[tid]=si;
  __syncthreads();
  for (int o2=128;o2>0;o2>>=1){
    if (tid<o2){ redr[tid]+=redr[tid+o2]; redi[tid]+=redi[tid+o2]; }
    __syncthreads();
  }
  __shared__ double sscale; __shared__ int spick;
  if (tid==0){
    int pick = (redr[0] >= redi[0]) ? 0 : 1;
    double nn = sqrt(pick ? redi[0] : redr[0]);
    spick = pick; sscale = 1.0/nn;
  }
  __syncthreads();
  for (int i=tid;i<nel;i+=256)
    w3j[off+i] = (float)((spick ? ciA[i] : cr[i]) * sscale);
}

// ---------------- weight convert+transpose: WT[n][k] = bf16(W[k][n]) ----------
__global__ __launch_bounds__(256) void wconv(
    const float* __restrict__ W, unsigned short* __restrict__ WT,
    int K, int N, int Kpad)
{
  int idx = blockIdx.x*256 + threadIdx.x;
  if (idx >= N*Kpad) return;
  int n = idx / Kpad, k = idx - n*Kpad;
  WT[idx] = (k < K) ? f2b(W[(size_t)k*N + n]) : (unsigned short)0;
}

// ---------------- edge geometry: feat48(bf16, zero-padded), Y, cut -------------
__global__ __launch_bounds__(256) void edge_init(
    const float* __restrict__ vec, const float* __restrict__ na,
    const int* __restrict__ snd, const int* __restrict__ rcv,
    unsigned short* __restrict__ feat, float* __restrict__ Y, float* __restrict__ cutb, int E)
{
  int e = blockIdx.x*256 + threadIdx.x;
  if (e >= E) return;
  float vx = vec[(size_t)e*3], vy = vec[(size_t)e*3+1], vz = vec[(size_t)e*3+2];
  float d = sqrtf(vx*vx + vy*vy + vz*vz);
  float inv = 1.f/(d + 1e-9f);
  float x = vx*inv, y = vy*inv, z = vz*inv;
  float dc = d * 0.4f;               // d / 2.5
  float dci = 1.f/(dc + 1e-9f);
  unsigned short* f = feat + (size_t)e*48;
  #pragma unroll
  for (int k=1;k<=8;k++)
    f[k-1] = f2b(1.41421356237309515f * sinf(dc * 3.14159265358979323846f * k) * dci);
  int s = snd[e], r = rcv[e];
  #pragma unroll
  for (int i=0;i<16;i++) f[8+i]  = f2b(na[(size_t)s*16+i]);
  #pragma unroll
  for (int i=0;i<16;i++) f[24+i] = f2b(na[(size_t)r*16+i]);
  #pragma unroll
  for (int i=40;i<48;i++) f[i] = 0;
  float cv = 0.f;
  if (dc < 1.f){
    float d2 = dc*dc; float d6 = d2*d2*d2; float d7 = d6*dc; float d8 = d7*dc;
    cv = 1.f - 28.f*d6 + 48.f*d7 - 21.f*d8;
  }
  cutb[e] = cv;
  float* Ye = Y + (size_t)e*16;
  const float s3=1.7320508075688772f, s5=2.2360679774997896f, s15=3.8729833462074170f;
  Ye[0] = 1.f;
  Ye[1] = s3*y; Ye[2] = s3*z; Ye[3] = s3*x;
  Ye[4] = s15*x*y; Ye[5] = s15*y*z; Ye[6] = 0.5f*s5*(3.f*z*z-1.f);
  Ye[7] = s15*x*z; Ye[8] = 0.5f*s15*(x*x - y*y);
  const float c1=2.0916500663351889f, c2=10.246950765959598f, c3=1.6201851746019649f, c4=1.3228756555322954f;
  Ye[9]  = c1*y*(3.f*x*x - y*y);
  Ye[10] = c2*x*y*z;
  Ye[11] = c3*y*(5.f*z*z - 1.f);
  Ye[12] = c4*z*(5.f*z*z - 3.f);
  Ye[13] = c3*x*(5.f*z*z - 1.f);
  Ye[14] = 0.5f*c2*z*(x*x - y*y);
  Ye[15] = c1*x*(x*x - 3.f*y*y);
}

// ---------------- MFMA bf16 GEMM: C = act(scale*[A|A2]@W) (*cut) ---------------
// A: M x lda (bf16), first K1 cols logical; A2: fp32 tail (concat), cols K1..K-1.
// WT: N x ldw (bf16) = W transposed. Tiles: 128 rows x 64 cols, BK=64, 4 waves.
template<typename TC, bool SILU, bool CUT, bool HASA2>
__global__ __launch_bounds__(256) void gemm_mfma(
    const unsigned short* __restrict__ A, int lda, int K1,
    const float* __restrict__ A2, int lda2,
    const unsigned short* __restrict__ WT, int ldw,
    TC* __restrict__ C, int ldc,
    const float* __restrict__ cutv,
    int N, int K, float scale)
{
  __shared__ s8v As8[128*9];   // 128 rows, pitch 9 x (8 bf16)
  __shared__ s8v Bs8[64*9];
  const int tid = threadIdx.x;
  const int wid = tid >> 6, lane = tid & 63;
  const int r15 = lane & 15, kg = lane >> 4;
  const int col0 = blockIdx.x * 64;
  const int row0 = blockIdx.y * 128;
  f4v acc[2][4] = {};
  for (int k0 = 0; k0 < K; k0 += 64) {
    #pragma unroll
    for (int i = 0; i < 4; i++) {              // A tile: 1024 segs of 8 bf16
      int seg = tid + i*256;
      int r = seg >> 3, ks = seg & 7;
      int k = k0 + ks*8;
      s8v val = {};
      if (k + 8 <= K1) {
        val = *(const s8v*)(A + (size_t)(row0+r)*lda + k);
      } else if (HASA2 && k >= K1 && k + 8 <= K) {
        const float* s2 = A2 + (size_t)(row0+r)*lda2 + (k - K1);
        #pragma unroll
        for (int j=0;j<8;j++) val[j] = (short)f2b(s2[j]);
      }
      As8[r*9 + ks] = val;
    }
    #pragma unroll
    for (int i = 0; i < 2; i++) {              // B tile: 512 segs
      int seg = tid + i*256;
      int n = seg >> 3, ks = seg & 7;
      int k = k0 + ks*8;
      s8v val = {};
      if (col0 + n < N && k + 8 <= K)
        val = *(const s8v*)(WT + (size_t)(col0+n)*ldw + k);
      Bs8[n*9 + ks] = val;
    }
    __syncthreads();
    #pragma unroll
    for (int s = 0; s < 2; s++) {
      s8v a0 = As8[(wid*32      + r15)*9 + s*4 + kg];
      s8v a1 = As8[(wid*32 + 16 + r15)*9 + s*4 + kg];
      s8v b0 = Bs8[(      r15)*9 + s*4 + kg];
      s8v b1 = Bs8[(16  + r15)*9 + s*4 + kg];
      s8v b2 = Bs8[(32  + r15)*9 + s*4 + kg];
      s8v b3 = Bs8[(48  + r15)*9 + s*4 + kg];
      acc[0][0] = __builtin_amdgcn_mfma_f32_16x16x32_bf16(a0, b0, acc[0][0], 0,0,0);
      acc[0][1] = __builtin_amdgcn_mfma_f32_16x16x32_bf16(a0, b1, acc[0][1], 0,0,0);
      acc[0][2] = __builtin_amdgcn_mfma_f32_16x16x32_bf16(a0, b2, acc[0][2], 0,0,0);
      acc[0][3] = __builtin_amdgcn_mfma_f32_16x16x32_bf16(a0, b3, acc[0][3], 0,0,0);
      acc[1][0] = __builtin_amdgcn_mfma_f32_16x16x32_bf16(a1, b0, acc[1][0], 0,0,0);
      acc[1][1] = __builtin_amdgcn_mfma_f32_16x16x32_bf16(a1, b1, acc[1][1], 0,0,0);
      acc[1][2] = __builtin_amdgcn_mfma_f32_16x16x32_bf16(a1, b2, acc[1][2], 0,0,0);
      acc[1][3] = __builtin_amdgcn_mfma_f32_16x16x32_bf16(a1, b3, acc[1][3], 0,0,0);
    }
    __syncthreads();
  }
  // epilogue: C/D layout col = lane&15, row = (lane>>4)*4 + j
  #pragma unroll
  for (int g=0; g<2; g++) {
    #pragma unroll
    for (int c=0; c<4; c++) {
      int col = col0 + c*16 + r15;
      if (col >= N) continue;
      #pragma unroll
      for (int j=0;j<4;j++) {
        int row = row0 + wid*32 + g*16 + kg*4 + j;
        float v = acc[g][c][j] * scale;
        if (SILU) v = v / (1.f + __expf(-v));
        if (CUT)  v *= cutv[row];
        stC(&C[(size_t)row*ldc + col], v);
      }
    }
  }
}

// ---------------- V init (chunk): V[e][m][kk] = wi[e][l(kk)*32+m] * Y[e][kk] ----
__global__ __launch_bounds__(256) void vbuild(
    const unsigned short* __restrict__ wi, const float* __restrict__ Y,
    unsigned short* __restrict__ V, int count)
{
  size_t t = (size_t)blockIdx.x*256 + threadIdx.x;
  if (t >= (size_t)count*512) return;
  int e = (int)(t >> 9); int j = (int)(t & 511);
  int m = j >> 4, kk = j & 15;
  int l = (kk>=9)?3:((kk>=4)?2:((kk>=1)?1:0));
  V[t] = f2b(b2f(wi[(size_t)e*128 + l*32 + m]) * Y[(size_t)e*16 + kk]);
}

// ---------------- zero fill ----------------
__global__ __launch_bounds__(256) void zerok(float* __restrict__ p, size_t n){
  size_t t = (size_t)blockIdx.x*256 + threadIdx.x;
  if (t < n) p[t] = 0.f;
}

// ---------------- segment_sum scatter ----------------
__global__ __launch_bounds__(256) void scatter_env(
    const float* __restrict__ w, const float* __restrict__ Y,
    const int* __restrict__ rcv, float* __restrict__ nenv, int E)
{
  size_t t = (size_t)blockIdx.x*256 + threadIdx.x;
  if (t >= (size_t)E*512) return;
  int e = (int)(t >> 9); int j = (int)(t & 511);
  int m = j >> 4, kk = j & 15;
  float val = w[(size_t)e*32 + m] * Y[(size_t)e*16 + kk];
  atomicAdd(&nenv[(size_t)rcv[e]*512 + j], val);
}

// ------------ fused tensor product + V-mix (T never hits global) ---------------
// 8 edges/block, thread (le,m). Writes t0 slice; if MIX, overwrites V in place.
template<bool MIX>
__global__ __launch_bounds__(256) void tp_mix(
    const float* __restrict__ nenv, const int* __restrict__ senders,
    unsigned short* __restrict__ V, const float* __restrict__ w3j,
    const float* __restrict__ wm,     // layer slice: [4][32][32]
    float* __restrict__ t0, int E)
{
  __shared__ float w3s[W3J_TOTAL];
  __shared__ float Ts[8][32][17];
  const int tid = threadIdx.x;
  for (int i = tid; i < W3J_TOTAL; i += 256) w3s[i] = w3j[i];
  const int le = tid >> 5, m = tid & 31;
  const int e = blockIdx.x*8 + le;
  const int s = senders[e];
  float env[16], v[16], acc[16];
  const float4* ne4 = (const float4*)(nenv + (size_t)s*512 + (size_t)m*16);
  #pragma unroll
  for (int q=0;q<4;q++){
    float4 f = ne4[q];
    env[q*4]=f.x*0.25f; env[q*4+1]=f.y*0.25f; env[q*4+2]=f.z*0.25f; env[q*4+3]=f.w*0.25f;
  }
  const s8v* vv = (const s8v*)(V + (size_t)e*512 + (size_t)m*16);
  s8v v0 = vv[0], v1 = vv[1];
  #pragma unroll
  for (int q=0;q<8;q++){ v[q] = b2f((unsigned short)v0[q]); v[8+q] = b2f((unsigned short)v1[q]); }
  #pragma unroll
  for (int k=0;k<16;k++) acc[k] = 0.f;
  __syncthreads();                     // w3s ready
  #pragma unroll
  for (int tr=0; tr<34; ++tr) {
    const int l1 = TRS[tr].l1, l2 = TRS[tr].l2, l3 = TRS[tr].l3, o = TRS[tr].off;
    const int n1 = 2*l1+1, n2 = 2*l2+1, n3 = 2*l3+1;
    #pragma unroll
    for (int k1=0;k1<n1;k1++) {
      #pragma unroll
      for (int k2=0;k2<n2;k2++) {
        float p = env[LOFFC[l1]+k1] * v[LOFFC[l2]+k2];
        #pragma unroll
        for (int k3=0;k3<n3;k3++)
          acc[LOFFC[l3]+k3] += w3s[o + (k1*n2+k2)*n3 + k3] * p;
      }
    }
  }
  t0[(size_t)e*32 + m] = acc[0] * 0.5f;
  #pragma unroll
  for (int k=0;k<16;k++) Ts[le][m][k] = acc[k] * TNORMC[LOFK[k]];
  if (MIX) {
    __syncthreads();                   // Ts ready
    float o16[16];
    #pragma unroll
    for (int k=0;k<16;k++) o16[k] = 0.f;
    #pragma unroll
    for (int mm=0; mm<32; mm++) {
      float w0 = wm[        mm*32 + m];
      float w1 = wm[1024 +  mm*32 + m];
      float w2 = wm[2048 +  mm*32 + m];
      float w3 = wm[3072 +  mm*32 + m];
      float wsel[4] = {w0,w1,w2,w3};
      #pragma unroll
      for (int k=0;k<16;k++) o16[k] += Ts[le][mm][k] * wsel[LOFK[k]];
    }
    unsigned short* vo = V + (size_t)e*512 + (size_t)m*16;
    #pragma unroll
    for (int k=0;k<16;k++) vo[k] = f2b(o16[k] * 0.17677669529663689f); // 1/sqrt(32)
  }
}

// ---------------- output: out[e] = (1/sqrt(512)) * dot(x[e], wout) --------------
__global__ __launch_bounds__(256) void out_kernel(
    const unsigned short* __restrict__ x, const float* __restrict__ wout,
    float* __restrict__ out, int E)
{
  int gw = (blockIdx.x*256 + threadIdx.x) >> 6;
  int lane = threadIdx.x & 63;
  if (gw >= E) return;
  const s8v* xr = (const s8v*)(x + (size_t)gw*512);
  s8v chunk = xr[lane];
  float s = 0.f;
  #pragma unroll
  for (int j=0;j<8;j++) s += b2f((unsigned short)chunk[j]) * wout[lane*8 + j];
  #pragma unroll
  for (int off=32; off; off>>=1) s += __shfl_down(s, off);
  if (lane == 0) out[gw] = s * 0.044194173824159216f; // 1/sqrt(512)
}

// ---------------- workspace sizing ----------------
static inline size_t alup(size_t b){ return (b + 255) & ~(size_t)255; }
static size_t need_bytes(int E, int N){
  size_t s = 0;
  s += alup((size_t)W3J_TOTAL*4);       // w3j
  s += alup((size_t)E*16*4);            // Yb
  s += alup((size_t)E*4);               // cutb
  s += alup((size_t)E*32*4);            // wbuf
  s += alup((size_t)E*32*4);            // t0b
  s += alup((size_t)N*512*4);           // nenv
  s += alup((size_t)E*48*2);            // feat (bf16, padded to 48)
  s += alup((size_t)CH*512*2);          // cbuf (bf16 chunk transient)
  s += alup((size_t)E*512*2);           // Vb
  s += alup((size_t)E*512*2);           // xb
  s += alup((size_t)512*48*2);          // we0T
  s += alup((size_t)512*512*2);         // we1T
  s += alup((size_t)128*512*2);         // winitT
  s += alup((size_t)2*32*512*2);        // wenvT x2
  s += alup((size_t)2*512*544*2);       // wlat0T x2
  s += alup((size_t)2*512*512*2);       // wlat1T x2
  return s;
}

// ---------------- launch ----------------
extern "C" void kernel_launch(void* const* d_in, const int* in_sizes, int n_in,
                              void* d_out, int out_size, void* d_ws, size_t ws_size,
                              hipStream_t stream)
{
  const float* node_attrs = (const float*)d_in[0];
  const float* vectors    = (const float*)d_in[1];
  const float* we0        = (const float*)d_in[2];
  const float* we1        = (const float*)d_in[3];
  const float* winit      = (const float*)d_in[4];
  const float* wenv       = (const float*)d_in[5];
  const float* wlat0      = (const float*)d_in[6];
  const float* wlat1      = (const float*)d_in[7];
  const float* wmix       = (const float*)d_in[8];
  const float* wout       = (const float*)d_in[9];
  const int*   senders    = (const int*)d_in[10];
  const int*   receivers  = (const int*)d_in[11];
  float* out = (float*)d_out;
  const int E = in_sizes[1] / 3;
  const int N = in_sizes[0] / 16;

  if (need_bytes(E, N) > ws_size) return;   // diagnostic clean fail

  char* base = (char*)d_ws;
  size_t off = 0;
  auto carve = [&](size_t b) -> char* { char* p = base + off; off += alup(b); return p; };
  float*          w3j   = (float*)carve((size_t)W3J_TOTAL*4);
  float*          Yb    = (float*)carve((size_t)E*16*4);
  float*          cutb  = (float*)carve((size_t)E*4);
  float*          wbuf  = (float*)carve((size_t)E*32*4);
  float*          t0b   = (float*)carve((size_t)E*32*4);
  float*          nenv  = (float*)carve((size_t)N*512*4);
  unsigned short* feat  = (unsigned short*)carve((size_t)E*48*2);
  unsigned short* cbuf  = (unsigned short*)carve((size_t)CH*512*2);
  unsigned short* Vb    = (unsigned short*)carve((size_t)E*512*2);
  unsigned short* xb    = (unsigned short*)carve((size_t)E*512*2);
  unsigned short* we0T  = (unsigned short*)carve((size_t)512*48*2);
  unsigned short* we1T  = (unsigned short*)carve((size_t)512*512*2);
  unsigned short* winT  = (unsigned short*)carve((size_t)128*512*2);
  unsigned short* wenvT = (unsigned short*)carve((size_t)2*32*512*2);
  unsigned short* wl0T  = (unsigned short*)carve((size_t)2*512*544*2);
  unsigned short* wl1T  = (unsigned short*)carve((size_t)2*512*512*2);

  const float rs40  = 0.15811388300841897f;  // 1/sqrt(40)
  const float rs512 = 0.044194173824159216f; // 1/sqrt(512)
  const float rs544 = 0.042874646285627205f; // 1/sqrt(544)

  dim3 blk(256);
  w3j_kernel<<<34, blk, 0, stream>>>(w3j);
  // weight convert+transpose
  wconv<<<(512*48+255)/256, blk, 0, stream>>>(we0, we0T, 40, 512, 48);
  wconv<<<(512*512+255)/256, blk, 0, stream>>>(we1, we1T, 512, 512, 512);
  wconv<<<(128*512+255)/256, blk, 0, stream>>>(winit, winT, 512, 128, 512);
  for (int l=0;l<2;l++){
    wconv<<<(32*512+255)/256, blk, 0, stream>>>(wenv + (size_t)l*512*32, wenvT + (size_t)l*32*512, 512, 32, 512);
    wconv<<<(512*544+255)/256, blk, 0, stream>>>(wlat0 + (size_t)l*544*512, wl0T + (size_t)l*512*544, 544, 512, 544);
    wconv<<<(512*512+255)/256, blk, 0, stream>>>(wlat1 + (size_t)l*512*512, wl1T + (size_t)l*512*512, 512, 512, 512);
  }
  edge_init<<<E/256, blk, 0, stream>>>(vectors, node_attrs, senders, receivers, feat, Yb, cutb, E);

  // edge embedding MLP + V init (chunked; h and wi live only in cbuf)
  for (int c0 = 0; c0 < E; c0 += CH) {
    gemm_mfma<unsigned short,true,false,false><<<dim3(8, CH/128), blk, 0, stream>>>(
        feat + (size_t)c0*48, 48, 48, nullptr, 0, we0T, 48, cbuf, 512, nullptr, 512, 48, rs40);
    gemm_mfma<unsigned short,false,true,false><<<dim3(8, CH/128), blk, 0, stream>>>(
        cbuf, 512, 512, nullptr, 0, we1T, 512, xb + (size_t)c0*512, 512, cutb + c0, 512, 512, rs512);
    gemm_mfma<unsigned short,false,false,false><<<dim3(2, CH/128), blk, 0, stream>>>(
        xb + (size_t)c0*512, 512, 512, nullptr, 0, winT, 512, cbuf, 128, nullptr, 128, 512, rs512);
    vbuild<<<(CH*512)/256, blk, 0, stream>>>(cbuf, Yb + (size_t)c0*16, Vb + (size_t)c0*512, CH);
  }

  for (int layer = 0; layer < 2; ++layer) {
    // w = x @ wenv  (fp32 out for scatter)
    gemm_mfma<float,false,false,false><<<dim3(1, E/128), blk, 0, stream>>>(
        xb, 512, 512, nullptr, 0, wenvT + (size_t)layer*32*512, 512, wbuf, 32, nullptr, 32, 512, rs512);
    zerok<<<(int)(((size_t)N*512)/256), blk, 0, stream>>>(nenv, (size_t)N*512);
    scatter_env<<<(int)(((size_t)E*512)/256), blk, 0, stream>>>(wbuf, Yb, receivers, nenv, E);
    // fused TP + mix (last layer: no mix, V dead afterwards)
    if (layer == 0)
      tp_mix<true><<<E/8, blk, 0, stream>>>(nenv, senders, Vb, w3j,
          wmix + (size_t)layer*4*32*32, t0b, E);
    else
      tp_mix<false><<<E/8, blk, 0, stream>>>(nenv, senders, Vb, w3j,
          wmix + (size_t)layer*4*32*32, t0b, E);
    // latent MLP chunked: [x | t0](544) -> h silu -> x * cut
    for (int c0 = 0; c0 < E; c0 += CH) {
      gemm_mfma<unsigned short,true,false,true><<<dim3(8, CH/128), blk, 0, stream>>>(
          xb + (size_t)c0*512, 512, 512, t0b + (size_t)c0*32, 32,
          wl0T + (size_t)layer*512*544, 544, cbuf, 512, nullptr, 512, 544, rs544);
      gemm_mfma<unsigned short,false,true,false><<<dim3(8, CH/128), blk, 0, stream>>>(
          cbuf, 512, 512, nullptr, 0, wl1T + (size_t)layer*512*512, 512,
          xb + (size_t)c0*512, 512, cutb + c0, 512, 512, rs512);
    }
  }

  out_kernel<<<E/4, blk, 0, stream>>>(xb, wout, out, E);
}

// Round 5
// 1113.522 us; speedup vs baseline: 8.8538x; 2.8881x over previous
//
#include <hip/hip_runtime.h>
#include <math.h>

typedef __attribute__((ext_vector_type(8))) short s8v;   // 8 bf16 (4 VGPR)
typedef __attribute__((ext_vector_type(4))) float f4v;   // MFMA acc

#define CH 8192

// ---------------- bf16 bit helpers ----------------
__device__ inline float b2f(unsigned short u){ return __uint_as_float(((unsigned)u)<<16); }
__device__ inline unsigned short f2b(float f){
  unsigned u = __float_as_uint(f);
  return (unsigned short)((u + 0x7FFFu + ((u>>16)&1u)) >> 16);   // RNE
}
__device__ inline void stC(float* p, float v){ *p = v; }
__device__ inline void stC(unsigned short* p, float v){ *p = f2b(v); }

// ================= compile-time real Wigner (CG) tables =================
constexpr double FCT[11] = {1.,1.,2.,6.,24.,120.,720.,5040.,40320.,362880.,3628800.};
constexpr double csqrt_c(double x){
  double g = x > 1.0 ? x : 1.0;
  for (int i=0;i<60;i++) g = 0.5*(g + x/g);
  return g;
}
struct CD { double re, im; };
constexpr CD cmulc(CD a, CD b){ return {a.re*b.re - a.im*b.im, a.re*b.im + a.im*b.re}; }

constexpr double su2cg_c(int j1,int j2,int j3,int m1,int m2,int m3){
  if (m1+m2 != m3) return 0.0;
  double pref = csqrt_c((double)(2*j3+1) * FCT[j1+j2-j3]*FCT[j1-j2+j3]*FCT[-j1+j2+j3]/FCT[j1+j2+j3+1]
              * FCT[j3+m3]*FCT[j3-m3]*FCT[j1-m1]*FCT[j1+m1]*FCT[j2-m2]*FCT[j2+m2]);
  int kmin = 0;
  if (j2-j3-m1 > kmin) kmin = j2-j3-m1;
  if (j1-j3+m2 > kmin) kmin = j1-j3+m2;
  int kmax = j1+j2-j3;
  if (j1-m1 < kmax) kmax = j1-m1;
  if (j2+m2 < kmax) kmax = j2+m2;
  double s = 0.0;
  for (int k=kmin;k<=kmax;k++){
    double t = 1.0/(FCT[k]*FCT[j1+j2-j3-k]*FCT[j1-m1-k]*FCT[j2+m2-k]*FCT[j3-j2+m1+k]*FCT[j3-j1-m2+k]);
    s += (k&1) ? -t : t;
  }
  return pref*s;
}

constexpr CD qelem_c(int l, int i, int j){
  int m = i - l;
  const double is2 = 0.70710678118654752440;
  double re=0.0, im=0.0;
  if (m < 0){
    if (j == l - m) re = is2;
    else if (j == l + m) im = -is2;
  } else if (m == 0){
    if (j == l) re = 1.0;
  } else {
    double sgn = (m & 1) ? -1.0 : 1.0;
    if (j == l + m) re = sgn*is2;
    else if (j == l - m) im = sgn*is2;
  }
  CD r{};
  switch (l & 3){                    // (-i)^l
    case 0: r = {re, im}; break;
    case 1: r = {im, -re}; break;
    case 2: r = {-re, -im}; break;
    default: r = {-im, re}; break;
  }
  return r;
}

// path-count normalization per l3: n = {4,9,11,10}
constexpr double TN3[4] = {0.5, 1.0/3.0, 0.30151134457776363, 0.31622776601683794};

template<int L1,int L2,int L3>
struct TriVals { float v[(2*L1+1)*(2*L2+1)*(2*L3+1)]; };

template<int L1,int L2,int L3>
constexpr TriVals<L1,L2,L3> make_tri(){
  constexpr int n1=2*L1+1, n2=2*L2+1, n3=2*L3+1;
  double cg[n1*n2*n3] = {};
  for (int a=0;a<n1;a++)
    for (int b=0;b<n2;b++)
      for (int c=0;c<n3;c++)
        cg[(a*n2+b)*n3+c] = su2cg_c(L1,L2,L3, a-L1, b-L2, c-L3);
  double cr[n1*n2*n3] = {};
  double ci[n1*n2*n3] = {};
  for (int i=0;i<n1;i++)
   for (int j=0;j<n2;j++)
    for (int k=0;k<n3;k++){
      double sre=0.0, sim=0.0;
      for (int a=0;a<n1;a++){
        CD q1 = qelem_c(L1,i,a);
        if (q1.re==0.0 && q1.im==0.0) continue;
        for (int b=0;b<n2;b++){
          CD q2 = qelem_c(L2,j,b);
          if (q2.re==0.0 && q2.im==0.0) continue;
          CD q12 = cmulc(q1,q2);
          for (int c=0;c<n3;c++){
            double g = cg[(a*n2+b)*n3+c];
            if (g == 0.0) continue;
            CD q3 = qelem_c(L3,k,c);
            CD q3c{q3.re, -q3.im};
            CD q = cmulc(q12,q3c);
            sre += q.re*g; sim += q.im*g;
          }
        }
      }
      cr[(i*n2+j)*n3+k]=sre; ci[(i*n2+j)*n3+k]=sim;
    }
  double nr=0.0, ni=0.0;
  for (int i=0;i<n1*n2*n3;i++){ nr += cr[i]*cr[i]; ni += ci[i]*ci[i]; }
  bool pr = nr >= ni;
  double nn = csqrt_c(pr ? nr : ni);
  TriVals<L1,L2,L3> t{};
  for (int i=0;i<n1*n2*n3;i++)
    t.v[i] = (float)(((pr ? cr[i] : ci[i]) / nn) * TN3[L3]);
  return t;
}

template<int L1,int L2,int L3>
constexpr TriVals<L1,L2,L3> W3V = make_tri<L1,L2,L3>();

constexpr int LOFFC[4] = {0,1,4,9};

// TP contraction for one triple; coefficients fold to literals, zeros vanish.
template<int L1,int L2,int L3>
__device__ __forceinline__ void tp_tri(const float* __restrict__ env,
                                       const float* __restrict__ v,
                                       float* __restrict__ acc){
  constexpr int n1=2*L1+1, n2=2*L2+1, n3=2*L3+1;
  #pragma unroll
  for (int k1=0;k1<n1;k1++)
    #pragma unroll
    for (int k2=0;k2<n2;k2++){
      float p = env[LOFFC[L1]+k1] * v[LOFFC[L2]+k2];
      #pragma unroll
      for (int k3=0;k3<n3;k3++){
        float w = W3V<L1,L2,L3>.v[(k1*n2+k2)*n3+k3];
        if (w != 0.f) acc[LOFFC[L3]+k3] += w * p;
      }
    }
}

// ---------------- weight convert+transpose: WT[n][k] = bf16(W[k][n]) ----------
__global__ __launch_bounds__(256) void wconv(
    const float* __restrict__ W, unsigned short* __restrict__ WT,
    int K, int N, int Kpad)
{
  int idx = blockIdx.x*256 + threadIdx.x;
  if (idx >= N*Kpad) return;
  int n = idx / Kpad, k = idx - n*Kpad;
  WT[idx] = (k < K) ? f2b(W[(size_t)k*N + n]) : (unsigned short)0;
}

// ---------------- edge geometry: feat48(bf16, zero-padded), Y, cut -------------
__global__ __launch_bounds__(256) void edge_init(
    const float* __restrict__ vec, const float* __restrict__ na,
    const int* __restrict__ snd, const int* __restrict__ rcv,
    unsigned short* __restrict__ feat, float* __restrict__ Y, float* __restrict__ cutb, int E)
{
  int e = blockIdx.x*256 + threadIdx.x;
  if (e >= E) return;
  float vx = vec[(size_t)e*3], vy = vec[(size_t)e*3+1], vz = vec[(size_t)e*3+2];
  float d = sqrtf(vx*vx + vy*vy + vz*vz);
  float inv = 1.f/(d + 1e-9f);
  float x = vx*inv, y = vy*inv, z = vz*inv;
  float dc = d * 0.4f;               // d / 2.5
  float dci = 1.f/(dc + 1e-9f);
  unsigned short* f = feat + (size_t)e*48;
  #pragma unroll
  for (int k=1;k<=8;k++)
    f[k-1] = f2b(1.41421356237309515f * sinf(dc * 3.14159265358979323846f * k) * dci);
  int s = snd[e], r = rcv[e];
  #pragma unroll
  for (int i=0;i<16;i++) f[8+i]  = f2b(na[(size_t)s*16+i]);
  #pragma unroll
  for (int i=0;i<16;i++) f[24+i] = f2b(na[(size_t)r*16+i]);
  #pragma unroll
  for (int i=40;i<48;i++) f[i] = 0;
  float cv = 0.f;
  if (dc < 1.f){
    float d2 = dc*dc; float d6 = d2*d2*d2; float d7 = d6*dc; float d8 = d7*dc;
    cv = 1.f - 28.f*d6 + 48.f*d7 - 21.f*d8;
  }
  cutb[e] = cv;
  float* Ye = Y + (size_t)e*16;
  const float s3=1.7320508075688772f, s5=2.2360679774997896f, s15=3.8729833462074170f;
  Ye[0] = 1.f;
  Ye[1] = s3*y; Ye[2] = s3*z; Ye[3] = s3*x;
  Ye[4] = s15*x*y; Ye[5] = s15*y*z; Ye[6] = 0.5f*s5*(3.f*z*z-1.f);
  Ye[7] = s15*x*z; Ye[8] = 0.5f*s15*(x*x - y*y);
  const float c1=2.0916500663351889f, c2=10.246950765959598f, c3=1.6201851746019649f, c4=1.3228756555322954f;
  Ye[9]  = c1*y*(3.f*x*x - y*y);
  Ye[10] = c2*x*y*z;
  Ye[11] = c3*y*(5.f*z*z - 1.f);
  Ye[12] = c4*z*(5.f*z*z - 3.f);
  Ye[13] = c3*x*(5.f*z*z - 1.f);
  Ye[14] = 0.5f*c2*z*(x*x - y*y);
  Ye[15] = c1*x*(x*x - 3.f*y*y);
}

// ---------------- MFMA bf16 GEMM: C = act(scale*[A|A2]@W) (*cut) ---------------
template<typename TC, bool SILU, bool CUT, bool HASA2>
__global__ __launch_bounds__(256) void gemm_mfma(
    const unsigned short* __restrict__ A, int lda, int K1,
    const float* __restrict__ A2, int lda2,
    const unsigned short* __restrict__ WT, int ldw,
    TC* __restrict__ C, int ldc,
    const float* __restrict__ cutv,
    int N, int K, float scale)
{
  __shared__ s8v As8[128*9];   // 128 rows, pitch 9 x (8 bf16)
  __shared__ s8v Bs8[64*9];
  const int tid = threadIdx.x;
  const int wid = tid >> 6, lane = tid & 63;
  const int r15 = lane & 15, kg = lane >> 4;
  const int col0 = blockIdx.x * 64;
  const int row0 = blockIdx.y * 128;
  f4v acc[2][4] = {};
  for (int k0 = 0; k0 < K; k0 += 64) {
    #pragma unroll
    for (int i = 0; i < 4; i++) {              // A tile
      int seg = tid + i*256;
      int r = seg >> 3, ks = seg & 7;
      int k = k0 + ks*8;
      s8v val = {};
      if (k + 8 <= K1) {
        val = *(const s8v*)(A + (size_t)(row0+r)*lda + k);
      } else if (HASA2 && k >= K1 && k + 8 <= K) {
        const float* s2 = A2 + (size_t)(row0+r)*lda2 + (k - K1);
        #pragma unroll
        for (int j=0;j<8;j++) val[j] = (short)f2b(s2[j]);
      }
      As8[r*9 + ks] = val;
    }
    #pragma unroll
    for (int i = 0; i < 2; i++) {              // B tile
      int seg = tid + i*256;
      int n = seg >> 3, ks = seg & 7;
      int k = k0 + ks*8;
      s8v val = {};
      if (col0 + n < N && k + 8 <= K)
        val = *(const s8v*)(WT + (size_t)(col0+n)*ldw + k);
      Bs8[n*9 + ks] = val;
    }
    __syncthreads();
    #pragma unroll
    for (int s = 0; s < 2; s++) {
      s8v a0 = As8[(wid*32      + r15)*9 + s*4 + kg];
      s8v a1 = As8[(wid*32 + 16 + r15)*9 + s*4 + kg];
      s8v b0 = Bs8[(      r15)*9 + s*4 + kg];
      s8v b1 = Bs8[(16  + r15)*9 + s*4 + kg];
      s8v b2 = Bs8[(32  + r15)*9 + s*4 + kg];
      s8v b3 = Bs8[(48  + r15)*9 + s*4 + kg];
      acc[0][0] = __builtin_amdgcn_mfma_f32_16x16x32_bf16(a0, b0, acc[0][0], 0,0,0);
      acc[0][1] = __builtin_amdgcn_mfma_f32_16x16x32_bf16(a0, b1, acc[0][1], 0,0,0);
      acc[0][2] = __builtin_amdgcn_mfma_f32_16x16x32_bf16(a0, b2, acc[0][2], 0,0,0);
      acc[0][3] = __builtin_amdgcn_mfma_f32_16x16x32_bf16(a0, b3, acc[0][3], 0,0,0);
      acc[1][0] = __builtin_amdgcn_mfma_f32_16x16x32_bf16(a1, b0, acc[1][0], 0,0,0);
      acc[1][1] = __builtin_amdgcn_mfma_f32_16x16x32_bf16(a1, b1, acc[1][1], 0,0,0);
      acc[1][2] = __builtin_amdgcn_mfma_f32_16x16x32_bf16(a1, b2, acc[1][2], 0,0,0);
      acc[1][3] = __builtin_amdgcn_mfma_f32_16x16x32_bf16(a1, b3, acc[1][3], 0,0,0);
    }
    __syncthreads();
  }
  #pragma unroll
  for (int g=0; g<2; g++) {
    #pragma unroll
    for (int c=0; c<4; c++) {
      int col = col0 + c*16 + r15;
      if (col >= N) continue;
      #pragma unroll
      for (int j=0;j<4;j++) {
        int row = row0 + wid*32 + g*16 + kg*4 + j;
        float v = acc[g][c][j] * scale;
        if (SILU) v = v / (1.f + __expf(-v));
        if (CUT)  v *= cutv[row];
        stC(&C[(size_t)row*ldc + col], v);
      }
    }
  }
}

// ---------------- V init: V[e][m][kk] = wi[e][l(kk)*32+m] * Y[e][kk] ------------
__global__ __launch_bounds__(256) void vbuild(
    const unsigned short* __restrict__ wi, const float* __restrict__ Y,
    unsigned short* __restrict__ V, int count)
{
  size_t t = (size_t)blockIdx.x*256 + threadIdx.x;
  if (t >= (size_t)count*512) return;
  int e = (int)(t >> 9); int j = (int)(t & 511);
  int m = j >> 4, kk = j & 15;
  int l = (kk>=9)?3:((kk>=4)?2:((kk>=1)?1:0));
  V[t] = f2b(b2f(wi[(size_t)e*128 + l*32 + m]) * Y[(size_t)e*16 + kk]);
}

// ---------------- zero fill ----------------
__global__ __launch_bounds__(256) void zerok(float* __restrict__ p, size_t n){
  size_t t = (size_t)blockIdx.x*256 + threadIdx.x;
  if (t < n) p[t] = 0.f;
}

// ---------------- segment_sum scatter ----------------
__global__ __launch_bounds__(256) void scatter_env(
    const float* __restrict__ w, const float* __restrict__ Y,
    const int* __restrict__ rcv, float* __restrict__ nenv, int E)
{
  size_t t = (size_t)blockIdx.x*256 + threadIdx.x;
  if (t >= (size_t)E*512) return;
  int e = (int)(t >> 9); int j = (int)(t & 511);
  int m = j >> 4, kk = j & 15;
  float val = w[(size_t)e*32 + m] * Y[(size_t)e*16 + kk];
  atomicAdd(&nenv[(size_t)rcv[e]*512 + j], val);
}

// ------------ fused tensor product + V-mix (compile-time W3J) -------------------
// 8 edges/block, thread (le,m). Writes t0 slice; if MIX, overwrites V in place.
template<bool MIX>
__global__ __launch_bounds__(256) void tp_mix(
    const float* __restrict__ nenv, const int* __restrict__ senders,
    unsigned short* __restrict__ V,
    const float* __restrict__ wm,     // layer slice: [4][32][32]
    float* __restrict__ t0, int E)
{
  __shared__ float Ts[MIX?8:1][32][17];   // pitch 17: conflict-free writes
  const int tid = threadIdx.x;
  const int le = tid >> 5, m = tid & 31;
  const int e = blockIdx.x*8 + le;
  const int s = senders[e];
  float env[16], v[16], acc[16];
  const float4* ne4 = (const float4*)(nenv + (size_t)s*512 + (size_t)m*16);
  #pragma unroll
  for (int q=0;q<4;q++){
    float4 f = ne4[q];
    env[q*4]=f.x*0.25f; env[q*4+1]=f.y*0.25f; env[q*4+2]=f.z*0.25f; env[q*4+3]=f.w*0.25f;
  }
  const s8v* vv = (const s8v*)(V + (size_t)e*512 + (size_t)m*16);
  s8v v0 = vv[0], v1 = vv[1];
  #pragma unroll
  for (int q=0;q<8;q++){ v[q] = b2f((unsigned short)v0[q]); v[8+q] = b2f((unsigned short)v1[q]); }
  #pragma unroll
  for (int k=0;k<16;k++) acc[k] = 0.f;

  tp_tri<0,0,0>(env,v,acc); tp_tri<0,1,1>(env,v,acc); tp_tri<0,2,2>(env,v,acc); tp_tri<0,3,3>(env,v,acc);
  tp_tri<1,0,1>(env,v,acc); tp_tri<1,1,0>(env,v,acc); tp_tri<1,1,1>(env,v,acc); tp_tri<1,1,2>(env,v,acc);
  tp_tri<1,2,1>(env,v,acc); tp_tri<1,2,2>(env,v,acc); tp_tri<1,2,3>(env,v,acc); tp_tri<1,3,2>(env,v,acc);
  tp_tri<1,3,3>(env,v,acc);
  tp_tri<2,0,2>(env,v,acc); tp_tri<2,1,1>(env,v,acc); tp_tri<2,1,2>(env,v,acc); tp_tri<2,1,3>(env,v,acc);
  tp_tri<2,2,0>(env,v,acc); tp_tri<2,2,1>(env,v,acc); tp_tri<2,2,2>(env,v,acc); tp_tri<2,2,3>(env,v,acc);
  tp_tri<2,3,1>(env,v,acc); tp_tri<2,3,2>(env,v,acc); tp_tri<2,3,3>(env,v,acc);
  tp_tri<3,0,3>(env,v,acc); tp_tri<3,1,2>(env,v,acc); tp_tri<3,1,3>(env,v,acc); tp_tri<3,2,1>(env,v,acc);
  tp_tri<3,2,2>(env,v,acc); tp_tri<3,2,3>(env,v,acc); tp_tri<3,3,0>(env,v,acc); tp_tri<3,3,1>(env,v,acc);
  tp_tri<3,3,2>(env,v,acc); tp_tri<3,3,3>(env,v,acc);

  t0[(size_t)e*32 + m] = acc[0];        // TN3 folded into W3V
  if (MIX) {
    constexpr int LOFK[16] = {0,1,1,1,2,2,2,2,2,3,3,3,3,3,3,3};
    #pragma unroll
    for (int k=0;k<16;k++) Ts[le][m][k] = acc[k];
    __syncthreads();
    float o16[16];
    #pragma unroll
    for (int k=0;k<16;k++) o16[k] = 0.f;
    #pragma unroll
    for (int mm=0; mm<32; mm++) {
      float w0 = wm[        mm*32 + m];
      float w1 = wm[1024 +  mm*32 + m];
      float w2 = wm[2048 +  mm*32 + m];
      float w3 = wm[3072 +  mm*32 + m];
      float wsel[4] = {w0,w1,w2,w3};
      #pragma unroll
      for (int k=0;k<16;k++) o16[k] += Ts[le][mm][k] * wsel[LOFK[k]];
    }
    unsigned short* vo = V + (size_t)e*512 + (size_t)m*16;
    #pragma unroll
    for (int k=0;k<16;k++) vo[k] = f2b(o16[k] * 0.17677669529663689f); // 1/sqrt(32)
  }
}

// ---------------- output: out[e] = (1/sqrt(512)) * dot(x[e], wout) --------------
__global__ __launch_bounds__(256) void out_kernel(
    const unsigned short* __restrict__ x, const float* __restrict__ wout,
    float* __restrict__ out, int E)
{
  int gw = (blockIdx.x*256 + threadIdx.x) >> 6;
  int lane = threadIdx.x & 63;
  if (gw >= E) return;
  const s8v* xr = (const s8v*)(x + (size_t)gw*512);
  s8v chunk = xr[lane];
  float s = 0.f;
  #pragma unroll
  for (int j=0;j<8;j++) s += b2f((unsigned short)chunk[j]) * wout[lane*8 + j];
  #pragma unroll
  for (int off=32; off; off>>=1) s += __shfl_down(s, off);
  if (lane == 0) out[gw] = s * 0.044194173824159216f; // 1/sqrt(512)
}

// ---------------- workspace sizing ----------------
static inline size_t alup(size_t b){ return (b + 255) & ~(size_t)255; }
static size_t need_bytes(int E, int N, int chd){
  size_t s = 0;
  s += alup((size_t)E*16*4);            // Yb
  s += alup((size_t)E*4);               // cutb
  s += alup((size_t)E*32*4);            // wbuf
  s += alup((size_t)E*32*4);            // t0b
  s += alup((size_t)N*512*4);           // nenv
  s += alup((size_t)E*48*2);            // feat
  s += alup((size_t)chd*512*2);         // cbuf
  s += alup((size_t)E*512*2);           // Vb
  s += alup((size_t)E*512*2);           // xb
  s += alup((size_t)512*48*2);          // we0T
  s += alup((size_t)512*512*2);         // we1T
  s += alup((size_t)128*512*2);         // winitT
  s += alup((size_t)2*32*512*2);        // wenvT
  s += alup((size_t)2*512*544*2);       // wlat0T
  s += alup((size_t)2*512*512*2);       // wlat1T
  return s;
}

// ---------------- launch ----------------
extern "C" void kernel_launch(void* const* d_in, const int* in_sizes, int n_in,
                              void* d_out, int out_size, void* d_ws, size_t ws_size,
                              hipStream_t stream)
{
  const float* node_attrs = (const float*)d_in[0];
  const float* vectors    = (const float*)d_in[1];
  const float* we0        = (const float*)d_in[2];
  const float* we1        = (const float*)d_in[3];
  const float* winit      = (const float*)d_in[4];
  const float* wenv       = (const float*)d_in[5];
  const float* wlat0      = (const float*)d_in[6];
  const float* wlat1      = (const float*)d_in[7];
  const float* wmix       = (const float*)d_in[8];
  const float* wout       = (const float*)d_in[9];
  const int*   senders    = (const int*)d_in[10];
  const int*   receivers  = (const int*)d_in[11];
  float* out = (float*)d_out;
  const int E = in_sizes[1] / 3;
  const int N = in_sizes[0] / 16;

  // pick chunking tier on actual ws_size (host-side, deterministic)
  int CHD;
  if (need_bytes(E, N, E) <= ws_size)        CHD = E;     // unchunked GEMMs
  else if (need_bytes(E, N, CH) <= ws_size)  CHD = CH;    // chunked transients
  else return;                                            // diagnostic clean fail

  char* base = (char*)d_ws;
  size_t off = 0;
  auto carve = [&](size_t b) -> char* { char* p = base + off; off += alup(b); return p; };
  float*          Yb    = (float*)carve((size_t)E*16*4);
  float*          cutb  = (float*)carve((size_t)E*4);
  float*          wbuf  = (float*)carve((size_t)E*32*4);
  float*          t0b   = (float*)carve((size_t)E*32*4);
  float*          nenv  = (float*)carve((size_t)N*512*4);
  unsigned short* feat  = (unsigned short*)carve((size_t)E*48*2);
  unsigned short* cbuf  = (unsigned short*)carve((size_t)CHD*512*2);
  unsigned short* Vb    = (unsigned short*)carve((size_t)E*512*2);
  unsigned short* xb    = (unsigned short*)carve((size_t)E*512*2);
  unsigned short* we0T  = (unsigned short*)carve((size_t)512*48*2);
  unsigned short* we1T  = (unsigned short*)carve((size_t)512*512*2);
  unsigned short* winT  = (unsigned short*)carve((size_t)128*512*2);
  unsigned short* wenvT = (unsigned short*)carve((size_t)2*32*512*2);
  unsigned short* wl0T  = (unsigned short*)carve((size_t)2*512*544*2);
  unsigned short* wl1T  = (unsigned short*)carve((size_t)2*512*512*2);

  const float rs40  = 0.15811388300841897f;  // 1/sqrt(40)
  const float rs512 = 0.044194173824159216f; // 1/sqrt(512)
  const float rs544 = 0.042874646285627205f; // 1/sqrt(544)

  dim3 blk(256);
  wconv<<<(512*48+255)/256, blk, 0, stream>>>(we0, we0T, 40, 512, 48);
  wconv<<<(512*512+255)/256, blk, 0, stream>>>(we1, we1T, 512, 512, 512);
  wconv<<<(128*512+255)/256, blk, 0, stream>>>(winit, winT, 512, 128, 512);
  for (int l=0;l<2;l++){
    wconv<<<(32*512+255)/256, blk, 0, stream>>>(wenv + (size_t)l*512*32, wenvT + (size_t)l*32*512, 512, 32, 512);
    wconv<<<(512*544+255)/256, blk, 0, stream>>>(wlat0 + (size_t)l*544*512, wl0T + (size_t)l*512*544, 544, 512, 544);
    wconv<<<(512*512+255)/256, blk, 0, stream>>>(wlat1 + (size_t)l*512*512, wl1T + (size_t)l*512*512, 512, 512, 512);
  }
  edge_init<<<E/256, blk, 0, stream>>>(vectors, node_attrs, senders, receivers, feat, Yb, cutb, E);

  // edge embedding MLP + V init
  for (int c0 = 0; c0 < E; c0 += CHD) {
    gemm_mfma<unsigned short,true,false,false><<<dim3(8, CHD/128), blk, 0, stream>>>(
        feat + (size_t)c0*48, 48, 48, nullptr, 0, we0T, 48, cbuf, 512, nullptr, 512, 48, rs40);
    gemm_mfma<unsigned short,false,true,false><<<dim3(8, CHD/128), blk, 0, stream>>>(
        cbuf, 512, 512, nullptr, 0, we1T, 512, xb + (size_t)c0*512, 512, cutb + c0, 512, 512, rs512);
    gemm_mfma<unsigned short,false,false,false><<<dim3(2, CHD/128), blk, 0, stream>>>(
        xb + (size_t)c0*512, 512, 512, nullptr, 0, winT, 512, cbuf, 128, nullptr, 128, 512, rs512);
    vbuild<<<(CHD*512)/256, blk, 0, stream>>>(cbuf, Yb + (size_t)c0*16, Vb + (size_t)c0*512, CHD);
  }

  for (int layer = 0; layer < 2; ++layer) {
    gemm_mfma<float,false,false,false><<<dim3(1, E/128), blk, 0, stream>>>(
        xb, 512, 512, nullptr, 0, wenvT + (size_t)layer*32*512, 512, wbuf, 32, nullptr, 32, 512, rs512);
    zerok<<<(int)(((size_t)N*512)/256), blk, 0, stream>>>(nenv, (size_t)N*512);
    scatter_env<<<(int)(((size_t)E*512)/256), blk, 0, stream>>>(wbuf, Yb, receivers, nenv, E);
    if (layer == 0)
      tp_mix<true><<<E/8, blk, 0, stream>>>(nenv, senders, Vb,
          wmix + (size_t)layer*4*32*32, t0b, E);
    else
      tp_mix<false><<<E/8, blk, 0, stream>>>(nenv, senders, Vb,
          wmix + (size_t)layer*4*32*32, t0b, E);
    for (int c0 = 0; c0 < E; c0 += CHD) {
      gemm_mfma<unsigned short,true,false,true><<<dim3(8, CHD/128), blk, 0, stream>>>(
          xb + (size_t)c0*512, 512, 512, t0b + (size_t)c0*32, 32,
          wl0T + (size_t)layer*512*544, 544, cbuf, 512, nullptr, 512, 544, rs544);
      gemm_mfma<unsigned short,false,true,false><<<dim3(8, CHD/128), blk, 0, stream>>>(
          cbuf, 512, 512, nullptr, 0, wl1T + (size_t)layer*512*512, 512,
          xb + (size_t)c0*512, 512, cutb + c0, 512, 512, rs512);
    }
  }

  out_kernel<<<E/4, blk, 0, stream>>>(xb, wout, out, E);
}

// Round 6
// 1052.971 us; speedup vs baseline: 9.3629x; 1.0575x over previous
//
#include <hip/hip_runtime.h>
#include <math.h>

typedef __attribute__((ext_vector_type(8))) short s8v;   // 8 bf16 (4 VGPR)
typedef __attribute__((ext_vector_type(4))) float f4v;   // MFMA acc

#define CH 8192

// ---------------- bf16 bit helpers ----------------
__device__ inline float b2f(unsigned short u){ return __uint_as_float(((unsigned)u)<<16); }
__device__ inline unsigned short f2b(float f){
  unsigned u = __float_as_uint(f);
  return (unsigned short)((u + 0x7FFFu + ((u>>16)&1u)) >> 16);   // RNE
}
__device__ inline void stC(float* p, float v){ *p = v; }
__device__ inline void stC(unsigned short* p, float v){ *p = f2b(v); }

// async global->LDS, 16B per lane; lds base must be wave-uniform
__device__ __forceinline__ void gl16(const void* g, void* l){
  __builtin_amdgcn_global_load_lds(
      (const __attribute__((address_space(1))) unsigned*)g,
      (__attribute__((address_space(3))) unsigned*)l, 16, 0, 0);
}

// ================= compile-time real Wigner (CG) tables =================
constexpr double FCT[11] = {1.,1.,2.,6.,24.,120.,720.,5040.,40320.,362880.,3628800.};
constexpr double csqrt_c(double x){
  double g = x > 1.0 ? x : 1.0;
  for (int i=0;i<60;i++) g = 0.5*(g + x/g);
  return g;
}
struct CD { double re, im; };
constexpr CD cmulc(CD a, CD b){ return {a.re*b.re - a.im*b.im, a.re*b.im + a.im*b.re}; }

constexpr double su2cg_c(int j1,int j2,int j3,int m1,int m2,int m3){
  if (m1+m2 != m3) return 0.0;
  double pref = csqrt_c((double)(2*j3+1) * FCT[j1+j2-j3]*FCT[j1-j2+j3]*FCT[-j1+j2+j3]/FCT[j1+j2+j3+1]
              * FCT[j3+m3]*FCT[j3-m3]*FCT[j1-m1]*FCT[j1+m1]*FCT[j2-m2]*FCT[j2+m2]);
  int kmin = 0;
  if (j2-j3-m1 > kmin) kmin = j2-j3-m1;
  if (j1-j3+m2 > kmin) kmin = j1-j3+m2;
  int kmax = j1+j2-j3;
  if (j1-m1 < kmax) kmax = j1-m1;
  if (j2+m2 < kmax) kmax = j2+m2;
  double s = 0.0;
  for (int k=kmin;k<=kmax;k++){
    double t = 1.0/(FCT[k]*FCT[j1+j2-j3-k]*FCT[j1-m1-k]*FCT[j2+m2-k]*FCT[j3-j2+m1+k]*FCT[j3-j1-m2+k]);
    s += (k&1) ? -t : t;
  }
  return pref*s;
}

constexpr CD qelem_c(int l, int i, int j){
  int m = i - l;
  const double is2 = 0.70710678118654752440;
  double re=0.0, im=0.0;
  if (m < 0){
    if (j == l - m) re = is2;
    else if (j == l + m) im = -is2;
  } else if (m == 0){
    if (j == l) re = 1.0;
  } else {
    double sgn = (m & 1) ? -1.0 : 1.0;
    if (j == l + m) re = sgn*is2;
    else if (j == l - m) im = sgn*is2;
  }
  CD r{};
  switch (l & 3){                    // (-i)^l
    case 0: r = {re, im}; break;
    case 1: r = {im, -re}; break;
    case 2: r = {-re, -im}; break;
    default: r = {-im, re}; break;
  }
  return r;
}

// path-count normalization per l3: n = {4,9,11,10}
constexpr double TN3[4] = {0.5, 1.0/3.0, 0.30151134457776363, 0.31622776601683794};

template<int L1,int L2,int L3>
struct TriVals { float v[(2*L1+1)*(2*L2+1)*(2*L3+1)]; };

template<int L1,int L2,int L3>
constexpr TriVals<L1,L2,L3> make_tri(){
  constexpr int n1=2*L1+1, n2=2*L2+1, n3=2*L3+1;
  double cg[n1*n2*n3] = {};
  for (int a=0;a<n1;a++)
    for (int b=0;b<n2;b++)
      for (int c=0;c<n3;c++)
        cg[(a*n2+b)*n3+c] = su2cg_c(L1,L2,L3, a-L1, b-L2, c-L3);
  double cr[n1*n2*n3] = {};
  double ci[n1*n2*n3] = {};
  for (int i=0;i<n1;i++)
   for (int j=0;j<n2;j++)
    for (int k=0;k<n3;k++){
      double sre=0.0, sim=0.0;
      for (int a=0;a<n1;a++){
        CD q1 = qelem_c(L1,i,a);
        if (q1.re==0.0 && q1.im==0.0) continue;
        for (int b=0;b<n2;b++){
          CD q2 = qelem_c(L2,j,b);
          if (q2.re==0.0 && q2.im==0.0) continue;
          CD q12 = cmulc(q1,q2);
          for (int c=0;c<n3;c++){
            double g = cg[(a*n2+b)*n3+c];
            if (g == 0.0) continue;
            CD q3 = qelem_c(L3,k,c);
            CD q3c{q3.re, -q3.im};
            CD q = cmulc(q12,q3c);
            sre += q.re*g; sim += q.im*g;
          }
        }
      }
      cr[(i*n2+j)*n3+k]=sre; ci[(i*n2+j)*n3+k]=sim;
    }
  double nr=0.0, ni=0.0;
  for (int i=0;i<n1*n2*n3;i++){ nr += cr[i]*cr[i]; ni += ci[i]*ci[i]; }
  bool pr = nr >= ni;
  double nn = csqrt_c(pr ? nr : ni);
  TriVals<L1,L2,L3> t{};
  for (int i=0;i<n1*n2*n3;i++)
    t.v[i] = (float)(((pr ? cr[i] : ci[i]) / nn) * TN3[L3]);
  return t;
}

template<int L1,int L2,int L3>
constexpr TriVals<L1,L2,L3> W3V = make_tri<L1,L2,L3>();

constexpr int LOFFC[4] = {0,1,4,9};

template<int L1,int L2,int L3>
__device__ __forceinline__ void tp_tri(const float* __restrict__ env,
                                       const float* __restrict__ v,
                                       float* __restrict__ acc){
  constexpr int n1=2*L1+1, n2=2*L2+1, n3=2*L3+1;
  #pragma unroll
  for (int k1=0;k1<n1;k1++)
    #pragma unroll
    for (int k2=0;k2<n2;k2++){
      float p = env[LOFFC[L1]+k1] * v[LOFFC[L2]+k2];
      #pragma unroll
      for (int k3=0;k3<n3;k3++){
        float w = W3V<L1,L2,L3>.v[(k1*n2+k2)*n3+k3];
        if (w != 0.f) acc[LOFFC[L3]+k3] += w * p;
      }
    }
}

// ---------------- weight convert+transpose: WT[n][k] = bf16(W[k][n]) ----------
__global__ __launch_bounds__(256) void wconv(
    const float* __restrict__ W, unsigned short* __restrict__ WT,
    int K, int N, int Kpad)
{
  int idx = blockIdx.x*256 + threadIdx.x;
  if (idx >= N*Kpad) return;
  int n = idx / Kpad, k = idx - n*Kpad;
  WT[idx] = (k < K) ? f2b(W[(size_t)k*N + n]) : (unsigned short)0;
}

// ---------------- edge geometry: feat64(bf16, zero-padded), Y, cut -------------
__global__ __launch_bounds__(256) void edge_init(
    const float* __restrict__ vec, const float* __restrict__ na,
    const int* __restrict__ snd, const int* __restrict__ rcv,
    unsigned short* __restrict__ feat, float* __restrict__ Y, float* __restrict__ cutb, int E)
{
  int e = blockIdx.x*256 + threadIdx.x;
  if (e >= E) return;
  float vx = vec[(size_t)e*3], vy = vec[(size_t)e*3+1], vz = vec[(size_t)e*3+2];
  float d = sqrtf(vx*vx + vy*vy + vz*vz);
  float inv = 1.f/(d + 1e-9f);
  float x = vx*inv, y = vy*inv, z = vz*inv;
  float dc = d * 0.4f;               // d / 2.5
  float dci = 1.f/(dc + 1e-9f);
  unsigned short* f = feat + (size_t)e*64;
  #pragma unroll
  for (int k=1;k<=8;k++)
    f[k-1] = f2b(1.41421356237309515f * sinf(dc * 3.14159265358979323846f * k) * dci);
  int s = snd[e], r = rcv[e];
  #pragma unroll
  for (int i=0;i<16;i++) f[8+i]  = f2b(na[(size_t)s*16+i]);
  #pragma unroll
  for (int i=0;i<16;i++) f[24+i] = f2b(na[(size_t)r*16+i]);
  #pragma unroll
  for (int i=40;i<64;i++) f[i] = 0;
  float cv = 0.f;
  if (dc < 1.f){
    float d2 = dc*dc; float d6 = d2*d2*d2; float d7 = d6*dc; float d8 = d7*dc;
    cv = 1.f - 28.f*d6 + 48.f*d7 - 21.f*d8;
  }
  cutb[e] = cv;
  float* Ye = Y + (size_t)e*16;
  const float s3=1.7320508075688772f, s5=2.2360679774997896f, s15=3.8729833462074170f;
  Ye[0] = 1.f;
  Ye[1] = s3*y; Ye[2] = s3*z; Ye[3] = s3*x;
  Ye[4] = s15*x*y; Ye[5] = s15*y*z; Ye[6] = 0.5f*s5*(3.f*z*z-1.f);
  Ye[7] = s15*x*z; Ye[8] = 0.5f*s15*(x*x - y*y);
  const float c1=2.0916500663351889f, c2=10.246950765959598f, c3=1.6201851746019649f, c4=1.3228756555322954f;
  Ye[9]  = c1*y*(3.f*x*x - y*y);
  Ye[10] = c2*x*y*z;
  Ye[11] = c3*y*(5.f*z*z - 1.f);
  Ye[12] = c4*z*(5.f*z*z - 3.f);
  Ye[13] = c3*x*(5.f*z*z - 1.f);
  Ye[14] = 0.5f*c2*z*(x*x - y*y);
  Ye[15] = c1*x*(x*x - 3.f*y*y);
}

// ---------------- MFMA bf16 GEMM with global_load_lds staging ------------------
// C = act(scale*[A|A2]@W) (*cut).  Tile: 128 rows x NT cols, BK=64, 4 waves.
// LDS layout linear [row][8 s8v] with XOR swizzle: physical slot ks holds
// logical k-col (ks ^ (row&7)); source pre-swizzled, read side applies same XOR.
template<int NT, typename TC, bool SILU, bool CUT, bool HASA2>
__global__ __launch_bounds__(256) void gemm_mfma(
    const unsigned short* __restrict__ A, int lda, int K1,
    const float* __restrict__ A2, int lda2,
    const unsigned short* __restrict__ WT, int ldw,
    TC* __restrict__ C, int ldc,
    const float* __restrict__ cutv,
    int N, int K, float scale)
{
  constexpr int NB = NT/16;
  __shared__ s8v As8[128*8];
  __shared__ s8v Bs8[NT*8];
  const int tid = threadIdx.x;
  const int wid = tid >> 6, lane = tid & 63;
  const int r15 = lane & 15, kg = lane >> 4;
  const int col0 = blockIdx.x * NT;
  const int row0 = blockIdx.y * 128;
  f4v acc[2][NB] = {};

  auto compute = [&](){
    #pragma unroll
    for (int s = 0; s < 2; s++) {
      const int cb = s*4 + kg;
      const int cx = cb ^ (r15 & 7);
      s8v a0 = As8[(wid*32      + r15)*8 + cx];
      s8v a1 = As8[(wid*32 + 16 + r15)*8 + cx];
      #pragma unroll
      for (int j = 0; j < NB; j++) {
        s8v b = Bs8[(j*16 + r15)*8 + cx];
        acc[0][j] = __builtin_amdgcn_mfma_f32_16x16x32_bf16(a0, b, acc[0][j], 0,0,0);
        acc[1][j] = __builtin_amdgcn_mfma_f32_16x16x32_bf16(a1, b, acc[1][j], 0,0,0);
      }
    }
  };

  const int Kfull = HASA2 ? K1 : K;     // K1 is a multiple of 64 when HASA2
  for (int k0 = 0; k0 < Kfull; k0 += 64) {
    #pragma unroll
    for (int i = 0; i < 4; i++) {       // A tile: 1024 segs of 16B
      int seg = i*256 + tid;
      int r = seg >> 3, ks = seg & 7;
      int ksx = ks ^ (r & 7);
      gl16(A + (size_t)(row0+r)*lda + k0 + ksx*8, &As8[i*256 + (tid & ~63)]);
    }
    #pragma unroll
    for (int i = 0; i < NT/32; i++) {   // B tile: NT*8 segs
      int seg = i*256 + tid;
      int n = seg >> 3, ks = seg & 7;
      int ksx = ks ^ (n & 7);
      gl16(WT + (size_t)(col0+n)*ldw + k0 + ksx*8, &Bs8[i*256 + (tid & ~63)]);
    }
    __syncthreads();
    compute();
    __syncthreads();
  }
  if (HASA2 && Kfull < K) {             // fp32 concat tail (one K-step)
    #pragma unroll
    for (int i = 0; i < 4; i++) {       // A tail: VGPR-staged, swizzled slot
      int seg = i*256 + tid;
      int r = seg >> 3, ks = seg & 7;
      int cl = ks ^ (r & 7);            // logical col block
      s8v val = {};
      #pragma unroll
      for (int j = 0; j < 8; j++) {
        int kk = cl*8 + j;              // col within tail
        if (K1 + kk < K) val[j] = (short)f2b(A2[(size_t)(row0+r)*lda2 + kk]);
      }
      As8[seg] = val;
    }
    #pragma unroll
    for (int i = 0; i < NT/32; i++) {   // B tail async (overrun reads benign)
      int seg = i*256 + tid;
      int n = seg >> 3, ks = seg & 7;
      int ksx = ks ^ (n & 7);
      gl16(WT + (size_t)(col0+n)*ldw + K1 + ksx*8, &Bs8[i*256 + (tid & ~63)]);
    }
    __syncthreads();
    compute();
  }
  // epilogue: C/D layout col = lane&15, row = (lane>>4)*4 + j
  #pragma unroll
  for (int g=0; g<2; g++) {
    #pragma unroll
    for (int c=0; c<NB; c++) {
      int col = col0 + c*16 + r15;
      if (col >= N) continue;
      #pragma unroll
      for (int j=0;j<4;j++) {
        int row = row0 + wid*32 + g*16 + kg*4 + j;
        float v = acc[g][c][j] * scale;
        if (SILU) v = v / (1.f + __expf(-v));
        if (CUT)  v *= cutv[row];
        stC(&C[(size_t)row*ldc + col], v);
      }
    }
  }
}

// ---------------- V init: V[e][m][kk] = wi[e][l(kk)*32+m] * Y[e][kk] ------------
__global__ __launch_bounds__(256) void vbuild(
    const unsigned short* __restrict__ wi, const float* __restrict__ Y,
    unsigned short* __restrict__ V, int count)
{
  size_t t = (size_t)blockIdx.x*256 + threadIdx.x;
  if (t >= (size_t)count*512) return;
  int e = (int)(t >> 9); int j = (int)(t & 511);
  int m = j >> 4, kk = j & 15;
  int l = (kk>=9)?3:((kk>=4)?2:((kk>=1)?1:0));
  V[t] = f2b(b2f(wi[(size_t)e*128 + l*32 + m]) * Y[(size_t)e*16 + kk]);
}

// ---------------- zero fill ----------------
__global__ __launch_bounds__(256) void zerok(float* __restrict__ p, size_t n){
  size_t t = (size_t)blockIdx.x*256 + threadIdx.x;
  if (t < n) p[t] = 0.f;
}

// ---------------- segment_sum scatter ----------------
__global__ __launch_bounds__(256) void scatter_env(
    const float* __restrict__ w, const float* __restrict__ Y,
    const int* __restrict__ rcv, float* __restrict__ nenv, int E)
{
  size_t t = (size_t)blockIdx.x*256 + threadIdx.x;
  if (t >= (size_t)E*512) return;
  int e = (int)(t >> 9); int j = (int)(t & 511);
  int m = j >> 4, kk = j & 15;
  float val = w[(size_t)e*32 + m] * Y[(size_t)e*16 + kk];
  atomicAdd(&nenv[(size_t)rcv[e]*512 + j], val);
}

// ------------ fused tensor product + V-mix (compile-time W3J) -------------------
// env scale 1/sqrt(16) is folded into the wenv GEMM scale upstream.
template<bool MIX>
__global__ __launch_bounds__(256) void tp_mix(
    const float* __restrict__ nenv, const int* __restrict__ senders,
    unsigned short* __restrict__ V,
    const float* __restrict__ wm,     // layer slice: [4][32][32]
    float* __restrict__ t0, int E)
{
  __shared__ float Ts[MIX?8:1][32][17];
  const int tid = threadIdx.x;
  const int le = tid >> 5, m = tid & 31;
  const int e = blockIdx.x*8 + le;
  const int s = senders[e];
  float env[16], v[16], acc[16];
  const float4* ne4 = (const float4*)(nenv + (size_t)s*512 + (size_t)m*16);
  #pragma unroll
  for (int q=0;q<4;q++){
    float4 f = ne4[q];
    env[q*4]=f.x; env[q*4+1]=f.y; env[q*4+2]=f.z; env[q*4+3]=f.w;
  }
  const s8v* vv = (const s8v*)(V + (size_t)e*512 + (size_t)m*16);
  s8v v0 = vv[0], v1 = vv[1];
  #pragma unroll
  for (int q=0;q<8;q++){ v[q] = b2f((unsigned short)v0[q]); v[8+q] = b2f((unsigned short)v1[q]); }
  #pragma unroll
  for (int k=0;k<16;k++) acc[k] = 0.f;

  tp_tri<0,0,0>(env,v,acc); tp_tri<0,1,1>(env,v,acc); tp_tri<0,2,2>(env,v,acc); tp_tri<0,3,3>(env,v,acc);
  tp_tri<1,0,1>(env,v,acc); tp_tri<1,1,0>(env,v,acc); tp_tri<1,1,1>(env,v,acc); tp_tri<1,1,2>(env,v,acc);
  tp_tri<1,2,1>(env,v,acc); tp_tri<1,2,2>(env,v,acc); tp_tri<1,2,3>(env,v,acc); tp_tri<1,3,2>(env,v,acc);
  tp_tri<1,3,3>(env,v,acc);
  tp_tri<2,0,2>(env,v,acc); tp_tri<2,1,1>(env,v,acc); tp_tri<2,1,2>(env,v,acc); tp_tri<2,1,3>(env,v,acc);
  tp_tri<2,2,0>(env,v,acc); tp_tri<2,2,1>(env,v,acc); tp_tri<2,2,2>(env,v,acc); tp_tri<2,2,3>(env,v,acc);
  tp_tri<2,3,1>(env,v,acc); tp_tri<2,3,2>(env,v,acc); tp_tri<2,3,3>(env,v,acc);
  tp_tri<3,0,3>(env,v,acc); tp_tri<3,1,2>(env,v,acc); tp_tri<3,1,3>(env,v,acc); tp_tri<3,2,1>(env,v,acc);
  tp_tri<3,2,2>(env,v,acc); tp_tri<3,2,3>(env,v,acc); tp_tri<3,3,0>(env,v,acc); tp_tri<3,3,1>(env,v,acc);
  tp_tri<3,3,2>(env,v,acc); tp_tri<3,3,3>(env,v,acc);

  t0[(size_t)e*32 + m] = acc[0];        // TN3 folded into W3V
  if (MIX) {
    constexpr int LOFK[16] = {0,1,1,1,2,2,2,2,2,3,3,3,3,3,3,3};
    #pragma unroll
    for (int k=0;k<16;k++) Ts[le][m][k] = acc[k];
    __syncthreads();
    float o16[16];
    #pragma unroll
    for (int k=0;k<16;k++) o16[k] = 0.f;
    #pragma unroll
    for (int mm=0; mm<32; mm++) {
      float w0 = wm[        mm*32 + m];
      float w1 = wm[1024 +  mm*32 + m];
      float w2 = wm[2048 +  mm*32 + m];
      float w3 = wm[3072 +  mm*32 + m];
      float wsel[4] = {w0,w1,w2,w3};
      #pragma unroll
      for (int k=0;k<16;k++) o16[k] += Ts[le][mm][k] * wsel[LOFK[k]];
    }
    unsigned short* vo = V + (size_t)e*512 + (size_t)m*16;
    #pragma unroll
    for (int k=0;k<16;k++) vo[k] = f2b(o16[k] * 0.17677669529663689f); // 1/sqrt(32)
  }
}

// ---------------- output: out[e] = (1/sqrt(512)) * dot(x[e], wout) --------------
__global__ __launch_bounds__(256) void out_kernel(
    const unsigned short* __restrict__ x, const float* __restrict__ wout,
    float* __restrict__ out, int E)
{
  int gw = (blockIdx.x*256 + threadIdx.x) >> 6;
  int lane = threadIdx.x & 63;
  if (gw >= E) return;
  const s8v* xr = (const s8v*)(x + (size_t)gw*512);
  s8v chunk = xr[lane];
  float s = 0.f;
  #pragma unroll
  for (int j=0;j<8;j++) s += b2f((unsigned short)chunk[j]) * wout[lane*8 + j];
  #pragma unroll
  for (int off=32; off; off>>=1) s += __shfl_down(s, off);
  if (lane == 0) out[gw] = s * 0.044194173824159216f; // 1/sqrt(512)
}

// ---------------- workspace sizing ----------------
static inline size_t alup(size_t b){ return (b + 255) & ~(size_t)255; }
static size_t need_bytes(int E, int N, int chd){
  size_t s = 0;
  s += alup((size_t)E*16*4);            // Yb
  s += alup((size_t)E*4);               // cutb
  s += alup((size_t)E*32*4);            // wbuf
  s += alup((size_t)E*32*4);            // t0b
  s += alup((size_t)N*512*4);           // nenv
  s += alup((size_t)E*64*2);            // feat (padded to 64)
  s += alup((size_t)chd*512*2);         // cbuf
  s += alup((size_t)E*512*2);           // Vb
  s += alup((size_t)E*512*2);           // xb
  s += alup((size_t)512*64*2);          // we0T
  s += alup((size_t)512*512*2);         // we1T
  s += alup((size_t)128*512*2);         // winitT
  s += alup((size_t)2*32*512*2);        // wenvT
  s += alup((size_t)2*512*544*2);       // wlat0T
  s += alup((size_t)2*512*512*2);       // wlat1T
  return s;
}

// ---------------- launch ----------------
extern "C" void kernel_launch(void* const* d_in, const int* in_sizes, int n_in,
                              void* d_out, int out_size, void* d_ws, size_t ws_size,
                              hipStream_t stream)
{
  const float* node_attrs = (const float*)d_in[0];
  const float* vectors    = (const float*)d_in[1];
  const float* we0        = (const float*)d_in[2];
  const float* we1        = (const float*)d_in[3];
  const float* winit      = (const float*)d_in[4];
  const float* wenv       = (const float*)d_in[5];
  const float* wlat0      = (const float*)d_in[6];
  const float* wlat1      = (const float*)d_in[7];
  const float* wmix       = (const float*)d_in[8];
  const float* wout       = (const float*)d_in[9];
  const int*   senders    = (const int*)d_in[10];
  const int*   receivers  = (const int*)d_in[11];
  float* out = (float*)d_out;
  const int E = in_sizes[1] / 3;
  const int N = in_sizes[0] / 16;

  int CHD;
  if (need_bytes(E, N, E) <= ws_size)        CHD = E;     // unchunked GEMMs
  else if (need_bytes(E, N, CH) <= ws_size)  CHD = CH;    // chunked transients
  else return;                                            // diagnostic clean fail

  char* base = (char*)d_ws;
  size_t off = 0;
  auto carve = [&](size_t b) -> char* { char* p = base + off; off += alup(b); return p; };
  float*          Yb    = (float*)carve((size_t)E*16*4);
  float*          cutb  = (float*)carve((size_t)E*4);
  float*          wbuf  = (float*)carve((size_t)E*32*4);
  float*          t0b   = (float*)carve((size_t)E*32*4);
  float*          nenv  = (float*)carve((size_t)N*512*4);
  unsigned short* feat  = (unsigned short*)carve((size_t)E*64*2);
  unsigned short* cbuf  = (unsigned short*)carve((size_t)CHD*512*2);
  unsigned short* Vb    = (unsigned short*)carve((size_t)E*512*2);
  unsigned short* xb    = (unsigned short*)carve((size_t)E*512*2);
  unsigned short* we0T  = (unsigned short*)carve((size_t)512*64*2);
  unsigned short* we1T  = (unsigned short*)carve((size_t)512*512*2);
  unsigned short* winT  = (unsigned short*)carve((size_t)128*512*2);
  unsigned short* wenvT = (unsigned short*)carve((size_t)2*32*512*2);
  unsigned short* wl0T  = (unsigned short*)carve((size_t)2*512*544*2);
  unsigned short* wl1T  = (unsigned short*)carve((size_t)2*512*512*2);

  const float rs40  = 0.15811388300841897f;  // 1/sqrt(40)
  const float rs512 = 0.044194173824159216f; // 1/sqrt(512)
  const float rs544 = 0.042874646285627205f; // 1/sqrt(544)

  dim3 blk(256);
  wconv<<<(512*64+255)/256, blk, 0, stream>>>(we0, we0T, 40, 512, 64);
  wconv<<<(512*512+255)/256, blk, 0, stream>>>(we1, we1T, 512, 512, 512);
  wconv<<<(128*512+255)/256, blk, 0, stream>>>(winit, winT, 512, 128, 512);
  for (int l=0;l<2;l++){
    wconv<<<(32*512+255)/256, blk, 0, stream>>>(wenv + (size_t)l*512*32, wenvT + (size_t)l*32*512, 512, 32, 512);
    wconv<<<(512*544+255)/256, blk, 0, stream>>>(wlat0 + (size_t)l*544*512, wl0T + (size_t)l*512*544, 544, 512, 544);
    wconv<<<(512*512+255)/256, blk, 0, stream>>>(wlat1 + (size_t)l*512*512, wl1T + (size_t)l*512*512, 512, 512, 512);
  }
  edge_init<<<E/256, blk, 0, stream>>>(vectors, node_attrs, senders, receivers, feat, Yb, cutb, E);

  // edge embedding MLP + V init
  for (int c0 = 0; c0 < E; c0 += CHD) {
    gemm_mfma<128,unsigned short,true,false,false><<<dim3(4, CHD/128), blk, 0, stream>>>(
        feat + (size_t)c0*64, 64, 64, nullptr, 0, we0T, 64, cbuf, 512, nullptr, 512, 64, rs40);
    gemm_mfma<128,unsigned short,false,true,false><<<dim3(4, CHD/128), blk, 0, stream>>>(
        cbuf, 512, 512, nullptr, 0, we1T, 512, xb + (size_t)c0*512, 512, cutb + c0, 512, 512, rs512);
    gemm_mfma<128,unsigned short,false,false,false><<<dim3(1, CHD/128), blk, 0, stream>>>(
        xb + (size_t)c0*512, 512, 512, nullptr, 0, winT, 512, cbuf, 128, nullptr, 128, 512, rs512);
    vbuild<<<(CHD*512)/256, blk, 0, stream>>>(cbuf, Yb + (size_t)c0*16, Vb + (size_t)c0*512, CHD);
  }

  for (int layer = 0; layer < 2; ++layer) {
    // w = x @ wenv, with 1/sqrt(AVG_NEIGH)=0.25 folded in
    gemm_mfma<64,float,false,false,false><<<dim3(1, E/128), blk, 0, stream>>>(
        xb, 512, 512, nullptr, 0, wenvT + (size_t)layer*32*512, 512, wbuf, 32, nullptr, 32, 512, rs512*0.25f);
    zerok<<<(int)(((size_t)N*512)/256), blk, 0, stream>>>(nenv, (size_t)N*512);
    scatter_env<<<(int)(((size_t)E*512)/256), blk, 0, stream>>>(wbuf, Yb, receivers, nenv, E);
    if (layer == 0)
      tp_mix<true><<<E/8, blk, 0, stream>>>(nenv, senders, Vb,
          wmix + (size_t)layer*4*32*32, t0b, E);
    else
      tp_mix<false><<<E/8, blk, 0, stream>>>(nenv, senders, Vb,
          wmix + (size_t)layer*4*32*32, t0b, E);
    for (int c0 = 0; c0 < E; c0 += CHD) {
      gemm_mfma<128,unsigned short,true,false,true><<<dim3(4, CHD/128), blk, 0, stream>>>(
          xb + (size_t)c0*512, 512, 512, t0b + (size_t)c0*32, 32,
          wl0T + (size_t)layer*512*544, 544, cbuf, 512, nullptr, 512, 544, rs544);
      gemm_mfma<128,unsigned short,false,true,false><<<dim3(4, CHD/128), blk, 0, stream>>>(
          cbuf, 512, 512, nullptr, 0, wl1T + (size_t)layer*512*512, 512,
          xb + (size_t)c0*512, 512, cutb + c0, 512, 512, rs512);
    }
  }

  out_kernel<<<E/4, blk, 0, stream>>>(xb, wout, out, E);
}

// Round 7
// 983.430 us; speedup vs baseline: 10.0250x; 1.0707x over previous
//
#include <hip/hip_runtime.h>
#include <math.h>

typedef __attribute__((ext_vector_type(8))) short s8v;   // 8 bf16 (4 VGPR)
typedef __attribute__((ext_vector_type(4))) float f4v;   // MFMA acc

#define CH 8192

// ---------------- bf16 bit helpers ----------------
__device__ inline float b2f(unsigned short u){ return __uint_as_float(((unsigned)u)<<16); }
__device__ inline unsigned short f2b(float f){
  unsigned u = __float_as_uint(f);
  return (unsigned short)((u + 0x7FFFu + ((u>>16)&1u)) >> 16);   // RNE
}
__device__ inline void stC(float* p, float v){ *p = v; }
__device__ inline void stC(unsigned short* p, float v){ *p = f2b(v); }

// async global->LDS, 16B per lane; lds base must be wave-uniform
__device__ __forceinline__ void gl16(const void* g, void* l){
  __builtin_amdgcn_global_load_lds(
      (const __attribute__((address_space(1))) unsigned*)g,
      (__attribute__((address_space(3))) unsigned*)l, 16, 0, 0);
}

// ================= compile-time real Wigner (CG) tables =================
constexpr double FCT[11] = {1.,1.,2.,6.,24.,120.,720.,5040.,40320.,362880.,3628800.};
constexpr double csqrt_c(double x){
  double g = x > 1.0 ? x : 1.0;
  for (int i=0;i<60;i++) g = 0.5*(g + x/g);
  return g;
}
struct CD { double re, im; };
constexpr CD cmulc(CD a, CD b){ return {a.re*b.re - a.im*b.im, a.re*b.im + a.im*b.re}; }

constexpr double su2cg_c(int j1,int j2,int j3,int m1,int m2,int m3){
  if (m1+m2 != m3) return 0.0;
  double pref = csqrt_c((double)(2*j3+1) * FCT[j1+j2-j3]*FCT[j1-j2+j3]*FCT[-j1+j2+j3]/FCT[j1+j2+j3+1]
              * FCT[j3+m3]*FCT[j3-m3]*FCT[j1-m1]*FCT[j1+m1]*FCT[j2-m2]*FCT[j2+m2]);
  int kmin = 0;
  if (j2-j3-m1 > kmin) kmin = j2-j3-m1;
  if (j1-j3+m2 > kmin) kmin = j1-j3+m2;
  int kmax = j1+j2-j3;
  if (j1-m1 < kmax) kmax = j1-m1;
  if (j2+m2 < kmax) kmax = j2+m2;
  double s = 0.0;
  for (int k=kmin;k<=kmax;k++){
    double t = 1.0/(FCT[k]*FCT[j1+j2-j3-k]*FCT[j1-m1-k]*FCT[j2+m2-k]*FCT[j3-j2+m1+k]*FCT[j3-j1-m2+k]);
    s += (k&1) ? -t : t;
  }
  return pref*s;
}

constexpr CD qelem_c(int l, int i, int j){
  int m = i - l;
  const double is2 = 0.70710678118654752440;
  double re=0.0, im=0.0;
  if (m < 0){
    if (j == l - m) re = is2;
    else if (j == l + m) im = -is2;
  } else if (m == 0){
    if (j == l) re = 1.0;
  } else {
    double sgn = (m & 1) ? -1.0 : 1.0;
    if (j == l + m) re = sgn*is2;
    else if (j == l - m) im = sgn*is2;
  }
  CD r{};
  switch (l & 3){                    // (-i)^l
    case 0: r = {re, im}; break;
    case 1: r = {im, -re}; break;
    case 2: r = {-re, -im}; break;
    default: r = {-im, re}; break;
  }
  return r;
}

// path-count normalization per l3: n = {4,9,11,10}
constexpr double TN3[4] = {0.5, 1.0/3.0, 0.30151134457776363, 0.31622776601683794};

template<int L1,int L2,int L3>
struct TriVals { float v[(2*L1+1)*(2*L2+1)*(2*L3+1)]; };

template<int L1,int L2,int L3>
constexpr TriVals<L1,L2,L3> make_tri(){
  constexpr int n1=2*L1+1, n2=2*L2+1, n3=2*L3+1;
  double cg[n1*n2*n3] = {};
  for (int a=0;a<n1;a++)
    for (int b=0;b<n2;b++)
      for (int c=0;c<n3;c++)
        cg[(a*n2+b)*n3+c] = su2cg_c(L1,L2,L3, a-L1, b-L2, c-L3);
  double cr[n1*n2*n3] = {};
  double ci[n1*n2*n3] = {};
  for (int i=0;i<n1;i++)
   for (int j=0;j<n2;j++)
    for (int k=0;k<n3;k++){
      double sre=0.0, sim=0.0;
      for (int a=0;a<n1;a++){
        CD q1 = qelem_c(L1,i,a);
        if (q1.re==0.0 && q1.im==0.0) continue;
        for (int b=0;b<n2;b++){
          CD q2 = qelem_c(L2,j,b);
          if (q2.re==0.0 && q2.im==0.0) continue;
          CD q12 = cmulc(q1,q2);
          for (int c=0;c<n3;c++){
            double g = cg[(a*n2+b)*n3+c];
            if (g == 0.0) continue;
            CD q3 = qelem_c(L3,k,c);
            CD q3c{q3.re, -q3.im};
            CD q = cmulc(q12,q3c);
            sre += q.re*g; sim += q.im*g;
          }
        }
      }
      cr[(i*n2+j)*n3+k]=sre; ci[(i*n2+j)*n3+k]=sim;
    }
  double nr=0.0, ni=0.0;
  for (int i=0;i<n1*n2*n3;i++){ nr += cr[i]*cr[i]; ni += ci[i]*ci[i]; }
  bool pr = nr >= ni;
  double nn = csqrt_c(pr ? nr : ni);
  TriVals<L1,L2,L3> t{};
  for (int i=0;i<n1*n2*n3;i++)
    t.v[i] = (float)(((pr ? cr[i] : ci[i]) / nn) * TN3[L3]);
  return t;
}

template<int L1,int L2,int L3>
constexpr TriVals<L1,L2,L3> W3V = make_tri<L1,L2,L3>();

constexpr int LOFFC[4] = {0,1,4,9};

template<int L1,int L2,int L3>
__device__ __forceinline__ void tp_tri(const float* __restrict__ env,
                                       const float* __restrict__ v,
                                       float* __restrict__ acc){
  constexpr int n1=2*L1+1, n2=2*L2+1, n3=2*L3+1;
  #pragma unroll
  for (int k1=0;k1<n1;k1++)
    #pragma unroll
    for (int k2=0;k2<n2;k2++){
      float p = env[LOFFC[L1]+k1] * v[LOFFC[L2]+k2];
      #pragma unroll
      for (int k3=0;k3<n3;k3++){
        float w = W3V<L1,L2,L3>.v[(k1*n2+k2)*n3+k3];
        if (w != 0.f) acc[LOFFC[L3]+k3] += w * p;
      }
    }
}

// ---------------- weight convert+transpose: WT[n][k] = bf16(W[k][n]) ----------
__global__ __launch_bounds__(256) void wconv(
    const float* __restrict__ W, unsigned short* __restrict__ WT,
    int K, int N, int Kpad)
{
  int idx = blockIdx.x*256 + threadIdx.x;
  if (idx >= N*Kpad) return;
  int n = idx / Kpad, k = idx - n*Kpad;
  WT[idx] = (k < K) ? f2b(W[(size_t)k*N + n]) : (unsigned short)0;
}

// ---------------- edge geometry: feat64(bf16, zero-padded), Y, cut -------------
__global__ __launch_bounds__(256) void edge_init(
    const float* __restrict__ vec, const float* __restrict__ na,
    const int* __restrict__ snd, const int* __restrict__ rcv,
    unsigned short* __restrict__ feat, float* __restrict__ Y, float* __restrict__ cutb, int E)
{
  int e = blockIdx.x*256 + threadIdx.x;
  if (e >= E) return;
  float vx = vec[(size_t)e*3], vy = vec[(size_t)e*3+1], vz = vec[(size_t)e*3+2];
  float d = sqrtf(vx*vx + vy*vy + vz*vz);
  float inv = 1.f/(d + 1e-9f);
  float x = vx*inv, y = vy*inv, z = vz*inv;
  float dc = d * 0.4f;               // d / 2.5
  float dci = 1.f/(dc + 1e-9f);
  unsigned short* f = feat + (size_t)e*64;
  #pragma unroll
  for (int k=1;k<=8;k++)
    f[k-1] = f2b(1.41421356237309515f * sinf(dc * 3.14159265358979323846f * k) * dci);
  int s = snd[e], r = rcv[e];
  #pragma unroll
  for (int i=0;i<16;i++) f[8+i]  = f2b(na[(size_t)s*16+i]);
  #pragma unroll
  for (int i=0;i<16;i++) f[24+i] = f2b(na[(size_t)r*16+i]);
  #pragma unroll
  for (int i=40;i<64;i++) f[i] = 0;
  float cv = 0.f;
  if (dc < 1.f){
    float d2 = dc*dc; float d6 = d2*d2*d2; float d7 = d6*dc; float d8 = d7*dc;
    cv = 1.f - 28.f*d6 + 48.f*d7 - 21.f*d8;
  }
  cutb[e] = cv;
  float* Ye = Y + (size_t)e*16;
  const float s3=1.7320508075688772f, s5=2.2360679774997896f, s15=3.8729833462074170f;
  Ye[0] = 1.f;
  Ye[1] = s3*y; Ye[2] = s3*z; Ye[3] = s3*x;
  Ye[4] = s15*x*y; Ye[5] = s15*y*z; Ye[6] = 0.5f*s5*(3.f*z*z-1.f);
  Ye[7] = s15*x*z; Ye[8] = 0.5f*s15*(x*x - y*y);
  const float c1=2.0916500663351889f, c2=10.246950765959598f, c3=1.6201851746019649f, c4=1.3228756555322954f;
  Ye[9]  = c1*y*(3.f*x*x - y*y);
  Ye[10] = c2*x*y*z;
  Ye[11] = c3*y*(5.f*z*z - 1.f);
  Ye[12] = c4*z*(5.f*z*z - 3.f);
  Ye[13] = c3*x*(5.f*z*z - 1.f);
  Ye[14] = 0.5f*c2*z*(x*x - y*y);
  Ye[15] = c1*x*(x*x - 3.f*y*y);
}

// ---------------- MFMA bf16 GEMM with global_load_lds staging ------------------
template<int NT, typename TC, bool SILU, bool CUT, bool HASA2>
__global__ __launch_bounds__(256) void gemm_mfma(
    const unsigned short* __restrict__ A, int lda, int K1,
    const float* __restrict__ A2, int lda2,
    const unsigned short* __restrict__ WT, int ldw,
    TC* __restrict__ C, int ldc,
    const float* __restrict__ cutv,
    int N, int K, float scale)
{
  constexpr int NB = NT/16;
  __shared__ s8v As8[128*8];
  __shared__ s8v Bs8[NT*8];
  const int tid = threadIdx.x;
  const int wid = tid >> 6, lane = tid & 63;
  const int r15 = lane & 15, kg = lane >> 4;
  const int col0 = blockIdx.x * NT;
  const int row0 = blockIdx.y * 128;
  f4v acc[2][NB] = {};

  auto compute = [&](){
    #pragma unroll
    for (int s = 0; s < 2; s++) {
      const int cb = s*4 + kg;
      const int cx = cb ^ (r15 & 7);
      s8v a0 = As8[(wid*32      + r15)*8 + cx];
      s8v a1 = As8[(wid*32 + 16 + r15)*8 + cx];
      #pragma unroll
      for (int j = 0; j < NB; j++) {
        s8v b = Bs8[(j*16 + r15)*8 + cx];
        acc[0][j] = __builtin_amdgcn_mfma_f32_16x16x32_bf16(a0, b, acc[0][j], 0,0,0);
        acc[1][j] = __builtin_amdgcn_mfma_f32_16x16x32_bf16(a1, b, acc[1][j], 0,0,0);
      }
    }
  };

  const int Kfull = HASA2 ? K1 : K;     // K1 is a multiple of 64 when HASA2
  for (int k0 = 0; k0 < Kfull; k0 += 64) {
    #pragma unroll
    for (int i = 0; i < 4; i++) {       // A tile: 1024 segs of 16B
      int seg = i*256 + tid;
      int r = seg >> 3, ks = seg & 7;
      int ksx = ks ^ (r & 7);
      gl16(A + (size_t)(row0+r)*lda + k0 + ksx*8, &As8[i*256 + (tid & ~63)]);
    }
    #pragma unroll
    for (int i = 0; i < NT/32; i++) {   // B tile: NT*8 segs
      int seg = i*256 + tid;
      int n = seg >> 3, ks = seg & 7;
      int ksx = ks ^ (n & 7);
      gl16(WT + (size_t)(col0+n)*ldw + k0 + ksx*8, &Bs8[i*256 + (tid & ~63)]);
    }
    __syncthreads();
    compute();
    __syncthreads();
  }
  if (HASA2 && Kfull < K) {             // fp32 concat tail (one K-step)
    #pragma unroll
    for (int i = 0; i < 4; i++) {       // A tail: VGPR-staged, swizzled slot
      int seg = i*256 + tid;
      int r = seg >> 3, ks = seg & 7;
      int cl = ks ^ (r & 7);            // logical col block
      s8v val = {};
      #pragma unroll
      for (int j = 0; j < 8; j++) {
        int kk = cl*8 + j;              // col within tail
        if (K1 + kk < K) val[j] = (short)f2b(A2[(size_t)(row0+r)*lda2 + kk]);
      }
      As8[seg] = val;
    }
    #pragma unroll
    for (int i = 0; i < NT/32; i++) {   // B tail async (overrun reads benign)
      int seg = i*256 + tid;
      int n = seg >> 3, ks = seg & 7;
      int ksx = ks ^ (n & 7);
      gl16(WT + (size_t)(col0+n)*ldw + K1 + ksx*8, &Bs8[i*256 + (tid & ~63)]);
    }
    __syncthreads();
    compute();
  }
  // epilogue: C/D layout col = lane&15, row = (lane>>4)*4 + j
  #pragma unroll
  for (int g=0; g<2; g++) {
    #pragma unroll
    for (int c=0; c<NB; c++) {
      int col = col0 + c*16 + r15;
      if (col >= N) continue;
      #pragma unroll
      for (int j=0;j<4;j++) {
        int row = row0 + wid*32 + g*16 + kg*4 + j;
        float v = acc[g][c][j] * scale;
        if (SILU) v = v / (1.f + __expf(-v));
        if (CUT)  v *= cutv[row];
        stC(&C[(size_t)row*ldc + col], v);
      }
    }
  }
}

// ---------------- V init: V[e][m][kk] = wi[e][l(kk)*32+m] * Y[e][kk] ------------
__global__ __launch_bounds__(256) void vbuild(
    const unsigned short* __restrict__ wi, const float* __restrict__ Y,
    unsigned short* __restrict__ V, int count)
{
  size_t t = (size_t)blockIdx.x*256 + threadIdx.x;
  if (t >= (size_t)count*512) return;
  int e = (int)(t >> 9); int j = (int)(t & 511);
  int m = j >> 4, kk = j & 15;
  int l = (kk>=9)?3:((kk>=4)?2:((kk>=1)?1:0));
  V[t] = f2b(b2f(wi[(size_t)e*128 + l*32 + m]) * Y[(size_t)e*16 + kk]);
}

// ---------------- segment_sum scatter ----------------
__global__ __launch_bounds__(256) void scatter_env(
    const float* __restrict__ w, const float* __restrict__ Y,
    const int* __restrict__ rcv, float* __restrict__ nenv, int E)
{
  size_t t = (size_t)blockIdx.x*256 + threadIdx.x;
  if (t >= (size_t)E*512) return;
  int e = (int)(t >> 9); int j = (int)(t & 511);
  int m = j >> 4, kk = j & 15;
  float val = w[(size_t)e*32 + m] * Y[(size_t)e*16 + kk];
  atomicAdd(&nenv[(size_t)rcv[e]*512 + j], val);
}

// ------------ fused tensor product + V-mix (compile-time W3J) -------------------
// env scale 1/sqrt(16) folded into the wenv GEMM scale upstream.
// __launch_bounds__(256,2): pin >=2 waves/EU so VGPR<=128 (R6 regression: 132 VGPR
// halved occupancy 22%->12% and cost +100us/dispatch).
template<bool MIX>
__global__ __launch_bounds__(256, 2) void tp_mix(
    const float* __restrict__ nenv, const int* __restrict__ senders,
    unsigned short* __restrict__ V,
    const float* __restrict__ wm,     // layer slice: [4][32][32]
    float* __restrict__ t0, int E)
{
  __shared__ float Ts[MIX?8:1][32][17];
  const int tid = threadIdx.x;
  const int le = tid >> 5, m = tid & 31;
  const int e = blockIdx.x*8 + le;
  const int s = senders[e];
  float env[16], v[16], acc[16];
  const float4* ne4 = (const float4*)(nenv + (size_t)s*512 + (size_t)m*16);
  #pragma unroll
  for (int q=0;q<4;q++){
    float4 f = ne4[q];
    env[q*4]=f.x; env[q*4+1]=f.y; env[q*4+2]=f.z; env[q*4+3]=f.w;
  }
  const s8v* vv = (const s8v*)(V + (size_t)e*512 + (size_t)m*16);
  s8v v0 = vv[0], v1 = vv[1];
  #pragma unroll
  for (int q=0;q<8;q++){ v[q] = b2f((unsigned short)v0[q]); v[8+q] = b2f((unsigned short)v1[q]); }
  #pragma unroll
  for (int k=0;k<16;k++) acc[k] = 0.f;

  tp_tri<0,0,0>(env,v,acc); tp_tri<0,1,1>(env,v,acc); tp_tri<0,2,2>(env,v,acc); tp_tri<0,3,3>(env,v,acc);
  tp_tri<1,0,1>(env,v,acc); tp_tri<1,1,0>(env,v,acc); tp_tri<1,1,1>(env,v,acc); tp_tri<1,1,2>(env,v,acc);
  tp_tri<1,2,1>(env,v,acc); tp_tri<1,2,2>(env,v,acc); tp_tri<1,2,3>(env,v,acc); tp_tri<1,3,2>(env,v,acc);
  tp_tri<1,3,3>(env,v,acc);
  tp_tri<2,0,2>(env,v,acc); tp_tri<2,1,1>(env,v,acc); tp_tri<2,1,2>(env,v,acc); tp_tri<2,1,3>(env,v,acc);
  tp_tri<2,2,0>(env,v,acc); tp_tri<2,2,1>(env,v,acc); tp_tri<2,2,2>(env,v,acc); tp_tri<2,2,3>(env,v,acc);
  tp_tri<2,3,1>(env,v,acc); tp_tri<2,3,2>(env,v,acc); tp_tri<2,3,3>(env,v,acc);
  tp_tri<3,0,3>(env,v,acc); tp_tri<3,1,2>(env,v,acc); tp_tri<3,1,3>(env,v,acc); tp_tri<3,2,1>(env,v,acc);
  tp_tri<3,2,2>(env,v,acc); tp_tri<3,2,3>(env,v,acc); tp_tri<3,3,0>(env,v,acc); tp_tri<3,3,1>(env,v,acc);
  tp_tri<3,3,2>(env,v,acc); tp_tri<3,3,3>(env,v,acc);

  t0[(size_t)e*32 + m] = acc[0];        // TN3 folded into W3V
  if (MIX) {
    constexpr int LOFK[16] = {0,1,1,1,2,2,2,2,2,3,3,3,3,3,3,3};
    #pragma unroll
    for (int k=0;k<16;k++) Ts[le][m][k] = acc[k];
    __syncthreads();
    float o16[16];
    #pragma unroll
    for (int k=0;k<16;k++) o16[k] = 0.f;
    #pragma unroll
    for (int mm=0; mm<32; mm++) {
      float w0 = wm[        mm*32 + m];
      float w1 = wm[1024 +  mm*32 + m];
      float w2 = wm[2048 +  mm*32 + m];
      float w3 = wm[3072 +  mm*32 + m];
      float wsel[4] = {w0,w1,w2,w3};
      #pragma unroll
      for (int k=0;k<16;k++) o16[k] += Ts[le][mm][k] * wsel[LOFK[k]];
    }
    // vectorized writeback: 16x2B scalar stores -> 2x16B stores
    s8v o0, o1;
    #pragma unroll
    for (int k=0;k<8;k++){
      o0[k] = (short)f2b(o16[k]   * 0.17677669529663689f); // 1/sqrt(32)
      o1[k] = (short)f2b(o16[8+k] * 0.17677669529663689f);
    }
    s8v* vo = (s8v*)(V + (size_t)e*512 + (size_t)m*16);
    vo[0] = o0; vo[1] = o1;
  }
}

// ---------------- output: out[e] = (1/sqrt(512)) * dot(x[e], wout) --------------
__global__ __launch_bounds__(256) void out_kernel(
    const unsigned short* __restrict__ x, const float* __restrict__ wout,
    float* __restrict__ out, int E)
{
  int gw = (blockIdx.x*256 + threadIdx.x) >> 6;
  int lane = threadIdx.x & 63;
  if (gw >= E) return;
  const s8v* xr = (const s8v*)(x + (size_t)gw*512);
  s8v chunk = xr[lane];
  float s = 0.f;
  #pragma unroll
  for (int j=0;j<8;j++) s += b2f((unsigned short)chunk[j]) * wout[lane*8 + j];
  #pragma unroll
  for (int off=32; off; off>>=1) s += __shfl_down(s, off);
  if (lane == 0) out[gw] = s * 0.044194173824159216f; // 1/sqrt(512)
}

// ---------------- workspace sizing ----------------
static inline size_t alup(size_t b){ return (b + 255) & ~(size_t)255; }
static size_t need_bytes(int E, int N, int chd){
  size_t s = 0;
  s += alup((size_t)E*16*4);            // Yb
  s += alup((size_t)E*4);               // cutb
  s += alup((size_t)E*32*4);            // wbuf
  s += alup((size_t)E*32*4);            // t0b
  s += alup((size_t)N*512*4);           // nenv
  s += alup((size_t)E*64*2);            // feat (padded to 64)
  s += alup((size_t)chd*512*2);         // cbuf
  s += alup((size_t)E*512*2);           // Vb
  s += alup((size_t)E*512*2);           // xb
  s += alup((size_t)512*64*2);          // we0T
  s += alup((size_t)512*512*2);         // we1T
  s += alup((size_t)128*512*2);         // winitT
  s += alup((size_t)2*32*512*2);        // wenvT
  s += alup((size_t)2*512*544*2);       // wlat0T
  s += alup((size_t)2*512*512*2);       // wlat1T
  return s;
}

// ---------------- launch ----------------
extern "C" void kernel_launch(void* const* d_in, const int* in_sizes, int n_in,
                              void* d_out, int out_size, void* d_ws, size_t ws_size,
                              hipStream_t stream)
{
  const float* node_attrs = (const float*)d_in[0];
  const float* vectors    = (const float*)d_in[1];
  const float* we0        = (const float*)d_in[2];
  const float* we1        = (const float*)d_in[3];
  const float* winit      = (const float*)d_in[4];
  const float* wenv       = (const float*)d_in[5];
  const float* wlat0      = (const float*)d_in[6];
  const float* wlat1      = (const float*)d_in[7];
  const float* wmix       = (const float*)d_in[8];
  const float* wout       = (const float*)d_in[9];
  const int*   senders    = (const int*)d_in[10];
  const int*   receivers  = (const int*)d_in[11];
  float* out = (float*)d_out;
  const int E = in_sizes[1] / 3;
  const int N = in_sizes[0] / 16;

  int CHD;
  if (need_bytes(E, N, E) <= ws_size)        CHD = E;     // unchunked GEMMs
  else if (need_bytes(E, N, CH) <= ws_size)  CHD = CH;    // chunked transients
  else return;                                            // diagnostic clean fail

  char* base = (char*)d_ws;
  size_t off = 0;
  auto carve = [&](size_t b) -> char* { char* p = base + off; off += alup(b); return p; };
  float*          Yb    = (float*)carve((size_t)E*16*4);
  float*          cutb  = (float*)carve((size_t)E*4);
  float*          wbuf  = (float*)carve((size_t)E*32*4);
  float*          t0b   = (float*)carve((size_t)E*32*4);
  float*          nenv  = (float*)carve((size_t)N*512*4);
  unsigned short* feat  = (unsigned short*)carve((size_t)E*64*2);
  unsigned short* cbuf  = (unsigned short*)carve((size_t)CHD*512*2);
  unsigned short* Vb    = (unsigned short*)carve((size_t)E*512*2);
  unsigned short* xb    = (unsigned short*)carve((size_t)E*512*2);
  unsigned short* we0T  = (unsigned short*)carve((size_t)512*64*2);
  unsigned short* we1T  = (unsigned short*)carve((size_t)512*512*2);
  unsigned short* winT  = (unsigned short*)carve((size_t)128*512*2);
  unsigned short* wenvT = (unsigned short*)carve((size_t)2*32*512*2);
  unsigned short* wl0T  = (unsigned short*)carve((size_t)2*512*544*2);
  unsigned short* wl1T  = (unsigned short*)carve((size_t)2*512*512*2);

  const float rs40  = 0.15811388300841897f;  // 1/sqrt(40)
  const float rs512 = 0.044194173824159216f; // 1/sqrt(512)
  const float rs544 = 0.042874646285627205f; // 1/sqrt(544)

  dim3 blk(256);
  wconv<<<(512*64+255)/256, blk, 0, stream>>>(we0, we0T, 40, 512, 64);
  wconv<<<(512*512+255)/256, blk, 0, stream>>>(we1, we1T, 512, 512, 512);
  wconv<<<(128*512+255)/256, blk, 0, stream>>>(winit, winT, 512, 128, 512);
  for (int l=0;l<2;l++){
    wconv<<<(32*512+255)/256, blk, 0, stream>>>(wenv + (size_t)l*512*32, wenvT + (size_t)l*32*512, 512, 32, 512);
    wconv<<<(512*544+255)/256, blk, 0, stream>>>(wlat0 + (size_t)l*544*512, wl0T + (size_t)l*512*544, 544, 512, 544);
    wconv<<<(512*512+255)/256, blk, 0, stream>>>(wlat1 + (size_t)l*512*512, wl1T + (size_t)l*512*512, 512, 512, 512);
  }
  edge_init<<<E/256, blk, 0, stream>>>(vectors, node_attrs, senders, receivers, feat, Yb, cutb, E);

  // edge embedding MLP + V init
  for (int c0 = 0; c0 < E; c0 += CHD) {
    gemm_mfma<128,unsigned short,true,false,false><<<dim3(4, CHD/128), blk, 0, stream>>>(
        feat + (size_t)c0*64, 64, 64, nullptr, 0, we0T, 64, cbuf, 512, nullptr, 512, 64, rs40);
    gemm_mfma<128,unsigned short,false,true,false><<<dim3(4, CHD/128), blk, 0, stream>>>(
        cbuf, 512, 512, nullptr, 0, we1T, 512, xb + (size_t)c0*512, 512, cutb + c0, 512, 512, rs512);
    gemm_mfma<128,unsigned short,false,false,false><<<dim3(1, CHD/128), blk, 0, stream>>>(
        xb + (size_t)c0*512, 512, 512, nullptr, 0, winT, 512, cbuf, 128, nullptr, 128, 512, rs512);
    vbuild<<<(CHD*512)/256, blk, 0, stream>>>(cbuf, Yb + (size_t)c0*16, Vb + (size_t)c0*512, CHD);
  }

  for (int layer = 0; layer < 2; ++layer) {
    // w = x @ wenv, with 1/sqrt(AVG_NEIGH)=0.25 folded in
    gemm_mfma<64,float,false,false,false><<<dim3(1, E/128), blk, 0, stream>>>(
        xb, 512, 512, nullptr, 0, wenvT + (size_t)layer*32*512, 512, wbuf, 32, nullptr, 32, 512, rs512*0.25f);
    hipMemsetAsync(nenv, 0, (size_t)N*512*4, stream);
    scatter_env<<<(int)(((size_t)E*512)/256), blk, 0, stream>>>(wbuf, Yb, receivers, nenv, E);
    if (layer == 0)
      tp_mix<true><<<E/8, blk, 0, stream>>>(nenv, senders, Vb,
          wmix + (size_t)layer*4*32*32, t0b, E);
    else
      tp_mix<false><<<E/8, blk, 0, stream>>>(nenv, senders, Vb,
          wmix + (size_t)layer*4*32*32, t0b, E);
    for (int c0 = 0; c0 < E; c0 += CHD) {
      gemm_mfma<128,unsigned short,true,false,true><<<dim3(4, CHD/128), blk, 0, stream>>>(
          xb + (size_t)c0*512, 512, 512, t0b + (size_t)c0*32, 32,
          wl0T + (size_t)layer*512*544, 544, cbuf, 512, nullptr, 512, 544, rs544);
      gemm_mfma<128,unsigned short,false,true,false><<<dim3(4, CHD/128), blk, 0, stream>>>(
          cbuf, 512, 512, nullptr, 0, wl1T + (size_t)layer*512*512, 512,
          xb + (size_t)c0*512, 512, cutb + c0, 512, 512, rs512);
    }
  }

  out_kernel<<<E/4, blk, 0, stream>>>(xb, wout, out, E);
}

// Round 8
// 940.227 us; speedup vs baseline: 10.4857x; 1.0459x over previous
//
#include <hip/hip_runtime.h>
#include <math.h>

typedef __attribute__((ext_vector_type(8))) short s8v;   // 8 bf16 (4 VGPR)
typedef __attribute__((ext_vector_type(4))) float f4v;   // MFMA acc
typedef __attribute__((ext_vector_type(2))) float f2v;   // packed f32 pair

#define CH 8192

// ---------------- bf16 bit helpers ----------------
__device__ inline float b2f(unsigned short u){ return __uint_as_float(((unsigned)u)<<16); }
__device__ inline unsigned short f2b(float f){
  unsigned u = __float_as_uint(f);
  return (unsigned short)((u + 0x7FFFu + ((u>>16)&1u)) >> 16);   // RNE
}
__device__ inline void stC(float* p, float v){ *p = v; }
__device__ inline void stC(unsigned short* p, float v){ *p = f2b(v); }

// async global->LDS, 16B per lane; lds base must be wave-uniform
__device__ __forceinline__ void gl16(const void* g, void* l){
  __builtin_amdgcn_global_load_lds(
      (const __attribute__((address_space(1))) unsigned*)g,
      (__attribute__((address_space(3))) unsigned*)l, 16, 0, 0);
}

// ================= compile-time real Wigner (CG) tables =================
constexpr double FCT[11] = {1.,1.,2.,6.,24.,120.,720.,5040.,40320.,362880.,3628800.};
constexpr double csqrt_c(double x){
  double g = x > 1.0 ? x : 1.0;
  for (int i=0;i<60;i++) g = 0.5*(g + x/g);
  return g;
}
struct CD { double re, im; };
constexpr CD cmulc(CD a, CD b){ return {a.re*b.re - a.im*b.im, a.re*b.im + a.im*b.re}; }

constexpr double su2cg_c(int j1,int j2,int j3,int m1,int m2,int m3){
  if (m1+m2 != m3) return 0.0;
  double pref = csqrt_c((double)(2*j3+1) * FCT[j1+j2-j3]*FCT[j1-j2+j3]*FCT[-j1+j2+j3]/FCT[j1+j2+j3+1]
              * FCT[j3+m3]*FCT[j3-m3]*FCT[j1-m1]*FCT[j1+m1]*FCT[j2-m2]*FCT[j2+m2]);
  int kmin = 0;
  if (j2-j3-m1 > kmin) kmin = j2-j3-m1;
  if (j1-j3+m2 > kmin) kmin = j1-j3+m2;
  int kmax = j1+j2-j3;
  if (j1-m1 < kmax) kmax = j1-m1;
  if (j2+m2 < kmax) kmax = j2+m2;
  double s = 0.0;
  for (int k=kmin;k<=kmax;k++){
    double t = 1.0/(FCT[k]*FCT[j1+j2-j3-k]*FCT[j1-m1-k]*FCT[j2+m2-k]*FCT[j3-j2+m1+k]*FCT[j3-j1-m2+k]);
    s += (k&1) ? -t : t;
  }
  return pref*s;
}

constexpr CD qelem_c(int l, int i, int j){
  int m = i - l;
  const double is2 = 0.70710678118654752440;
  double re=0.0, im=0.0;
  if (m < 0){
    if (j == l - m) re = is2;
    else if (j == l + m) im = -is2;
  } else if (m == 0){
    if (j == l) re = 1.0;
  } else {
    double sgn = (m & 1) ? -1.0 : 1.0;
    if (j == l + m) re = sgn*is2;
    else if (j == l - m) im = sgn*is2;
  }
  CD r{};
  switch (l & 3){                    // (-i)^l
    case 0: r = {re, im}; break;
    case 1: r = {im, -re}; break;
    case 2: r = {-re, -im}; break;
    default: r = {-im, re}; break;
  }
  return r;
}

// path-count normalization per l3: n = {4,9,11,10}
constexpr double TN3[4] = {0.5, 1.0/3.0, 0.30151134457776363, 0.31622776601683794};

template<int L1,int L2,int L3>
struct TriVals { float v[(2*L1+1)*(2*L2+1)*(2*L3+1)]; };

template<int L1,int L2,int L3>
constexpr TriVals<L1,L2,L3> make_tri(){
  constexpr int n1=2*L1+1, n2=2*L2+1, n3=2*L3+1;
  double cg[n1*n2*n3] = {};
  for (int a=0;a<n1;a++)
    for (int b=0;b<n2;b++)
      for (int c=0;c<n3;c++)
        cg[(a*n2+b)*n3+c] = su2cg_c(L1,L2,L3, a-L1, b-L2, c-L3);
  double cr[n1*n2*n3] = {};
  double ci[n1*n2*n3] = {};
  for (int i=0;i<n1;i++)
   for (int j=0;j<n2;j++)
    for (int k=0;k<n3;k++){
      double sre=0.0, sim=0.0;
      for (int a=0;a<n1;a++){
        CD q1 = qelem_c(L1,i,a);
        if (q1.re==0.0 && q1.im==0.0) continue;
        for (int b=0;b<n2;b++){
          CD q2 = qelem_c(L2,j,b);
          if (q2.re==0.0 && q2.im==0.0) continue;
          CD q12 = cmulc(q1,q2);
          for (int c=0;c<n3;c++){
            double g = cg[(a*n2+b)*n3+c];
            if (g == 0.0) continue;
            CD q3 = qelem_c(L3,k,c);
            CD q3c{q3.re, -q3.im};
            CD q = cmulc(q12,q3c);
            sre += q.re*g; sim += q.im*g;
          }
        }
      }
      cr[(i*n2+j)*n3+k]=sre; ci[(i*n2+j)*n3+k]=sim;
    }
  double nr=0.0, ni=0.0;
  for (int i=0;i<n1*n2*n3;i++){ nr += cr[i]*cr[i]; ni += ci[i]*ci[i]; }
  bool pr = nr >= ni;
  double nn = csqrt_c(pr ? nr : ni);
  TriVals<L1,L2,L3> t{};
  for (int i=0;i<n1*n2*n3;i++)
    t.v[i] = (float)(((pr ? cr[i] : ci[i]) / nn) * TN3[L3]);
  return t;
}

template<int L1,int L2,int L3>
constexpr TriVals<L1,L2,L3> W3V = make_tri<L1,L2,L3>();

constexpr int LOFFC[4] = {0,1,4,9};

// bounds-checked compile-time getter (folds after unroll)
template<int L1,int L2,int L3>
__device__ __forceinline__ constexpr float w3get(int k1,int k2,int k3){
  constexpr int n2=2*L2+1, n3=2*L3+1;
  if (k3 < 0 || k3 >= n3) return 0.f;
  return W3V<L1,L2,L3>.v[(k1*n2+k2)*n3+k3];
}

// scalar variant (used by tp_last's 4 l3=0 triples)
template<int L1,int L2,int L3>
__device__ __forceinline__ void tp_tri(const float* __restrict__ env,
                                       const float* __restrict__ v,
                                       float* __restrict__ acc){
  constexpr int n1=2*L1+1, n2=2*L2+1, n3=2*L3+1;
  #pragma unroll
  for (int k1=0;k1<n1;k1++)
    #pragma unroll
    for (int k2=0;k2<n2;k2++){
      float p = env[LOFFC[L1]+k1] * v[LOFFC[L2]+k2];
      #pragma unroll
      for (int k3=0;k3<n3;k3++){
        float w = W3V<L1,L2,L3>.v[(k1*n2+k2)*n3+k3];
        if (w != 0.f) acc[LOFFC[L3]+k3] += w * p;
      }
    }
}

// packed variant: acc as 8x float2 over absolute k index; weight pairs fold to
// literals; pairs with both-zero vanish -> ~650 v_pk_fma vs ~1100 v_fma.
template<int L1,int L2,int L3>
__device__ __forceinline__ void tp_tri2(const float* __restrict__ env,
                                        const float* __restrict__ v,
                                        f2v* __restrict__ acc2){
  constexpr int n1=2*L1+1, n2=2*L2+1, o3=LOFFC[L3];
  #pragma unroll
  for (int k1=0;k1<n1;k1++)
    #pragma unroll
    for (int k2=0;k2<n2;k2++){
      float p = env[LOFFC[L1]+k1] * v[LOFFC[L2]+k2];
      #pragma unroll
      for (int kp=0; kp<8; kp++){
        float wlo = w3get<L1,L2,L3>(k1,k2, 2*kp   - o3);
        float whi = w3get<L1,L2,L3>(k1,k2, 2*kp+1 - o3);
        if (wlo != 0.f || whi != 0.f){
          f2v w2; w2[0]=wlo; w2[1]=whi;
          f2v p2; p2[0]=p;  p2[1]=p;
          acc2[kp] += w2 * p2;       // -ffp-contract -> v_pk_fma_f32
        }
      }
    }
}

// ---------------- weight convert+transpose: WT[n][k] = bf16(W[k][n]) ----------
__global__ __launch_bounds__(256) void wconv(
    const float* __restrict__ W, unsigned short* __restrict__ WT,
    int K, int N, int Kpad)
{
  int idx = blockIdx.x*256 + threadIdx.x;
  if (idx >= N*Kpad) return;
  int n = idx / Kpad, k = idx - n*Kpad;
  WT[idx] = (k < K) ? f2b(W[(size_t)k*N + n]) : (unsigned short)0;
}

// ---------------- edge geometry: feat64(bf16, zero-padded), Y, cut -------------
__global__ __launch_bounds__(256) void edge_init(
    const float* __restrict__ vec, const float* __restrict__ na,
    const int* __restrict__ snd, const int* __restrict__ rcv,
    unsigned short* __restrict__ feat, float* __restrict__ Y, float* __restrict__ cutb, int E)
{
  int e = blockIdx.x*256 + threadIdx.x;
  if (e >= E) return;
  float vx = vec[(size_t)e*3], vy = vec[(size_t)e*3+1], vz = vec[(size_t)e*3+2];
  float d = sqrtf(vx*vx + vy*vy + vz*vz);
  float inv = 1.f/(d + 1e-9f);
  float x = vx*inv, y = vy*inv, z = vz*inv;
  float dc = d * 0.4f;               // d / 2.5
  float dci = 1.f/(dc + 1e-9f);
  unsigned short* f = feat + (size_t)e*64;
  #pragma unroll
  for (int k=1;k<=8;k++)
    f[k-1] = f2b(1.41421356237309515f * sinf(dc * 3.14159265358979323846f * k) * dci);
  int s = snd[e], r = rcv[e];
  #pragma unroll
  for (int i=0;i<16;i++) f[8+i]  = f2b(na[(size_t)s*16+i]);
  #pragma unroll
  for (int i=0;i<16;i++) f[24+i] = f2b(na[(size_t)r*16+i]);
  #pragma unroll
  for (int i=40;i<64;i++) f[i] = 0;
  float cv = 0.f;
  if (dc < 1.f){
    float d2 = dc*dc; float d6 = d2*d2*d2; float d7 = d6*dc; float d8 = d7*dc;
    cv = 1.f - 28.f*d6 + 48.f*d7 - 21.f*d8;
  }
  cutb[e] = cv;
  float* Ye = Y + (size_t)e*16;
  const float s3=1.7320508075688772f, s5=2.2360679774997896f, s15=3.8729833462074170f;
  Ye[0] = 1.f;
  Ye[1] = s3*y; Ye[2] = s3*z; Ye[3] = s3*x;
  Ye[4] = s15*x*y; Ye[5] = s15*y*z; Ye[6] = 0.5f*s5*(3.f*z*z-1.f);
  Ye[7] = s15*x*z; Ye[8] = 0.5f*s15*(x*x - y*y);
  const float c1=2.0916500663351889f, c2=10.246950765959598f, c3=1.6201851746019649f, c4=1.3228756555322954f;
  Ye[9]  = c1*y*(3.f*x*x - y*y);
  Ye[10] = c2*x*y*z;
  Ye[11] = c3*y*(5.f*z*z - 1.f);
  Ye[12] = c4*z*(5.f*z*z - 3.f);
  Ye[13] = c3*x*(5.f*z*z - 1.f);
  Ye[14] = 0.5f*c2*z*(x*x - y*y);
  Ye[15] = c1*x*(x*x - 3.f*y*y);
}

// ---------------- MFMA bf16 GEMM with global_load_lds staging ------------------
template<int NT, typename TC, bool SILU, bool CUT, bool HASA2>
__global__ __launch_bounds__(256) void gemm_mfma(
    const unsigned short* __restrict__ A, int lda, int K1,
    const float* __restrict__ A2, int lda2,
    const unsigned short* __restrict__ WT, int ldw,
    TC* __restrict__ C, int ldc,
    const float* __restrict__ cutv,
    int N, int K, float scale)
{
  constexpr int NB = NT/16;
  __shared__ s8v As8[128*8];
  __shared__ s8v Bs8[NT*8];
  const int tid = threadIdx.x;
  const int wid = tid >> 6, lane = tid & 63;
  const int r15 = lane & 15, kg = lane >> 4;
  const int col0 = blockIdx.x * NT;
  const int row0 = blockIdx.y * 128;
  f4v acc[2][NB] = {};

  auto compute = [&](){
    #pragma unroll
    for (int s = 0; s < 2; s++) {
      const int cb = s*4 + kg;
      const int cx = cb ^ (r15 & 7);
      s8v a0 = As8[(wid*32      + r15)*8 + cx];
      s8v a1 = As8[(wid*32 + 16 + r15)*8 + cx];
      #pragma unroll
      for (int j = 0; j < NB; j++) {
        s8v b = Bs8[(j*16 + r15)*8 + cx];
        acc[0][j] = __builtin_amdgcn_mfma_f32_16x16x32_bf16(a0, b, acc[0][j], 0,0,0);
        acc[1][j] = __builtin_amdgcn_mfma_f32_16x16x32_bf16(a1, b, acc[1][j], 0,0,0);
      }
    }
  };

  const int Kfull = HASA2 ? K1 : K;     // K1 is a multiple of 64 when HASA2
  for (int k0 = 0; k0 < Kfull; k0 += 64) {
    #pragma unroll
    for (int i = 0; i < 4; i++) {       // A tile: 1024 segs of 16B
      int seg = i*256 + tid;
      int r = seg >> 3, ks = seg & 7;
      int ksx = ks ^ (r & 7);
      gl16(A + (size_t)(row0+r)*lda + k0 + ksx*8, &As8[i*256 + (tid & ~63)]);
    }
    #pragma unroll
    for (int i = 0; i < NT/32; i++) {   // B tile: NT*8 segs
      int seg = i*256 + tid;
      int n = seg >> 3, ks = seg & 7;
      int ksx = ks ^ (n & 7);
      gl16(WT + (size_t)(col0+n)*ldw + k0 + ksx*8, &Bs8[i*256 + (tid & ~63)]);
    }
    __syncthreads();
    compute();
    __syncthreads();
  }
  if (HASA2 && Kfull < K) {             // fp32 concat tail (one K-step)
    #pragma unroll
    for (int i = 0; i < 4; i++) {       // A tail: VGPR-staged, swizzled slot
      int seg = i*256 + tid;
      int r = seg >> 3, ks = seg & 7;
      int cl = ks ^ (r & 7);            // logical col block
      s8v val = {};
      #pragma unroll
      for (int j = 0; j < 8; j++) {
        int kk = cl*8 + j;              // col within tail
        if (K1 + kk < K) val[j] = (short)f2b(A2[(size_t)(row0+r)*lda2 + kk]);
      }
      As8[seg] = val;
    }
    #pragma unroll
    for (int i = 0; i < NT/32; i++) {   // B tail async (overrun reads benign)
      int seg = i*256 + tid;
      int n = seg >> 3, ks = seg & 7;
      int ksx = ks ^ (n & 7);
      gl16(WT + (size_t)(col0+n)*ldw + K1 + ksx*8, &Bs8[i*256 + (tid & ~63)]);
    }
    __syncthreads();
    compute();
  }
  // epilogue: C/D layout col = lane&15, row = (lane>>4)*4 + j
  #pragma unroll
  for (int g=0; g<2; g++) {
    #pragma unroll
    for (int c=0; c<NB; c++) {
      int col = col0 + c*16 + r15;
      if (col >= N) continue;
      #pragma unroll
      for (int j=0;j<4;j++) {
        int row = row0 + wid*32 + g*16 + kg*4 + j;
        float v = acc[g][c][j] * scale;
        if (SILU) v = v / (1.f + __expf(-v));
        if (CUT)  v *= cutv[row];
        stC(&C[(size_t)row*ldc + col], v);
      }
    }
  }
}

// ---------------- V init: V[e][m][kk] = wi[e][l(kk)*32+m] * Y[e][kk] ------------
__global__ __launch_bounds__(256) void vbuild(
    const unsigned short* __restrict__ wi, const float* __restrict__ Y,
    unsigned short* __restrict__ V, int count)
{
  size_t t = (size_t)blockIdx.x*256 + threadIdx.x;
  if (t >= (size_t)count*512) return;
  int e = (int)(t >> 9); int j = (int)(t & 511);
  int m = j >> 4, kk = j & 15;
  int l = (kk>=9)?3:((kk>=4)?2:((kk>=1)?1:0));
  V[t] = f2b(b2f(wi[(size_t)e*128 + l*32 + m]) * Y[(size_t)e*16 + kk]);
}

// ---------------- segment_sum scatter ----------------
__global__ __launch_bounds__(256) void scatter_env(
    const float* __restrict__ w, const float* __restrict__ Y,
    const int* __restrict__ rcv, float* __restrict__ nenv, int E)
{
  size_t t = (size_t)blockIdx.x*256 + threadIdx.x;
  if (t >= (size_t)E*512) return;
  int e = (int)(t >> 9); int j = (int)(t & 511);
  int m = j >> 4, kk = j & 15;
  float val = w[(size_t)e*32 + m] * Y[(size_t)e*16 + kk];
  atomicAdd(&nenv[(size_t)rcv[e]*512 + j], val);
}

// ------------ fused tensor product + V-mix (layer 0; packed f32) ----------------
__global__ __launch_bounds__(256, 2) void tp_mix(
    const float* __restrict__ nenv, const int* __restrict__ senders,
    unsigned short* __restrict__ V,
    const float* __restrict__ wm,     // layer slice: [4][32][32]
    float* __restrict__ t0, int E)
{
  __shared__ float Ts[8][32][18];     // pitch 18: f2v-aligned rows, 2-way bank (free)
  const int tid = threadIdx.x;
  const int le = tid >> 5, m = tid & 31;
  const int e = blockIdx.x*8 + le;
  const int s = senders[e];
  float env[16], v[16];
  f2v acc2[8];
  const float4* ne4 = (const float4*)(nenv + (size_t)s*512 + (size_t)m*16);
  #pragma unroll
  for (int q=0;q<4;q++){
    float4 f = ne4[q];
    env[q*4]=f.x; env[q*4+1]=f.y; env[q*4+2]=f.z; env[q*4+3]=f.w;
  }
  const s8v* vv = (const s8v*)(V + (size_t)e*512 + (size_t)m*16);
  s8v v0 = vv[0], v1 = vv[1];
  #pragma unroll
  for (int q=0;q<8;q++){ v[q] = b2f((unsigned short)v0[q]); v[8+q] = b2f((unsigned short)v1[q]); }
  #pragma unroll
  for (int k=0;k<8;k++){ acc2[k][0] = 0.f; acc2[k][1] = 0.f; }

  tp_tri2<0,0,0>(env,v,acc2); tp_tri2<0,1,1>(env,v,acc2); tp_tri2<0,2,2>(env,v,acc2); tp_tri2<0,3,3>(env,v,acc2);
  tp_tri2<1,0,1>(env,v,acc2); tp_tri2<1,1,0>(env,v,acc2); tp_tri2<1,1,1>(env,v,acc2); tp_tri2<1,1,2>(env,v,acc2);
  tp_tri2<1,2,1>(env,v,acc2); tp_tri2<1,2,2>(env,v,acc2); tp_tri2<1,2,3>(env,v,acc2); tp_tri2<1,3,2>(env,v,acc2);
  tp_tri2<1,3,3>(env,v,acc2);
  tp_tri2<2,0,2>(env,v,acc2); tp_tri2<2,1,1>(env,v,acc2); tp_tri2<2,1,2>(env,v,acc2); tp_tri2<2,1,3>(env,v,acc2);
  tp_tri2<2,2,0>(env,v,acc2); tp_tri2<2,2,1>(env,v,acc2); tp_tri2<2,2,2>(env,v,acc2); tp_tri2<2,2,3>(env,v,acc2);
  tp_tri2<2,3,1>(env,v,acc2); tp_tri2<2,3,2>(env,v,acc2); tp_tri2<2,3,3>(env,v,acc2);
  tp_tri2<3,0,3>(env,v,acc2); tp_tri2<3,1,2>(env,v,acc2); tp_tri2<3,1,3>(env,v,acc2); tp_tri2<3,2,1>(env,v,acc2);
  tp_tri2<3,2,2>(env,v,acc2); tp_tri2<3,2,3>(env,v,acc2); tp_tri2<3,3,0>(env,v,acc2); tp_tri2<3,3,1>(env,v,acc2);
  tp_tri2<3,3,2>(env,v,acc2); tp_tri2<3,3,3>(env,v,acc2);

  t0[(size_t)e*32 + m] = acc2[0][0];  // TN3 folded into W3V

  // stash T row, then mix: V'[n][k] = (1/sqrt32) sum_m T[m][k] wm[l(k)][m][n]
  f2v* tsrow = (f2v*)Ts[le][m];
  #pragma unroll
  for (int kp=0;kp<8;kp++) tsrow[kp] = acc2[kp];
  __syncthreads();
  f2v o2[8];
  #pragma unroll
  for (int kp=0;kp<8;kp++){ o2[kp][0]=0.f; o2[kp][1]=0.f; }
  #pragma unroll
  for (int mm=0; mm<32; mm++) {
    float w0 = wm[        mm*32 + m];
    float w1 = wm[1024 +  mm*32 + m];
    float w2 = wm[2048 +  mm*32 + m];
    float w3 = wm[3072 +  mm*32 + m];
    const f2v* tr = (const f2v*)Ts[le][mm];
    // LOFK pairs: (0,1)(1,1)(2,2)(2,2)(2,3)(3,3)(3,3)(3,3)
    f2v p01; p01[0]=w0; p01[1]=w1;
    f2v p11; p11[0]=w1; p11[1]=w1;
    f2v p22; p22[0]=w2; p22[1]=w2;
    f2v p23; p23[0]=w2; p23[1]=w3;
    f2v p33; p33[0]=w3; p33[1]=w3;
    o2[0] += tr[0]*p01; o2[1] += tr[1]*p11; o2[2] += tr[2]*p22; o2[3] += tr[3]*p22;
    o2[4] += tr[4]*p23; o2[5] += tr[5]*p33; o2[6] += tr[6]*p33; o2[7] += tr[7]*p33;
  }
  s8v oa, ob;
  #pragma unroll
  for (int kp=0;kp<4;kp++){
    oa[2*kp]   = (short)f2b(o2[kp][0]   * 0.17677669529663689f); // 1/sqrt(32)
    oa[2*kp+1] = (short)f2b(o2[kp][1]   * 0.17677669529663689f);
    ob[2*kp]   = (short)f2b(o2[4+kp][0] * 0.17677669529663689f);
    ob[2*kp+1] = (short)f2b(o2[4+kp][1] * 0.17677669529663689f);
  }
  s8v* vo = (s8v*)(V + (size_t)e*512 + (size_t)m*16);
  vo[0] = oa; vo[1] = ob;
}

// ------------ last-layer TP: only l3=0 survives (feeds the latent concat) -------
__global__ __launch_bounds__(256) void tp_last(
    const float* __restrict__ nenv, const int* __restrict__ senders,
    const unsigned short* __restrict__ V, float* __restrict__ t0, int E)
{
  int t = blockIdx.x*256 + threadIdx.x;
  int e = t >> 5, m = t & 31;
  if (e >= E) return;
  int s = senders[e];
  float env[16], v[16], acc[16];
  const float4* ne4 = (const float4*)(nenv + (size_t)s*512 + (size_t)m*16);
  #pragma unroll
  for (int q=0;q<4;q++){
    float4 f = ne4[q];
    env[q*4]=f.x; env[q*4+1]=f.y; env[q*4+2]=f.z; env[q*4+3]=f.w;
  }
  const s8v* vv = (const s8v*)(V + (size_t)e*512 + (size_t)m*16);
  s8v v0 = vv[0], v1 = vv[1];
  #pragma unroll
  for (int q=0;q<8;q++){ v[q] = b2f((unsigned short)v0[q]); v[8+q] = b2f((unsigned short)v1[q]); }
  #pragma unroll
  for (int k=0;k<16;k++) acc[k] = 0.f;
  tp_tri<0,0,0>(env,v,acc); tp_tri<1,1,0>(env,v,acc);
  tp_tri<2,2,0>(env,v,acc); tp_tri<3,3,0>(env,v,acc);
  t0[(size_t)e*32 + m] = acc[0];
}

// ---------------- output: out[e] = (1/sqrt(512)) * dot(x[e], wout) --------------
__global__ __launch_bounds__(256) void out_kernel(
    const unsigned short* __restrict__ x, const float* __restrict__ wout,
    float* __restrict__ out, int E)
{
  int gw = (blockIdx.x*256 + threadIdx.x) >> 6;
  int lane = threadIdx.x & 63;
  if (gw >= E) return;
  const s8v* xr = (const s8v*)(x + (size_t)gw*512);
  s8v chunk = xr[lane];
  float s = 0.f;
  #pragma unroll
  for (int j=0;j<8;j++) s += b2f((unsigned short)chunk[j]) * wout[lane*8 + j];
  #pragma unroll
  for (int off=32; off; off>>=1) s += __shfl_down(s, off);
  if (lane == 0) out[gw] = s * 0.044194173824159216f; // 1/sqrt(512)
}

// ---------------- workspace sizing ----------------
static inline size_t alup(size_t b){ return (b + 255) & ~(size_t)255; }
static size_t need_bytes(int E, int N, int chd){
  size_t s = 0;
  s += alup((size_t)E*16*4);            // Yb
  s += alup((size_t)E*4);               // cutb
  s += alup((size_t)E*32*4);            // wbuf
  s += alup((size_t)E*32*4);            // t0b
  s += alup((size_t)N*512*4);           // nenv
  s += alup((size_t)E*64*2);            // feat (padded to 64)
  s += alup((size_t)chd*512*2);         // cbuf
  s += alup((size_t)E*512*2);           // Vb
  s += alup((size_t)E*512*2);           // xb
  s += alup((size_t)512*64*2);          // we0T
  s += alup((size_t)512*512*2);         // we1T
  s += alup((size_t)128*512*2);         // winitT
  s += alup((size_t)2*32*512*2);        // wenvT
  s += alup((size_t)2*512*544*2);       // wlat0T
  s += alup((size_t)2*512*512*2);       // wlat1T
  return s;
}

// ---------------- launch ----------------
extern "C" void kernel_launch(void* const* d_in, const int* in_sizes, int n_in,
                              void* d_out, int out_size, void* d_ws, size_t ws_size,
                              hipStream_t stream)
{
  const float* node_attrs = (const float*)d_in[0];
  const float* vectors    = (const float*)d_in[1];
  const float* we0        = (const float*)d_in[2];
  const float* we1        = (const float*)d_in[3];
  const float* winit      = (const float*)d_in[4];
  const float* wenv       = (const float*)d_in[5];
  const float* wlat0      = (const float*)d_in[6];
  const float* wlat1      = (const float*)d_in[7];
  const float* wmix       = (const float*)d_in[8];
  const float* wout       = (const float*)d_in[9];
  const int*   senders    = (const int*)d_in[10];
  const int*   receivers  = (const int*)d_in[11];
  float* out = (float*)d_out;
  const int E = in_sizes[1] / 3;
  const int N = in_sizes[0] / 16;

  int CHD;
  if (need_bytes(E, N, E) <= ws_size)        CHD = E;     // unchunked GEMMs
  else if (need_bytes(E, N, CH) <= ws_size)  CHD = CH;    // chunked transients
  else return;                                            // diagnostic clean fail

  char* base = (char*)d_ws;
  size_t off = 0;
  auto carve = [&](size_t b) -> char* { char* p = base + off; off += alup(b); return p; };
  float*          Yb    = (float*)carve((size_t)E*16*4);
  float*          cutb  = (float*)carve((size_t)E*4);
  float*          wbuf  = (float*)carve((size_t)E*32*4);
  float*          t0b   = (float*)carve((size_t)E*32*4);
  float*          nenv  = (float*)carve((size_t)N*512*4);
  unsigned short* feat  = (unsigned short*)carve((size_t)E*64*2);
  unsigned short* cbuf  = (unsigned short*)carve((size_t)CHD*512*2);
  unsigned short* Vb    = (unsigned short*)carve((size_t)E*512*2);
  unsigned short* xb    = (unsigned short*)carve((size_t)E*512*2);
  unsigned short* we0T  = (unsigned short*)carve((size_t)512*64*2);
  unsigned short* we1T  = (unsigned short*)carve((size_t)512*512*2);
  unsigned short* winT  = (unsigned short*)carve((size_t)128*512*2);
  unsigned short* wenvT = (unsigned short*)carve((size_t)2*32*512*2);
  unsigned short* wl0T  = (unsigned short*)carve((size_t)2*512*544*2);
  unsigned short* wl1T  = (unsigned short*)carve((size_t)2*512*512*2);

  const float rs40  = 0.15811388300841897f;  // 1/sqrt(40)
  const float rs512 = 0.044194173824159216f; // 1/sqrt(512)
  const float rs544 = 0.042874646285627205f; // 1/sqrt(544)

  dim3 blk(256);
  wconv<<<(512*64+255)/256, blk, 0, stream>>>(we0, we0T, 40, 512, 64);
  wconv<<<(512*512+255)/256, blk, 0, stream>>>(we1, we1T, 512, 512, 512);
  wconv<<<(128*512+255)/256, blk, 0, stream>>>(winit, winT, 512, 128, 512);
  for (int l=0;l<2;l++){
    wconv<<<(32*512+255)/256, blk, 0, stream>>>(wenv + (size_t)l*512*32, wenvT + (size_t)l*32*512, 512, 32, 512);
    wconv<<<(512*544+255)/256, blk, 0, stream>>>(wlat0 + (size_t)l*544*512, wl0T + (size_t)l*512*544, 544, 512, 544);
    wconv<<<(512*512+255)/256, blk, 0, stream>>>(wlat1 + (size_t)l*512*512, wl1T + (size_t)l*512*512, 512, 512, 512);
  }
  edge_init<<<E/256, blk, 0, stream>>>(vectors, node_attrs, senders, receivers, feat, Yb, cutb, E);

  // edge embedding MLP + V init
  for (int c0 = 0; c0 < E; c0 += CHD) {
    gemm_mfma<128,unsigned short,true,false,false><<<dim3(4, CHD/128), blk, 0, stream>>>(
        feat + (size_t)c0*64, 64, 64, nullptr, 0, we0T, 64, cbuf, 512, nullptr, 512, 64, rs40);
    gemm_mfma<128,unsigned short,false,true,false><<<dim3(4, CHD/128), blk, 0, stream>>>(
        cbuf, 512, 512, nullptr, 0, we1T, 512, xb + (size_t)c0*512, 512, cutb + c0, 512, 512, rs512);
    gemm_mfma<128,unsigned short,false,false,false><<<dim3(1, CHD/128), blk, 0, stream>>>(
        xb + (size_t)c0*512, 512, 512, nullptr, 0, winT, 512, cbuf, 128, nullptr, 128, 512, rs512);
    vbuild<<<(CHD*512)/256, blk, 0, stream>>>(cbuf, Yb + (size_t)c0*16, Vb + (size_t)c0*512, CHD);
  }

  for (int layer = 0; layer < 2; ++layer) {
    // w = x @ wenv, with 1/sqrt(AVG_NEIGH)=0.25 folded in
    gemm_mfma<64,float,false,false,false><<<dim3(1, E/128), blk, 0, stream>>>(
        xb, 512, 512, nullptr, 0, wenvT + (size_t)layer*32*512, 512, wbuf, 32, nullptr, 32, 512, rs512*0.25f);
    hipMemsetAsync(nenv, 0, (size_t)N*512*4, stream);
    scatter_env<<<(int)(((size_t)E*512)/256), blk, 0, stream>>>(wbuf, Yb, receivers, nenv, E);
    if (layer == 0)
      tp_mix<<<E/8, blk, 0, stream>>>(nenv, senders, Vb,
          wmix + (size_t)layer*4*32*32, t0b, E);
    else
      tp_last<<<(E*32)/256, blk, 0, stream>>>(nenv, senders, Vb, t0b, E);
    for (int c0 = 0; c0 < E; c0 += CHD) {
      gemm_mfma<128,unsigned short,true,false,true><<<dim3(4, CHD/128), blk, 0, stream>>>(
          xb + (size_t)c0*512, 512, 512, t0b + (size_t)c0*32, 32,
          wl0T + (size_t)layer*512*544, 544, cbuf, 512, nullptr, 512, 544, rs544);
      gemm_mfma<128,unsigned short,false,true,false><<<dim3(4, CHD/128), blk, 0, stream>>>(
          cbuf, 512, 512, nullptr, 0, wl1T + (size_t)layer*512*512, 512,
          xb + (size_t)c0*512, 512, cutb + c0, 512, 512, rs512);
    }
  }

  out_kernel<<<E/4, blk, 0, stream>>>(xb, wout, out, E);
}

// Round 9
// 803.573 us; speedup vs baseline: 12.2688x; 1.1701x over previous
//
#include <hip/hip_runtime.h>
#include <math.h>

typedef __attribute__((ext_vector_type(8))) short s8v;   // 8 bf16 (4 VGPR)
typedef __attribute__((ext_vector_type(4))) float f4v;   // MFMA acc
typedef __attribute__((ext_vector_type(2))) float f2v;   // packed f32 pair

#define CH 8192

// ---------------- bf16 bit helpers ----------------
__device__ inline float b2f(unsigned short u){ return __uint_as_float(((unsigned)u)<<16); }
__device__ inline unsigned short f2b(float f){
  unsigned u = __float_as_uint(f);
  return (unsigned short)((u + 0x7FFFu + ((u>>16)&1u)) >> 16);   // RNE
}
__device__ inline void stC(float* p, float v){ *p = v; }
__device__ inline void stC(unsigned short* p, float v){ *p = f2b(v); }

// async global->LDS, 16B per lane; lds base must be wave-uniform
__device__ __forceinline__ void gl16(const void* g, void* l){
  __builtin_amdgcn_global_load_lds(
      (const __attribute__((address_space(1))) unsigned*)g,
      (__attribute__((address_space(3))) unsigned*)l, 16, 0, 0);
}

// ================= compile-time real Wigner (CG) tables =================
constexpr double FCT[11] = {1.,1.,2.,6.,24.,120.,720.,5040.,40320.,362880.,3628800.};
constexpr double csqrt_c(double x){
  double g = x > 1.0 ? x : 1.0;
  for (int i=0;i<60;i++) g = 0.5*(g + x/g);
  return g;
}
struct CD { double re, im; };
constexpr CD cmulc(CD a, CD b){ return {a.re*b.re - a.im*b.im, a.re*b.im + a.im*b.re}; }

constexpr double su2cg_c(int j1,int j2,int j3,int m1,int m2,int m3){
  if (m1+m2 != m3) return 0.0;
  double pref = csqrt_c((double)(2*j3+1) * FCT[j1+j2-j3]*FCT[j1-j2+j3]*FCT[-j1+j2+j3]/FCT[j1+j2+j3+1]
              * FCT[j3+m3]*FCT[j3-m3]*FCT[j1-m1]*FCT[j1+m1]*FCT[j2-m2]*FCT[j2+m2]);
  int kmin = 0;
  if (j2-j3-m1 > kmin) kmin = j2-j3-m1;
  if (j1-j3+m2 > kmin) kmin = j1-j3+m2;
  int kmax = j1+j2-j3;
  if (j1-m1 < kmax) kmax = j1-m1;
  if (j2+m2 < kmax) kmax = j2+m2;
  double s = 0.0;
  for (int k=kmin;k<=kmax;k++){
    double t = 1.0/(FCT[k]*FCT[j1+j2-j3-k]*FCT[j1-m1-k]*FCT[j2+m2-k]*FCT[j3-j2+m1+k]*FCT[j3-j1-m2+k]);
    s += (k&1) ? -t : t;
  }
  return pref*s;
}

constexpr CD qelem_c(int l, int i, int j){
  int m = i - l;
  const double is2 = 0.70710678118654752440;
  double re=0.0, im=0.0;
  if (m < 0){
    if (j == l - m) re = is2;
    else if (j == l + m) im = -is2;
  } else if (m == 0){
    if (j == l) re = 1.0;
  } else {
    double sgn = (m & 1) ? -1.0 : 1.0;
    if (j == l + m) re = sgn*is2;
    else if (j == l - m) im = sgn*is2;
  }
  CD r{};
  switch (l & 3){                    // (-i)^l
    case 0: r = {re, im}; break;
    case 1: r = {im, -re}; break;
    case 2: r = {-re, -im}; break;
    default: r = {-im, re}; break;
  }
  return r;
}

// path-count normalization per l3: n = {4,9,11,10}
constexpr double TN3[4] = {0.5, 1.0/3.0, 0.30151134457776363, 0.31622776601683794};

template<int L1,int L2,int L3>
struct TriVals { float v[(2*L1+1)*(2*L2+1)*(2*L3+1)]; };

template<int L1,int L2,int L3>
constexpr TriVals<L1,L2,L3> make_tri(){
  constexpr int n1=2*L1+1, n2=2*L2+1, n3=2*L3+1;
  double cg[n1*n2*n3] = {};
  for (int a=0;a<n1;a++)
    for (int b=0;b<n2;b++)
      for (int c=0;c<n3;c++)
        cg[(a*n2+b)*n3+c] = su2cg_c(L1,L2,L3, a-L1, b-L2, c-L3);
  double cr[n1*n2*n3] = {};
  double ci[n1*n2*n3] = {};
  for (int i=0;i<n1;i++)
   for (int j=0;j<n2;j++)
    for (int k=0;k<n3;k++){
      double sre=0.0, sim=0.0;
      for (int a=0;a<n1;a++){
        CD q1 = qelem_c(L1,i,a);
        if (q1.re==0.0 && q1.im==0.0) continue;
        for (int b=0;b<n2;b++){
          CD q2 = qelem_c(L2,j,b);
          if (q2.re==0.0 && q2.im==0.0) continue;
          CD q12 = cmulc(q1,q2);
          for (int c=0;c<n3;c++){
            double g = cg[(a*n2+b)*n3+c];
            if (g == 0.0) continue;
            CD q3 = qelem_c(L3,k,c);
            CD q3c{q3.re, -q3.im};
            CD q = cmulc(q12,q3c);
            sre += q.re*g; sim += q.im*g;
          }
        }
      }
      cr[(i*n2+j)*n3+k]=sre; ci[(i*n2+j)*n3+k]=sim;
    }
  double nr=0.0, ni=0.0;
  for (int i=0;i<n1*n2*n3;i++){ nr += cr[i]*cr[i]; ni += ci[i]*ci[i]; }
  bool pr = nr >= ni;
  double nn = csqrt_c(pr ? nr : ni);
  TriVals<L1,L2,L3> t{};
  for (int i=0;i<n1*n2*n3;i++)
    t.v[i] = (float)(((pr ? cr[i] : ci[i]) / nn) * TN3[L3]);
  return t;
}

template<int L1,int L2,int L3>
constexpr TriVals<L1,L2,L3> W3V = make_tri<L1,L2,L3>();

constexpr int LOFFC[4] = {0,1,4,9};

// bounds-checked compile-time getter (folds after unroll)
template<int L1,int L2,int L3>
__device__ __forceinline__ constexpr float w3get(int k1,int k2,int k3){
  constexpr int n2=2*L2+1, n3=2*L3+1;
  if (k3 < 0 || k3 >= n3) return 0.f;
  return W3V<L1,L2,L3>.v[(k1*n2+k2)*n3+k3];
}

// scalar variant (used by tp_last's 4 l3=0 triples)
template<int L1,int L2,int L3>
__device__ __forceinline__ void tp_tri(const float* __restrict__ env,
                                       const float* __restrict__ v,
                                       float* __restrict__ acc){
  constexpr int n1=2*L1+1, n2=2*L2+1, n3=2*L3+1;
  #pragma unroll
  for (int k1=0;k1<n1;k1++)
    #pragma unroll
    for (int k2=0;k2<n2;k2++){
      float p = env[LOFFC[L1]+k1] * v[LOFFC[L2]+k2];
      #pragma unroll
      for (int k3=0;k3<n3;k3++){
        float w = W3V<L1,L2,L3>.v[(k1*n2+k2)*n3+k3];
        if (w != 0.f) acc[LOFFC[L3]+k3] += w * p;
      }
    }
}

// packed variant: acc as 8x float2 over absolute k index
template<int L1,int L2,int L3>
__device__ __forceinline__ void tp_tri2(const float* __restrict__ env,
                                        const float* __restrict__ v,
                                        f2v* __restrict__ acc2){
  constexpr int n1=2*L1+1, n2=2*L2+1, o3=LOFFC[L3];
  #pragma unroll
  for (int k1=0;k1<n1;k1++)
    #pragma unroll
    for (int k2=0;k2<n2;k2++){
      float p = env[LOFFC[L1]+k1] * v[LOFFC[L2]+k2];
      #pragma unroll
      for (int kp=0; kp<8; kp++){
        float wlo = w3get<L1,L2,L3>(k1,k2, 2*kp   - o3);
        float whi = w3get<L1,L2,L3>(k1,k2, 2*kp+1 - o3);
        if (wlo != 0.f || whi != 0.f){
          f2v w2; w2[0]=wlo; w2[1]=whi;
          f2v p2; p2[0]=p;  p2[1]=p;
          acc2[kp] += w2 * p2;       // -ffp-contract -> v_pk_fma_f32
        }
      }
    }
}

// ---------------- weight convert+transpose: WT[n][k] = bf16(W[k][n]) ----------
__global__ __launch_bounds__(256) void wconv(
    const float* __restrict__ W, unsigned short* __restrict__ WT,
    int K, int N, int Kpad)
{
  int idx = blockIdx.x*256 + threadIdx.x;
  if (idx >= N*Kpad) return;
  int n = idx / Kpad, k = idx - n*Kpad;
  WT[idx] = (k < K) ? f2b(W[(size_t)k*N + n]) : (unsigned short)0;
}

// ---------------- edge geometry: feat64(bf16, zero-padded), Y, cut -------------
__global__ __launch_bounds__(256) void edge_init(
    const float* __restrict__ vec, const float* __restrict__ na,
    const int* __restrict__ snd, const int* __restrict__ rcv,
    unsigned short* __restrict__ feat, float* __restrict__ Y, float* __restrict__ cutb, int E)
{
  int e = blockIdx.x*256 + threadIdx.x;
  if (e >= E) return;
  float vx = vec[(size_t)e*3], vy = vec[(size_t)e*3+1], vz = vec[(size_t)e*3+2];
  float d = sqrtf(vx*vx + vy*vy + vz*vz);
  float inv = 1.f/(d + 1e-9f);
  float x = vx*inv, y = vy*inv, z = vz*inv;
  float dc = d * 0.4f;               // d / 2.5
  float dci = 1.f/(dc + 1e-9f);
  unsigned short* f = feat + (size_t)e*64;
  #pragma unroll
  for (int k=1;k<=8;k++)
    f[k-1] = f2b(1.41421356237309515f * sinf(dc * 3.14159265358979323846f * k) * dci);
  int s = snd[e], r = rcv[e];
  #pragma unroll
  for (int i=0;i<16;i++) f[8+i]  = f2b(na[(size_t)s*16+i]);
  #pragma unroll
  for (int i=0;i<16;i++) f[24+i] = f2b(na[(size_t)r*16+i]);
  #pragma unroll
  for (int i=40;i<64;i++) f[i] = 0;
  float cv = 0.f;
  if (dc < 1.f){
    float d2 = dc*dc; float d6 = d2*d2*d2; float d7 = d6*dc; float d8 = d7*dc;
    cv = 1.f - 28.f*d6 + 48.f*d7 - 21.f*d8;
  }
  cutb[e] = cv;
  float* Ye = Y + (size_t)e*16;
  const float s3=1.7320508075688772f, s5=2.2360679774997896f, s15=3.8729833462074170f;
  Ye[0] = 1.f;
  Ye[1] = s3*y; Ye[2] = s3*z; Ye[3] = s3*x;
  Ye[4] = s15*x*y; Ye[5] = s15*y*z; Ye[6] = 0.5f*s5*(3.f*z*z-1.f);
  Ye[7] = s15*x*z; Ye[8] = 0.5f*s15*(x*x - y*y);
  const float c1=2.0916500663351889f, c2=10.246950765959598f, c3=1.6201851746019649f, c4=1.3228756555322954f;
  Ye[9]  = c1*y*(3.f*x*x - y*y);
  Ye[10] = c2*x*y*z;
  Ye[11] = c3*y*(5.f*z*z - 1.f);
  Ye[12] = c4*z*(5.f*z*z - 3.f);
  Ye[13] = c3*x*(5.f*z*z - 1.f);
  Ye[14] = 0.5f*c2*z*(x*x - y*y);
  Ye[15] = c1*x*(x*x - 3.f*y*y);
}

// ---------------- MFMA bf16 GEMM with global_load_lds staging ------------------
template<int NT, typename TC, bool SILU, bool CUT, bool HASA2>
__global__ __launch_bounds__(256) void gemm_mfma(
    const unsigned short* __restrict__ A, int lda, int K1,
    const float* __restrict__ A2, int lda2,
    const unsigned short* __restrict__ WT, int ldw,
    TC* __restrict__ C, int ldc,
    const float* __restrict__ cutv,
    int N, int K, float scale)
{
  constexpr int NB = NT/16;
  __shared__ s8v As8[128*8];
  __shared__ s8v Bs8[NT*8];
  const int tid = threadIdx.x;
  const int wid = tid >> 6, lane = tid & 63;
  const int r15 = lane & 15, kg = lane >> 4;
  const int col0 = blockIdx.x * NT;
  const int row0 = blockIdx.y * 128;
  f4v acc[2][NB] = {};

  auto compute = [&](){
    #pragma unroll
    for (int s = 0; s < 2; s++) {
      const int cb = s*4 + kg;
      const int cx = cb ^ (r15 & 7);
      s8v a0 = As8[(wid*32      + r15)*8 + cx];
      s8v a1 = As8[(wid*32 + 16 + r15)*8 + cx];
      #pragma unroll
      for (int j = 0; j < NB; j++) {
        s8v b = Bs8[(j*16 + r15)*8 + cx];
        acc[0][j] = __builtin_amdgcn_mfma_f32_16x16x32_bf16(a0, b, acc[0][j], 0,0,0);
        acc[1][j] = __builtin_amdgcn_mfma_f32_16x16x32_bf16(a1, b, acc[1][j], 0,0,0);
      }
    }
  };

  const int Kfull = HASA2 ? K1 : K;     // K1 is a multiple of 64 when HASA2
  for (int k0 = 0; k0 < Kfull; k0 += 64) {
    #pragma unroll
    for (int i = 0; i < 4; i++) {       // A tile: 1024 segs of 16B
      int seg = i*256 + tid;
      int r = seg >> 3, ks = seg & 7;
      int ksx = ks ^ (r & 7);
      gl16(A + (size_t)(row0+r)*lda + k0 + ksx*8, &As8[i*256 + (tid & ~63)]);
    }
    #pragma unroll
    for (int i = 0; i < NT/32; i++) {   // B tile: NT*8 segs
      int seg = i*256 + tid;
      int n = seg >> 3, ks = seg & 7;
      int ksx = ks ^ (n & 7);
      gl16(WT + (size_t)(col0+n)*ldw + k0 + ksx*8, &Bs8[i*256 + (tid & ~63)]);
    }
    __syncthreads();
    compute();
    __syncthreads();
  }
  if (HASA2 && Kfull < K) {             // fp32 concat tail (one K-step)
    #pragma unroll
    for (int i = 0; i < 4; i++) {       // A tail: VGPR-staged, swizzled slot
      int seg = i*256 + tid;
      int r = seg >> 3, ks = seg & 7;
      int cl = ks ^ (r & 7);            // logical col block
      s8v val = {};
      #pragma unroll
      for (int j = 0; j < 8; j++) {
        int kk = cl*8 + j;              // col within tail
        if (K1 + kk < K) val[j] = (short)f2b(A2[(size_t)(row0+r)*lda2 + kk]);
      }
      As8[seg] = val;
    }
    #pragma unroll
    for (int i = 0; i < NT/32; i++) {   // B tail async (overrun reads benign)
      int seg = i*256 + tid;
      int n = seg >> 3, ks = seg & 7;
      int ksx = ks ^ (n & 7);
      gl16(WT + (size_t)(col0+n)*ldw + K1 + ksx*8, &Bs8[i*256 + (tid & ~63)]);
    }
    __syncthreads();
    compute();
  }
  // epilogue: C/D layout col = lane&15, row = (lane>>4)*4 + j
  #pragma unroll
  for (int g=0; g<2; g++) {
    #pragma unroll
    for (int c=0; c<NB; c++) {
      int col = col0 + c*16 + r15;
      if (col >= N) continue;
      #pragma unroll
      for (int j=0;j<4;j++) {
        int row = row0 + wid*32 + g*16 + kg*4 + j;
        float v = acc[g][c][j] * scale;
        if (SILU) v = v / (1.f + __expf(-v));
        if (CUT)  v *= cutv[row];
        stC(&C[(size_t)row*ldc + col], v);
      }
    }
  }
}

// ---------------- V init: V[e][m][kk] = wi[e][l(kk)*32+m] * Y[e][kk] ------------
__global__ __launch_bounds__(256) void vbuild(
    const unsigned short* __restrict__ wi, const float* __restrict__ Y,
    unsigned short* __restrict__ V, int count)
{
  size_t t = (size_t)blockIdx.x*256 + threadIdx.x;
  if (t >= (size_t)count*512) return;
  int e = (int)(t >> 9); int j = (int)(t & 511);
  int m = j >> 4, kk = j & 15;
  int l = (kk>=9)?3:((kk>=4)?2:((kk>=1)?1:0));
  V[t] = f2b(b2f(wi[(size_t)e*128 + l*32 + m]) * Y[(size_t)e*16 + kk]);
}

// ---------------- CSR build: histogram -> scan -> fill -------------------------
__global__ __launch_bounds__(256) void hist_k(
    const int* __restrict__ rcv, int* __restrict__ deg, int E)
{
  int e = blockIdx.x*256 + threadIdx.x;
  if (e < E) atomicAdd(&deg[rcv[e]], 1);
}

// single block: exclusive scan of deg[0..Nn) -> offs (offs[Nn] = E)
__global__ __launch_bounds__(256) void scan_k(
    const int* __restrict__ deg, int* __restrict__ offs, int Nn)
{
  __shared__ int part[256];
  const int t = threadIdx.x;
  const int per = (Nn + 255) / 256;
  int base = t*per;
  int loc[32];                        // per <= 32 for Nn <= 8192
  int s = 0;
  for (int i=0;i<per;i++){ int v = (base+i<Nn)?deg[base+i]:0; loc[i]=s; s+=v; }
  part[t] = s;
  __syncthreads();
  for (int off=1; off<256; off<<=1){
    int v = (t>=off) ? part[t-off] : 0;
    __syncthreads();
    part[t] += v;
    __syncthreads();
  }
  int pre = (t==0) ? 0 : part[t-1];
  for (int i=0;i<per;i++) if (base+i<Nn) offs[base+i] = pre + loc[i];
  if (t==255) offs[Nn] = part[255];
}

__global__ __launch_bounds__(256) void fill_k(
    const int* __restrict__ rcv, int* __restrict__ cursor,
    const int* __restrict__ offs, int* __restrict__ elist, int E)
{
  int e = blockIdx.x*256 + threadIdx.x;
  if (e >= E) return;
  int r = rcv[e];
  int p = atomicAdd(&cursor[r], 1);
  elist[offs[r] + p] = e;
}

// ---------------- env build (replaces atomic scatter + memset) ------------------
// one block (512 thr) per node: nenv[n][m][kk] = sum_{e in bucket} w[e][m]*Y[e][kk]
__global__ __launch_bounds__(512) void env_build(
    const float* __restrict__ w, const float* __restrict__ Y,
    const int* __restrict__ elist, const int* __restrict__ offs,
    float* __restrict__ nenv)
{
  const int n = blockIdx.x;
  const int j = threadIdx.x;          // 0..511
  const int m = j >> 4, kk = j & 15;
  const int beg = offs[n], end = offs[n+1];
  float acc = 0.f;
  for (int p = beg; p < end; ++p) {
    int e = elist[p];
    acc += w[(size_t)e*32 + m] * Y[(size_t)e*16 + kk];
  }
  nenv[(size_t)n*512 + j] = acc;
}

// ------------ fused tensor product + V-mix (layer 0; packed f32) ----------------
__global__ __launch_bounds__(256, 2) void tp_mix(
    const float* __restrict__ nenv, const int* __restrict__ senders,
    unsigned short* __restrict__ V,
    const float* __restrict__ wm,     // layer slice: [4][32][32]
    float* __restrict__ t0, int E)
{
  __shared__ float Ts[8][32][18];     // pitch 18: f2v-aligned rows, 2-way bank (free)
  const int tid = threadIdx.x;
  const int le = tid >> 5, m = tid & 31;
  const int e = blockIdx.x*8 + le;
  const int s = senders[e];
  float env[16], v[16];
  f2v acc2[8];
  const float4* ne4 = (const float4*)(nenv + (size_t)s*512 + (size_t)m*16);
  #pragma unroll
  for (int q=0;q<4;q++){
    float4 f = ne4[q];
    env[q*4]=f.x; env[q*4+1]=f.y; env[q*4+2]=f.z; env[q*4+3]=f.w;
  }
  const s8v* vv = (const s8v*)(V + (size_t)e*512 + (size_t)m*16);
  s8v v0 = vv[0], v1 = vv[1];
  #pragma unroll
  for (int q=0;q<8;q++){ v[q] = b2f((unsigned short)v0[q]); v[8+q] = b2f((unsigned short)v1[q]); }
  #pragma unroll
  for (int k=0;k<8;k++){ acc2[k][0] = 0.f; acc2[k][1] = 0.f; }

  tp_tri2<0,0,0>(env,v,acc2); tp_tri2<0,1,1>(env,v,acc2); tp_tri2<0,2,2>(env,v,acc2); tp_tri2<0,3,3>(env,v,acc2);
  tp_tri2<1,0,1>(env,v,acc2); tp_tri2<1,1,0>(env,v,acc2); tp_tri2<1,1,1>(env,v,acc2); tp_tri2<1,1,2>(env,v,acc2);
  tp_tri2<1,2,1>(env,v,acc2); tp_tri2<1,2,2>(env,v,acc2); tp_tri2<1,2,3>(env,v,acc2); tp_tri2<1,3,2>(env,v,acc2);
  tp_tri2<1,3,3>(env,v,acc2);
  tp_tri2<2,0,2>(env,v,acc2); tp_tri2<2,1,1>(env,v,acc2); tp_tri2<2,1,2>(env,v,acc2); tp_tri2<2,1,3>(env,v,acc2);
  tp_tri2<2,2,0>(env,v,acc2); tp_tri2<2,2,1>(env,v,acc2); tp_tri2<2,2,2>(env,v,acc2); tp_tri2<2,2,3>(env,v,acc2);
  tp_tri2<2,3,1>(env,v,acc2); tp_tri2<2,3,2>(env,v,acc2); tp_tri2<2,3,3>(env,v,acc2);
  tp_tri2<3,0,3>(env,v,acc2); tp_tri2<3,1,2>(env,v,acc2); tp_tri2<3,1,3>(env,v,acc2); tp_tri2<3,2,1>(env,v,acc2);
  tp_tri2<3,2,2>(env,v,acc2); tp_tri2<3,2,3>(env,v,acc2); tp_tri2<3,3,0>(env,v,acc2); tp_tri2<3,3,1>(env,v,acc2);
  tp_tri2<3,3,2>(env,v,acc2); tp_tri2<3,3,3>(env,v,acc2);

  t0[(size_t)e*32 + m] = acc2[0][0];  // TN3 folded into W3V

  // stash T row, then mix: V'[n][k] = (1/sqrt32) sum_m T[m][k] wm[l(k)][m][n]
  f2v* tsrow = (f2v*)Ts[le][m];
  #pragma unroll
  for (int kp=0;kp<8;kp++) tsrow[kp] = acc2[kp];
  __syncthreads();
  f2v o2[8];
  #pragma unroll
  for (int kp=0;kp<8;kp++){ o2[kp][0]=0.f; o2[kp][1]=0.f; }
  #pragma unroll
  for (int mm=0; mm<32; mm++) {
    float w0 = wm[        mm*32 + m];
    float w1 = wm[1024 +  mm*32 + m];
    float w2 = wm[2048 +  mm*32 + m];
    float w3 = wm[3072 +  mm*32 + m];
    const f2v* tr = (const f2v*)Ts[le][mm];
    f2v p01; p01[0]=w0; p01[1]=w1;
    f2v p11; p11[0]=w1; p11[1]=w1;
    f2v p22; p22[0]=w2; p22[1]=w2;
    f2v p23; p23[0]=w2; p23[1]=w3;
    f2v p33; p33[0]=w3; p33[1]=w3;
    o2[0] += tr[0]*p01; o2[1] += tr[1]*p11; o2[2] += tr[2]*p22; o2[3] += tr[3]*p22;
    o2[4] += tr[4]*p23; o2[5] += tr[5]*p33; o2[6] += tr[6]*p33; o2[7] += tr[7]*p33;
  }
  s8v oa, ob;
  #pragma unroll
  for (int kp=0;kp<4;kp++){
    oa[2*kp]   = (short)f2b(o2[kp][0]   * 0.17677669529663689f); // 1/sqrt(32)
    oa[2*kp+1] = (short)f2b(o2[kp][1]   * 0.17677669529663689f);
    ob[2*kp]   = (short)f2b(o2[4+kp][0] * 0.17677669529663689f);
    ob[2*kp+1] = (short)f2b(o2[4+kp][1] * 0.17677669529663689f);
  }
  s8v* vo = (s8v*)(V + (size_t)e*512 + (size_t)m*16);
  vo[0] = oa; vo[1] = ob;
}

// ------------ last-layer TP: only l3=0 survives (feeds the latent concat) -------
__global__ __launch_bounds__(256) void tp_last(
    const float* __restrict__ nenv, const int* __restrict__ senders,
    const unsigned short* __restrict__ V, float* __restrict__ t0, int E)
{
  int t = blockIdx.x*256 + threadIdx.x;
  int e = t >> 5, m = t & 31;
  if (e >= E) return;
  int s = senders[e];
  float env[16], v[16], acc[16];
  const float4* ne4 = (const float4*)(nenv + (size_t)s*512 + (size_t)m*16);
  #pragma unroll
  for (int q=0;q<4;q++){
    float4 f = ne4[q];
    env[q*4]=f.x; env[q*4+1]=f.y; env[q*4+2]=f.z; env[q*4+3]=f.w;
  }
  const s8v* vv = (const s8v*)(V + (size_t)e*512 + (size_t)m*16);
  s8v v0 = vv[0], v1 = vv[1];
  #pragma unroll
  for (int q=0;q<8;q++){ v[q] = b2f((unsigned short)v0[q]); v[8+q] = b2f((unsigned short)v1[q]); }
  #pragma unroll
  for (int k=0;k<16;k++) acc[k] = 0.f;
  tp_tri<0,0,0>(env,v,acc); tp_tri<1,1,0>(env,v,acc);
  tp_tri<2,2,0>(env,v,acc); tp_tri<3,3,0>(env,v,acc);
  t0[(size_t)e*32 + m] = acc[0];
}

// ---------------- output: out[e] = (1/sqrt(512)) * dot(x[e], wout) --------------
__global__ __launch_bounds__(256) void out_kernel(
    const unsigned short* __restrict__ x, const float* __restrict__ wout,
    float* __restrict__ out, int E)
{
  int gw = (blockIdx.x*256 + threadIdx.x) >> 6;
  int lane = threadIdx.x & 63;
  if (gw >= E) return;
  const s8v* xr = (const s8v*)(x + (size_t)gw*512);
  s8v chunk = xr[lane];
  float s = 0.f;
  #pragma unroll
  for (int j=0;j<8;j++) s += b2f((unsigned short)chunk[j]) * wout[lane*8 + j];
  #pragma unroll
  for (int off=32; off; off>>=1) s += __shfl_down(s, off);
  if (lane == 0) out[gw] = s * 0.044194173824159216f; // 1/sqrt(512)
}

// ---------------- workspace sizing ----------------
static inline size_t alup(size_t b){ return (b + 255) & ~(size_t)255; }
static size_t need_bytes(int E, int N, int chd){
  size_t s = 0;
  s += alup((size_t)E*16*4);            // Yb
  s += alup((size_t)E*4);               // cutb
  s += alup((size_t)E*32*4);            // wbuf
  s += alup((size_t)E*32*4);            // t0b
  s += alup((size_t)N*512*4);           // nenv
  s += alup((size_t)E*64*2);            // feat (padded to 64)
  s += alup((size_t)chd*512*2);         // cbuf
  s += alup((size_t)E*512*2);           // Vb
  s += alup((size_t)E*512*2);           // xb
  s += alup((size_t)512*64*2);          // we0T
  s += alup((size_t)512*512*2);         // we1T
  s += alup((size_t)128*512*2);         // winitT
  s += alup((size_t)2*32*512*2);        // wenvT
  s += alup((size_t)2*512*544*2);       // wlat0T
  s += alup((size_t)2*512*512*2);       // wlat1T
  s += alup((size_t)N*4);               // deg
  s += alup(((size_t)N+1)*4);           // offs
  s += alup((size_t)N*4);               // cursor
  s += alup((size_t)E*4);               // elist
  return s;
}

// ---------------- launch ----------------
extern "C" void kernel_launch(void* const* d_in, const int* in_sizes, int n_in,
                              void* d_out, int out_size, void* d_ws, size_t ws_size,
                              hipStream_t stream)
{
  const float* node_attrs = (const float*)d_in[0];
  const float* vectors    = (const float*)d_in[1];
  const float* we0        = (const float*)d_in[2];
  const float* we1        = (const float*)d_in[3];
  const float* winit      = (const float*)d_in[4];
  const float* wenv       = (const float*)d_in[5];
  const float* wlat0      = (const float*)d_in[6];
  const float* wlat1      = (const float*)d_in[7];
  const float* wmix       = (const float*)d_in[8];
  const float* wout       = (const float*)d_in[9];
  const int*   senders    = (const int*)d_in[10];
  const int*   receivers  = (const int*)d_in[11];
  float* out = (float*)d_out;
  const int E = in_sizes[1] / 3;
  const int N = in_sizes[0] / 16;

  int CHD;
  if (need_bytes(E, N, E) <= ws_size)        CHD = E;     // unchunked GEMMs
  else if (need_bytes(E, N, CH) <= ws_size)  CHD = CH;    // chunked transients
  else return;                                            // diagnostic clean fail

  char* base = (char*)d_ws;
  size_t off = 0;
  auto carve = [&](size_t b) -> char* { char* p = base + off; off += alup(b); return p; };
  float*          Yb    = (float*)carve((size_t)E*16*4);
  float*          cutb  = (float*)carve((size_t)E*4);
  float*          wbuf  = (float*)carve((size_t)E*32*4);
  float*          t0b   = (float*)carve((size_t)E*32*4);
  float*          nenv  = (float*)carve((size_t)N*512*4);
  unsigned short* feat  = (unsigned short*)carve((size_t)E*64*2);
  unsigned short* cbuf  = (unsigned short*)carve((size_t)CHD*512*2);
  unsigned short* Vb    = (unsigned short*)carve((size_t)E*512*2);
  unsigned short* xb    = (unsigned short*)carve((size_t)E*512*2);
  unsigned short* we0T  = (unsigned short*)carve((size_t)512*64*2);
  unsigned short* we1T  = (unsigned short*)carve((size_t)512*512*2);
  unsigned short* winT  = (unsigned short*)carve((size_t)128*512*2);
  unsigned short* wenvT = (unsigned short*)carve((size_t)2*32*512*2);
  unsigned short* wl0T  = (unsigned short*)carve((size_t)2*512*544*2);
  unsigned short* wl1T  = (unsigned short*)carve((size_t)2*512*512*2);
  int*            deg   = (int*)carve((size_t)N*4);
  int*            offs  = (int*)carve(((size_t)N+1)*4);
  int*            cursor= (int*)carve((size_t)N*4);
  int*            elist = (int*)carve((size_t)E*4);

  const float rs40  = 0.15811388300841897f;  // 1/sqrt(40)
  const float rs512 = 0.044194173824159216f; // 1/sqrt(512)
  const float rs544 = 0.042874646285627205f; // 1/sqrt(544)

  dim3 blk(256);
  wconv<<<(512*64+255)/256, blk, 0, stream>>>(we0, we0T, 40, 512, 64);
  wconv<<<(512*512+255)/256, blk, 0, stream>>>(we1, we1T, 512, 512, 512);
  wconv<<<(128*512+255)/256, blk, 0, stream>>>(winit, winT, 512, 128, 512);
  for (int l=0;l<2;l++){
    wconv<<<(32*512+255)/256, blk, 0, stream>>>(wenv + (size_t)l*512*32, wenvT + (size_t)l*32*512, 512, 32, 512);
    wconv<<<(512*544+255)/256, blk, 0, stream>>>(wlat0 + (size_t)l*544*512, wl0T + (size_t)l*512*544, 544, 512, 544);
    wconv<<<(512*512+255)/256, blk, 0, stream>>>(wlat1 + (size_t)l*512*512, wl1T + (size_t)l*512*512, 512, 512, 512);
  }
  edge_init<<<E/256, blk, 0, stream>>>(vectors, node_attrs, senders, receivers, feat, Yb, cutb, E);

  // CSR of receivers (layer-invariant: build once)
  hipMemsetAsync(deg, 0, (size_t)N*4, stream);
  hipMemsetAsync(cursor, 0, (size_t)N*4, stream);
  hist_k<<<(E+255)/256, blk, 0, stream>>>(receivers, deg, E);
  scan_k<<<1, blk, 0, stream>>>(deg, offs, N);
  fill_k<<<(E+255)/256, blk, 0, stream>>>(receivers, cursor, offs, elist, E);

  // edge embedding MLP + V init
  for (int c0 = 0; c0 < E; c0 += CHD) {
    gemm_mfma<128,unsigned short,true,false,false><<<dim3(4, CHD/128), blk, 0, stream>>>(
        feat + (size_t)c0*64, 64, 64, nullptr, 0, we0T, 64, cbuf, 512, nullptr, 512, 64, rs40);
    gemm_mfma<128,unsigned short,false,true,false><<<dim3(4, CHD/128), blk, 0, stream>>>(
        cbuf, 512, 512, nullptr, 0, we1T, 512, xb + (size_t)c0*512, 512, cutb + c0, 512, 512, rs512);
    gemm_mfma<128,unsigned short,false,false,false><<<dim3(1, CHD/128), blk, 0, stream>>>(
        xb + (size_t)c0*512, 512, 512, nullptr, 0, winT, 512, cbuf, 128, nullptr, 128, 512, rs512);
    vbuild<<<(CHD*512)/256, blk, 0, stream>>>(cbuf, Yb + (size_t)c0*16, Vb + (size_t)c0*512, CHD);
  }

  for (int layer = 0; layer < 2; ++layer) {
    // w = x @ wenv, with 1/sqrt(AVG_NEIGH)=0.25 folded in
    gemm_mfma<64,float,false,false,false><<<dim3(1, E/128), blk, 0, stream>>>(
        xb, 512, 512, nullptr, 0, wenvT + (size_t)layer*32*512, 512, wbuf, 32, nullptr, 32, 512, rs512*0.25f);
    env_build<<<N, 512, 0, stream>>>(wbuf, Yb, elist, offs, nenv);
    if (layer == 0)
      tp_mix<<<E/8, blk, 0, stream>>>(nenv, senders, Vb,
          wmix + (size_t)layer*4*32*32, t0b, E);
    else
      tp_last<<<(E*32)/256, blk, 0, stream>>>(nenv, senders, Vb, t0b, E);
    for (int c0 = 0; c0 < E; c0 += CHD) {
      gemm_mfma<128,unsigned short,true,false,true><<<dim3(4, CHD/128), blk, 0, stream>>>(
          xb + (size_t)c0*512, 512, 512, t0b + (size_t)c0*32, 32,
          wl0T + (size_t)layer*512*544, 544, cbuf, 512, nullptr, 512, 544, rs544);
      gemm_mfma<128,unsigned short,false,true,false><<<dim3(4, CHD/128), blk, 0, stream>>>(
          cbuf, 512, 512, nullptr, 0, wl1T + (size_t)layer*512*512, 512,
          xb + (size_t)c0*512, 512, cutb + c0, 512, 512, rs512);
    }
  }

  out_kernel<<<E/4, blk, 0, stream>>>(xb, wout, out, E);
}

// Round 10
// 715.268 us; speedup vs baseline: 13.7835x; 1.1235x over previous
//
#include <hip/hip_runtime.h>
#include <math.h>
#include <type_traits>

typedef __attribute__((ext_vector_type(8))) short s8v;   // 8 bf16 (4 VGPR)
typedef __attribute__((ext_vector_type(4))) float f4v;   // MFMA acc
typedef __attribute__((ext_vector_type(2))) float f2v;   // packed f32 pair

#define CH 8192

// ---------------- bf16 bit helpers ----------------
__device__ inline float b2f(unsigned short u){ return __uint_as_float(((unsigned)u)<<16); }
__device__ inline unsigned short f2b(float f){
  unsigned u = __float_as_uint(f);
  return (unsigned short)((u + 0x7FFFu + ((u>>16)&1u)) >> 16);   // RNE
}
__device__ inline void stC(float* p, float v){ *p = v; }
__device__ inline void stC(unsigned short* p, float v){ *p = f2b(v); }

// async global->LDS, 16B per lane; lds base must be wave-uniform
__device__ __forceinline__ void gl16(const void* g, void* l){
  __builtin_amdgcn_global_load_lds(
      (const __attribute__((address_space(1))) unsigned*)g,
      (__attribute__((address_space(3))) unsigned*)l, 16, 0, 0);
}

// ================= compile-time real Wigner (CG) tables =================
constexpr double FCT[11] = {1.,1.,2.,6.,24.,120.,720.,5040.,40320.,362880.,3628800.};
constexpr double csqrt_c(double x){
  double g = x > 1.0 ? x : 1.0;
  for (int i=0;i<60;i++) g = 0.5*(g + x/g);
  return g;
}
struct CD { double re, im; };
constexpr CD cmulc(CD a, CD b){ return {a.re*b.re - a.im*b.im, a.re*b.im + a.im*b.re}; }

constexpr double su2cg_c(int j1,int j2,int j3,int m1,int m2,int m3){
  if (m1+m2 != m3) return 0.0;
  double pref = csqrt_c((double)(2*j3+1) * FCT[j1+j2-j3]*FCT[j1-j2+j3]*FCT[-j1+j2+j3]/FCT[j1+j2+j3+1]
              * FCT[j3+m3]*FCT[j3-m3]*FCT[j1-m1]*FCT[j1+m1]*FCT[j2-m2]*FCT[j2+m2]);
  int kmin = 0;
  if (j2-j3-m1 > kmin) kmin = j2-j3-m1;
  if (j1-j3+m2 > kmin) kmin = j1-j3+m2;
  int kmax = j1+j2-j3;
  if (j1-m1 < kmax) kmax = j1-m1;
  if (j2+m2 < kmax) kmax = j2+m2;
  double s = 0.0;
  for (int k=kmin;k<=kmax;k++){
    double t = 1.0/(FCT[k]*FCT[j1+j2-j3-k]*FCT[j1-m1-k]*FCT[j2+m2-k]*FCT[j3-j2+m1+k]*FCT[j3-j1-m2+k]);
    s += (k&1) ? -t : t;
  }
  return pref*s;
}

constexpr CD qelem_c(int l, int i, int j){
  int m = i - l;
  const double is2 = 0.70710678118654752440;
  double re=0.0, im=0.0;
  if (m < 0){
    if (j == l - m) re = is2;
    else if (j == l + m) im = -is2;
  } else if (m == 0){
    if (j == l) re = 1.0;
  } else {
    double sgn = (m & 1) ? -1.0 : 1.0;
    if (j == l + m) re = sgn*is2;
    else if (j == l - m) im = sgn*is2;
  }
  CD r{};
  switch (l & 3){                    // (-i)^l
    case 0: r = {re, im}; break;
    case 1: r = {im, -re}; break;
    case 2: r = {-re, -im}; break;
    default: r = {-im, re}; break;
  }
  return r;
}

// path-count normalization per l3: n = {4,9,11,10}
constexpr double TN3[4] = {0.5, 1.0/3.0, 0.30151134457776363, 0.31622776601683794};

template<int L1,int L2,int L3>
struct TriVals { float v[(2*L1+1)*(2*L2+1)*(2*L3+1)]; };

template<int L1,int L2,int L3>
constexpr TriVals<L1,L2,L3> make_tri(){
  constexpr int n1=2*L1+1, n2=2*L2+1, n3=2*L3+1;
  double cg[n1*n2*n3] = {};
  for (int a=0;a<n1;a++)
    for (int b=0;b<n2;b++)
      for (int c=0;c<n3;c++)
        cg[(a*n2+b)*n3+c] = su2cg_c(L1,L2,L3, a-L1, b-L2, c-L3);
  double cr[n1*n2*n3] = {};
  double ci[n1*n2*n3] = {};
  for (int i=0;i<n1;i++)
   for (int j=0;j<n2;j++)
    for (int k=0;k<n3;k++){
      double sre=0.0, sim=0.0;
      for (int a=0;a<n1;a++){
        CD q1 = qelem_c(L1,i,a);
        if (q1.re==0.0 && q1.im==0.0) continue;
        for (int b=0;b<n2;b++){
          CD q2 = qelem_c(L2,j,b);
          if (q2.re==0.0 && q2.im==0.0) continue;
          CD q12 = cmulc(q1,q2);
          for (int c=0;c<n3;c++){
            double g = cg[(a*n2+b)*n3+c];
            if (g == 0.0) continue;
            CD q3 = qelem_c(L3,k,c);
            CD q3c{q3.re, -q3.im};
            CD q = cmulc(q12,q3c);
            sre += q.re*g; sim += q.im*g;
          }
        }
      }
      cr[(i*n2+j)*n3+k]=sre; ci[(i*n2+j)*n3+k]=sim;
    }
  double nr=0.0, ni=0.0;
  for (int i=0;i<n1*n2*n3;i++){ nr += cr[i]*cr[i]; ni += ci[i]*ci[i]; }
  bool pr = nr >= ni;
  double nn = csqrt_c(pr ? nr : ni);
  TriVals<L1,L2,L3> t{};
  for (int i=0;i<n1*n2*n3;i++)
    t.v[i] = (float)(((pr ? cr[i] : ci[i]) / nn) * TN3[L3]);
  return t;
}

template<int L1,int L2,int L3>
constexpr TriVals<L1,L2,L3> W3V = make_tri<L1,L2,L3>();

constexpr int LOFFC[4] = {0,1,4,9};

// ---- FMA with inline 32-bit literal (VOP2 v_fmac_f32, src0=literal: free) ----
template<int WB>
__device__ __forceinline__ void fmac_lit(float& a, float p){
  asm("v_fmac_f32 %0, %2, %1" : "+v"(a) : "v"(p), "i"(WB));
}

// static-for
template<int I, int N, typename F>
__device__ __forceinline__ void sfor(F&& f){
  if constexpr (I < N){
    f(std::integral_constant<int,I>{});
    sfor<I+1,N>(static_cast<F&&>(f));
  }
}

// grouped TP: one (L1,L2) pair -> each product computed ONCE, all valid l3 emitted
template<int L1,int L2>
__device__ __forceinline__ void tp_pair(const float* __restrict__ env,
                                        const float* __restrict__ v,
                                        float* __restrict__ acc){
  sfor<0,2*L1+1>([&](auto K1c){
    constexpr int k1 = decltype(K1c)::value;
    sfor<0,2*L2+1>([&](auto K2c){
      constexpr int k2 = decltype(K2c)::value;
      float p = env[LOFFC[L1]+k1] * v[LOFFC[L2]+k2];
      sfor<0,4>([&](auto L3c){
        constexpr int l3 = decltype(L3c)::value;
        constexpr int lo = (L1>L2)?(L1-L2):(L2-L1);
        if constexpr (l3 >= lo && l3 <= L1+L2){
          sfor<0,2*l3+1>([&](auto K3c){
            constexpr int k3 = decltype(K3c)::value;
            constexpr float w = W3V<L1,L2,l3>.v[(k1*(2*L2+1)+k2)*(2*l3+1)+k3];
            if constexpr (w != 0.f){
              fmac_lit<__builtin_bit_cast(int, w)>(acc[LOFFC[l3]+k3], p);
            }
          });
        }
      });
    });
  });
}

// scalar per-triple variant (tp_last, l3=0 only: tiny)
template<int L1,int L2,int L3>
__device__ __forceinline__ void tp_tri(const float* __restrict__ env,
                                       const float* __restrict__ v,
                                       float* __restrict__ acc){
  constexpr int n1=2*L1+1, n2=2*L2+1, n3=2*L3+1;
  #pragma unroll
  for (int k1=0;k1<n1;k1++)
    #pragma unroll
    for (int k2=0;k2<n2;k2++){
      float p = env[LOFFC[L1]+k1] * v[LOFFC[L2]+k2];
      #pragma unroll
      for (int k3=0;k3<n3;k3++){
        float w = W3V<L1,L2,L3>.v[(k1*n2+k2)*n3+k3];
        if (w != 0.f) acc[LOFFC[L3]+k3] += w * p;
      }
    }
}

// ---------------- batched weight convert+transpose ----------------
struct WSeg { const float* W; unsigned short* WT; int K, N, Kpad, nblk; };
struct WDesc { WSeg s[9]; };
__global__ __launch_bounds__(256) void wconv_all(WDesc d){
  int b = blockIdx.x;
  int seg = 0;
  while (b >= d.s[seg].nblk){ b -= d.s[seg].nblk; ++seg; }
  const WSeg w = d.s[seg];
  int idx = b*256 + threadIdx.x;
  if (idx >= w.N*w.Kpad) return;
  int n = idx / w.Kpad, k = idx - n*w.Kpad;
  w.WT[idx] = (k < w.K) ? f2b(w.W[(size_t)k*w.N + n]) : (unsigned short)0;
}

// ---------------- edge geometry: feat64(bf16, zero-padded), Y, cut -------------
__global__ __launch_bounds__(256) void edge_init(
    const float* __restrict__ vec, const float* __restrict__ na,
    const int* __restrict__ snd, const int* __restrict__ rcv,
    unsigned short* __restrict__ feat, float* __restrict__ Y, float* __restrict__ cutb, int E)
{
  int e = blockIdx.x*256 + threadIdx.x;
  if (e >= E) return;
  float vx = vec[(size_t)e*3], vy = vec[(size_t)e*3+1], vz = vec[(size_t)e*3+2];
  float d = sqrtf(vx*vx + vy*vy + vz*vz);
  float inv = 1.f/(d + 1e-9f);
  float x = vx*inv, y = vy*inv, z = vz*inv;
  float dc = d * 0.4f;               // d / 2.5
  float dci = 1.f/(dc + 1e-9f);
  unsigned short* f = feat + (size_t)e*64;
  #pragma unroll
  for (int k=1;k<=8;k++)
    f[k-1] = f2b(1.41421356237309515f * sinf(dc * 3.14159265358979323846f * k) * dci);
  int s = snd[e], r = rcv[e];
  #pragma unroll
  for (int i=0;i<16;i++) f[8+i]  = f2b(na[(size_t)s*16+i]);
  #pragma unroll
  for (int i=0;i<16;i++) f[24+i] = f2b(na[(size_t)r*16+i]);
  #pragma unroll
  for (int i=40;i<64;i++) f[i] = 0;
  float cv = 0.f;
  if (dc < 1.f){
    float d2 = dc*dc; float d6 = d2*d2*d2; float d7 = d6*dc; float d8 = d7*dc;
    cv = 1.f - 28.f*d6 + 48.f*d7 - 21.f*d8;
  }
  cutb[e] = cv;
  float* Ye = Y + (size_t)e*16;
  const float s3=1.7320508075688772f, s5=2.2360679774997896f, s15=3.8729833462074170f;
  Ye[0] = 1.f;
  Ye[1] = s3*y; Ye[2] = s3*z; Ye[3] = s3*x;
  Ye[4] = s15*x*y; Ye[5] = s15*y*z; Ye[6] = 0.5f*s5*(3.f*z*z-1.f);
  Ye[7] = s15*x*z; Ye[8] = 0.5f*s15*(x*x - y*y);
  const float c1=2.0916500663351889f, c2=10.246950765959598f, c3=1.6201851746019649f, c4=1.3228756555322954f;
  Ye[9]  = c1*y*(3.f*x*x - y*y);
  Ye[10] = c2*x*y*z;
  Ye[11] = c3*y*(5.f*z*z - 1.f);
  Ye[12] = c4*z*(5.f*z*z - 3.f);
  Ye[13] = c3*x*(5.f*z*z - 1.f);
  Ye[14] = 0.5f*c2*z*(x*x - y*y);
  Ye[15] = c1*x*(x*x - 3.f*y*y);
}

// ---------------- MFMA bf16 GEMM with global_load_lds staging ------------------
template<int NT, typename TC, bool SILU, bool CUT, bool HASA2>
__global__ __launch_bounds__(256) void gemm_mfma(
    const unsigned short* __restrict__ A, int lda, int K1,
    const float* __restrict__ A2, int lda2,
    const unsigned short* __restrict__ WT, int ldw,
    TC* __restrict__ C, int ldc,
    const float* __restrict__ cutv,
    int N, int K, float scale)
{
  constexpr int NB = NT/16;
  __shared__ s8v As8[128*8];
  __shared__ s8v Bs8[NT*8];
  const int tid = threadIdx.x;
  const int wid = tid >> 6, lane = tid & 63;
  const int r15 = lane & 15, kg = lane >> 4;
  const int col0 = blockIdx.x * NT;
  const int row0 = blockIdx.y * 128;
  f4v acc[2][NB] = {};

  auto compute = [&](){
    #pragma unroll
    for (int s = 0; s < 2; s++) {
      const int cb = s*4 + kg;
      const int cx = cb ^ (r15 & 7);
      s8v a0 = As8[(wid*32      + r15)*8 + cx];
      s8v a1 = As8[(wid*32 + 16 + r15)*8 + cx];
      #pragma unroll
      for (int j = 0; j < NB; j++) {
        s8v b = Bs8[(j*16 + r15)*8 + cx];
        acc[0][j] = __builtin_amdgcn_mfma_f32_16x16x32_bf16(a0, b, acc[0][j], 0,0,0);
        acc[1][j] = __builtin_amdgcn_mfma_f32_16x16x32_bf16(a1, b, acc[1][j], 0,0,0);
      }
    }
  };

  const int Kfull = HASA2 ? K1 : K;     // K1 is a multiple of 64 when HASA2
  for (int k0 = 0; k0 < Kfull; k0 += 64) {
    #pragma unroll
    for (int i = 0; i < 4; i++) {       // A tile: 1024 segs of 16B
      int seg = i*256 + tid;
      int r = seg >> 3, ks = seg & 7;
      int ksx = ks ^ (r & 7);
      gl16(A + (size_t)(row0+r)*lda + k0 + ksx*8, &As8[i*256 + (tid & ~63)]);
    }
    #pragma unroll
    for (int i = 0; i < NT/32; i++) {   // B tile: NT*8 segs
      int seg = i*256 + tid;
      int n = seg >> 3, ks = seg & 7;
      int ksx = ks ^ (n & 7);
      gl16(WT + (size_t)(col0+n)*ldw + k0 + ksx*8, &Bs8[i*256 + (tid & ~63)]);
    }
    __syncthreads();
    compute();
    __syncthreads();
  }
  if (HASA2 && Kfull < K) {             // fp32 concat tail (one K-step)
    #pragma unroll
    for (int i = 0; i < 4; i++) {       // A tail: VGPR-staged, swizzled slot
      int seg = i*256 + tid;
      int r = seg >> 3, ks = seg & 7;
      int cl = ks ^ (r & 7);            // logical col block
      s8v val = {};
      #pragma unroll
      for (int j = 0; j < 8; j++) {
        int kk = cl*8 + j;              // col within tail
        if (K1 + kk < K) val[j] = (short)f2b(A2[(size_t)(row0+r)*lda2 + kk]);
      }
      As8[seg] = val;
    }
    #pragma unroll
    for (int i = 0; i < NT/32; i++) {   // B tail async (overrun reads benign)
      int seg = i*256 + tid;
      int n = seg >> 3, ks = seg & 7;
      int ksx = ks ^ (n & 7);
      gl16(WT + (size_t)(col0+n)*ldw + K1 + ksx*8, &Bs8[i*256 + (tid & ~63)]);
    }
    __syncthreads();
    compute();
  }
  // epilogue: C/D layout col = lane&15, row = (lane>>4)*4 + j
  #pragma unroll
  for (int g=0; g<2; g++) {
    #pragma unroll
    for (int c=0; c<NB; c++) {
      int col = col0 + c*16 + r15;
      if (col >= N) continue;
      #pragma unroll
      for (int j=0;j<4;j++) {
        int row = row0 + wid*32 + g*16 + kg*4 + j;
        float v = acc[g][c][j] * scale;
        if (SILU) v = v / (1.f + __expf(-v));
        if (CUT)  v *= cutv[row];
        stC(&C[(size_t)row*ldc + col], v);
      }
    }
  }
}

// ---------------- V init (vectorized): thread per (e,m) ------------------------
__global__ __launch_bounds__(256) void vbuild(
    const unsigned short* __restrict__ wi, const float* __restrict__ Y,
    unsigned short* __restrict__ V, int count)
{
  int t = blockIdx.x*256 + threadIdx.x;
  if (t >= count*32) return;
  int e = t >> 5, m = t & 31;
  const unsigned short* wr = wi + (size_t)e*128 + m;
  float ws[4] = { b2f(wr[0]), b2f(wr[32]), b2f(wr[64]), b2f(wr[96]) };
  const float4* Y4 = (const float4*)(Y + (size_t)e*16);
  float yv[16];
  #pragma unroll
  for (int q=0;q<4;q++){ float4 f=Y4[q]; yv[q*4]=f.x; yv[q*4+1]=f.y; yv[q*4+2]=f.z; yv[q*4+3]=f.w; }
  constexpr int LOFK[16] = {0,1,1,1,2,2,2,2,2,3,3,3,3,3,3,3};
  s8v o0, o1;
  #pragma unroll
  for (int k=0;k<8;k++)  o0[k] = (short)f2b(ws[LOFK[k]]   * yv[k]);
  #pragma unroll
  for (int k=0;k<8;k++)  o1[k] = (short)f2b(ws[LOFK[8+k]] * yv[8+k]);
  s8v* vo = (s8v*)(V + (size_t)e*512 + (size_t)m*16);
  vo[0] = o0; vo[1] = o1;
}

// ---------------- CSR build: histogram -> scan -> fill -------------------------
__global__ __launch_bounds__(256) void hist_k(
    const int* __restrict__ rcv, int* __restrict__ deg, int E)
{
  int e = blockIdx.x*256 + threadIdx.x;
  if (e < E) atomicAdd(&deg[rcv[e]], 1);
}

__global__ __launch_bounds__(256) void scan_k(
    const int* __restrict__ deg, int* __restrict__ offs, int Nn)
{
  __shared__ int part[256];
  const int t = threadIdx.x;
  const int per = (Nn + 255) / 256;
  int base = t*per;
  int loc[32];
  int s = 0;
  for (int i=0;i<per;i++){ int v = (base+i<Nn)?deg[base+i]:0; loc[i]=s; s+=v; }
  part[t] = s;
  __syncthreads();
  for (int off=1; off<256; off<<=1){
    int v = (t>=off) ? part[t-off] : 0;
    __syncthreads();
    part[t] += v;
    __syncthreads();
  }
  int pre = (t==0) ? 0 : part[t-1];
  for (int i=0;i<per;i++) if (base+i<Nn) offs[base+i] = pre + loc[i];
  if (t==255) offs[Nn] = part[255];
}

__global__ __launch_bounds__(256) void fill_k(
    const int* __restrict__ rcv, int* __restrict__ cursor,
    const int* __restrict__ offs, int* __restrict__ elist, int E)
{
  int e = blockIdx.x*256 + threadIdx.x;
  if (e >= E) return;
  int r = rcv[e];
  int p = atomicAdd(&cursor[r], 1);
  elist[offs[r] + p] = e;
}

// ---------------- env build ----------------
__global__ __launch_bounds__(512) void env_build(
    const float* __restrict__ w, const float* __restrict__ Y,
    const int* __restrict__ elist, const int* __restrict__ offs,
    float* __restrict__ nenv)
{
  const int n = blockIdx.x;
  const int j = threadIdx.x;          // 0..511
  const int m = j >> 4, kk = j & 15;
  const int beg = offs[n], end = offs[n+1];
  float acc = 0.f;
  for (int p = beg; p < end; ++p) {
    int e = elist[p];
    acc += w[(size_t)e*32 + m] * Y[(size_t)e*16 + kk];
  }
  nenv[(size_t)n*512 + j] = acc;
}

// ------------ fused tensor product + V-mix (layer 0; literal-fmac TP) ----------
__global__ __launch_bounds__(256, 2) void tp_mix(
    const float* __restrict__ nenv, const int* __restrict__ senders,
    unsigned short* __restrict__ V,
    const float* __restrict__ wm,     // layer slice: [4][32][32]
    float* __restrict__ t0, int E)
{
  __shared__ float Ts[8][32][18];     // pitch 18: f2v-aligned rows, 2-way bank (free)
  const int tid = threadIdx.x;
  const int le = tid >> 5, m = tid & 31;
  const int e = blockIdx.x*8 + le;
  const int s = senders[e];
  float env[16], v[16], acc[16];
  const float4* ne4 = (const float4*)(nenv + (size_t)s*512 + (size_t)m*16);
  #pragma unroll
  for (int q=0;q<4;q++){
    float4 f = ne4[q];
    env[q*4]=f.x; env[q*4+1]=f.y; env[q*4+2]=f.z; env[q*4+3]=f.w;
  }
  const s8v* vv = (const s8v*)(V + (size_t)e*512 + (size_t)m*16);
  s8v v0 = vv[0], v1 = vv[1];
  #pragma unroll
  for (int q=0;q<8;q++){ v[q] = b2f((unsigned short)v0[q]); v[8+q] = b2f((unsigned short)v1[q]); }
  #pragma unroll
  for (int k=0;k<16;k++) acc[k] = 0.f;

  // 16 (L1,L2) pair groups cover all 34 triples; products computed once each
  tp_pair<0,0>(env,v,acc); tp_pair<0,1>(env,v,acc); tp_pair<0,2>(env,v,acc); tp_pair<0,3>(env,v,acc);
  tp_pair<1,0>(env,v,acc); tp_pair<1,1>(env,v,acc); tp_pair<1,2>(env,v,acc); tp_pair<1,3>(env,v,acc);
  tp_pair<2,0>(env,v,acc); tp_pair<2,1>(env,v,acc); tp_pair<2,2>(env,v,acc); tp_pair<2,3>(env,v,acc);
  tp_pair<3,0>(env,v,acc); tp_pair<3,1>(env,v,acc); tp_pair<3,2>(env,v,acc); tp_pair<3,3>(env,v,acc);

  t0[(size_t)e*32 + m] = acc[0];      // TN3 folded into W3V

  #pragma unroll
  for (int k=0;k<16;k++) Ts[le][m][k] = acc[k];
  __syncthreads();
  f2v o2[8];
  #pragma unroll
  for (int kp=0;kp<8;kp++){ o2[kp][0]=0.f; o2[kp][1]=0.f; }
  #pragma unroll
  for (int mm=0; mm<32; mm++) {
    float w0 = wm[        mm*32 + m];
    float w1 = wm[1024 +  mm*32 + m];
    float w2 = wm[2048 +  mm*32 + m];
    float w3 = wm[3072 +  mm*32 + m];
    const f2v* tr = (const f2v*)Ts[le][mm];
    f2v p01; p01[0]=w0; p01[1]=w1;
    f2v p11; p11[0]=w1; p11[1]=w1;
    f2v p22; p22[0]=w2; p22[1]=w2;
    f2v p23; p23[0]=w2; p23[1]=w3;
    f2v p33; p33[0]=w3; p33[1]=w3;
    o2[0] += tr[0]*p01; o2[1] += tr[1]*p11; o2[2] += tr[2]*p22; o2[3] += tr[3]*p22;
    o2[4] += tr[4]*p23; o2[5] += tr[5]*p33; o2[6] += tr[6]*p33; o2[7] += tr[7]*p33;
  }
  s8v oa, ob;
  #pragma unroll
  for (int kp=0;kp<4;kp++){
    oa[2*kp]   = (short)f2b(o2[kp][0]   * 0.17677669529663689f); // 1/sqrt(32)
    oa[2*kp+1] = (short)f2b(o2[kp][1]   * 0.17677669529663689f);
    ob[2*kp]   = (short)f2b(o2[4+kp][0] * 0.17677669529663689f);
    ob[2*kp+1] = (short)f2b(o2[4+kp][1] * 0.17677669529663689f);
  }
  s8v* vo = (s8v*)(V + (size_t)e*512 + (size_t)m*16);
  vo[0] = oa; vo[1] = ob;
}

// ------------ last-layer TP: only l3=0 survives (feeds the latent concat) -------
__global__ __launch_bounds__(256) void tp_last(
    const float* __restrict__ nenv, const int* __restrict__ senders,
    const unsigned short* __restrict__ V, float* __restrict__ t0, int E)
{
  int t = blockIdx.x*256 + threadIdx.x;
  int e = t >> 5, m = t & 31;
  if (e >= E) return;
  int s = senders[e];
  float env[16], v[16], acc[16];
  const float4* ne4 = (const float4*)(nenv + (size_t)s*512 + (size_t)m*16);
  #pragma unroll
  for (int q=0;q<4;q++){
    float4 f = ne4[q];
    env[q*4]=f.x; env[q*4+1]=f.y; env[q*4+2]=f.z; env[q*4+3]=f.w;
  }
  const s8v* vv = (const s8v*)(V + (size_t)e*512 + (size_t)m*16);
  s8v v0 = vv[0], v1 = vv[1];
  #pragma unroll
  for (int q=0;q<8;q++){ v[q] = b2f((unsigned short)v0[q]); v[8+q] = b2f((unsigned short)v1[q]); }
  #pragma unroll
  for (int k=0;k<16;k++) acc[k] = 0.f;
  tp_tri<0,0,0>(env,v,acc); tp_tri<1,1,0>(env,v,acc);
  tp_tri<2,2,0>(env,v,acc); tp_tri<3,3,0>(env,v,acc);
  t0[(size_t)e*32 + m] = acc[0];
}

// ---------------- output: out[e] = (1/sqrt(512)) * dot(x[e], wout) --------------
__global__ __launch_bounds__(256) void out_kernel(
    const unsigned short* __restrict__ x, const float* __restrict__ wout,
    float* __restrict__ out, int E)
{
  int gw = (blockIdx.x*256 + threadIdx.x) >> 6;
  int lane = threadIdx.x & 63;
  if (gw >= E) return;
  const s8v* xr = (const s8v*)(x + (size_t)gw*512);
  s8v chunk = xr[lane];
  float s = 0.f;
  #pragma unroll
  for (int j=0;j<8;j++) s += b2f((unsigned short)chunk[j]) * wout[lane*8 + j];
  #pragma unroll
  for (int off=32; off; off>>=1) s += __shfl_down(s, off);
  if (lane == 0) out[gw] = s * 0.044194173824159216f; // 1/sqrt(512)
}

// ---------------- workspace sizing ----------------
static inline size_t alup(size_t b){ return (b + 255) & ~(size_t)255; }
static size_t need_bytes(int E, int N, int chd){
  size_t s = 0;
  s += alup((size_t)E*16*4);            // Yb
  s += alup((size_t)E*4);               // cutb
  s += alup((size_t)E*32*4);            // wbuf
  s += alup((size_t)E*32*4);            // t0b
  s += alup((size_t)N*512*4);           // nenv
  s += alup((size_t)E*64*2);            // feat
  s += alup((size_t)chd*512*2);         // cbuf
  s += alup((size_t)E*512*2);           // Vb
  s += alup((size_t)E*512*2);           // xb
  s += alup((size_t)512*64*2);          // we0T
  s += alup((size_t)512*512*2);         // we1T
  s += alup((size_t)128*512*2);         // winitT
  s += alup((size_t)2*32*512*2);        // wenvT
  s += alup((size_t)2*512*544*2);       // wlat0T
  s += alup((size_t)2*512*512*2);       // wlat1T
  s += alup((size_t)N*4);               // deg
  s += alup(((size_t)N+1)*4);           // offs
  s += alup((size_t)N*4);               // cursor
  s += alup((size_t)E*4);               // elist
  return s;
}

// ---------------- launch ----------------
extern "C" void kernel_launch(void* const* d_in, const int* in_sizes, int n_in,
                              void* d_out, int out_size, void* d_ws, size_t ws_size,
                              hipStream_t stream)
{
  const float* node_attrs = (const float*)d_in[0];
  const float* vectors    = (const float*)d_in[1];
  const float* we0        = (const float*)d_in[2];
  const float* we1        = (const float*)d_in[3];
  const float* winit      = (const float*)d_in[4];
  const float* wenv       = (const float*)d_in[5];
  const float* wlat0      = (const float*)d_in[6];
  const float* wlat1      = (const float*)d_in[7];
  const float* wmix       = (const float*)d_in[8];
  const float* wout       = (const float*)d_in[9];
  const int*   senders    = (const int*)d_in[10];
  const int*   receivers  = (const int*)d_in[11];
  float* out = (float*)d_out;
  const int E = in_sizes[1] / 3;
  const int N = in_sizes[0] / 16;

  // chunk tier: largest transient that fits (fewest dispatches)
  int CHD = -1;
  const int tiers[4] = {E, E/2, E/4, CH};
  for (int i=0;i<4;i++){
    if (tiers[i] >= CH && need_bytes(E, N, tiers[i]) <= ws_size){ CHD = tiers[i]; break; }
  }
  if (CHD < 0) return;                  // diagnostic clean fail

  char* base = (char*)d_ws;
  size_t off = 0;
  auto carve = [&](size_t b) -> char* { char* p = base + off; off += alup(b); return p; };
  float*          Yb    = (float*)carve((size_t)E*16*4);
  float*          cutb  = (float*)carve((size_t)E*4);
  float*          wbuf  = (float*)carve((size_t)E*32*4);
  float*          t0b   = (float*)carve((size_t)E*32*4);
  float*          nenv  = (float*)carve((size_t)N*512*4);
  unsigned short* feat  = (unsigned short*)carve((size_t)E*64*2);
  unsigned short* cbuf  = (unsigned short*)carve((size_t)CHD*512*2);
  unsigned short* Vb    = (unsigned short*)carve((size_t)E*512*2);
  unsigned short* xb    = (unsigned short*)carve((size_t)E*512*2);
  unsigned short* we0T  = (unsigned short*)carve((size_t)512*64*2);
  unsigned short* we1T  = (unsigned short*)carve((size_t)512*512*2);
  unsigned short* winT  = (unsigned short*)carve((size_t)128*512*2);
  unsigned short* wenvT = (unsigned short*)carve((size_t)2*32*512*2);
  unsigned short* wl0T  = (unsigned short*)carve((size_t)2*512*544*2);
  unsigned short* wl1T  = (unsigned short*)carve((size_t)2*512*512*2);
  int*            deg   = (int*)carve((size_t)N*4);
  int*            offs  = (int*)carve(((size_t)N+1)*4);
  int*            cursor= (int*)carve((size_t)N*4);
  int*            elist = (int*)carve((size_t)E*4);

  const float rs40  = 0.15811388300841897f;  // 1/sqrt(40)
  const float rs512 = 0.044194173824159216f; // 1/sqrt(512)
  const float rs544 = 0.042874646285627205f; // 1/sqrt(544)

  dim3 blk(256);
  // batched weight conversion (9 segments, one dispatch)
  WDesc wd;
  auto seg = [&](int i, const float* W, unsigned short* WT, int K, int Nn, int Kpad){
    wd.s[i] = { W, WT, K, Nn, Kpad, (Nn*Kpad + 255)/256 };
  };
  seg(0, we0,  we0T, 40, 512, 64);
  seg(1, we1,  we1T, 512, 512, 512);
  seg(2, winit, winT, 512, 128, 512);
  seg(3, wenv,                wenvT,            512, 32, 512);
  seg(4, wenv + (size_t)512*32, wenvT + (size_t)32*512, 512, 32, 512);
  seg(5, wlat0,                 wl0T,                 544, 512, 544);
  seg(6, wlat0 + (size_t)544*512, wl0T + (size_t)512*544, 544, 512, 544);
  seg(7, wlat1,                 wl1T,                 512, 512, 512);
  seg(8, wlat1 + (size_t)512*512, wl1T + (size_t)512*512, 512, 512, 512);
  int totblk = 0;
  for (int i=0;i<9;i++) totblk += wd.s[i].nblk;
  wconv_all<<<totblk, blk, 0, stream>>>(wd);

  edge_init<<<E/256, blk, 0, stream>>>(vectors, node_attrs, senders, receivers, feat, Yb, cutb, E);

  // CSR of receivers (layer-invariant: build once)
  hipMemsetAsync(deg, 0, (size_t)N*4, stream);
  hipMemsetAsync(cursor, 0, (size_t)N*4, stream);
  hist_k<<<(E+255)/256, blk, 0, stream>>>(receivers, deg, E);
  scan_k<<<1, blk, 0, stream>>>(deg, offs, N);
  fill_k<<<(E+255)/256, blk, 0, stream>>>(receivers, cursor, offs, elist, E);

  // edge embedding MLP + V init
  for (int c0 = 0; c0 < E; c0 += CHD) {
    gemm_mfma<128,unsigned short,true,false,false><<<dim3(4, CHD/128), blk, 0, stream>>>(
        feat + (size_t)c0*64, 64, 64, nullptr, 0, we0T, 64, cbuf, 512, nullptr, 512, 64, rs40);
    gemm_mfma<128,unsigned short,false,true,false><<<dim3(4, CHD/128), blk, 0, stream>>>(
        cbuf, 512, 512, nullptr, 0, we1T, 512, xb + (size_t)c0*512, 512, cutb + c0, 512, 512, rs512);
    gemm_mfma<128,unsigned short,false,false,false><<<dim3(1, CHD/128), blk, 0, stream>>>(
        xb + (size_t)c0*512, 512, 512, nullptr, 0, winT, 512, cbuf, 128, nullptr, 128, 512, rs512);
    vbuild<<<(CHD*32)/256, blk, 0, stream>>>(cbuf, Yb + (size_t)c0*16, Vb + (size_t)c0*512, CHD);
  }

  for (int layer = 0; layer < 2; ++layer) {
    // w = x @ wenv, with 1/sqrt(AVG_NEIGH)=0.25 folded in
    gemm_mfma<64,float,false,false,false><<<dim3(1, E/128), blk, 0, stream>>>(
        xb, 512, 512, nullptr, 0, wenvT + (size_t)layer*32*512, 512, wbuf, 32, nullptr, 32, 512, rs512*0.25f);
    env_build<<<N, 512, 0, stream>>>(wbuf, Yb, elist, offs, nenv);
    if (layer == 0)
      tp_mix<<<E/8, blk, 0, stream>>>(nenv, senders, Vb,
          wmix + (size_t)layer*4*32*32, t0b, E);
    else
      tp_last<<<(E*32)/256, blk, 0, stream>>>(nenv, senders, Vb, t0b, E);
    for (int c0 = 0; c0 < E; c0 += CHD) {
      gemm_mfma<128,unsigned short,true,false,true><<<dim3(4, CHD/128), blk, 0, stream>>>(
          xb + (size_t)c0*512, 512, 512, t0b + (size_t)c0*32, 32,
          wl0T + (size_t)layer*512*544, 544, cbuf, 512, nullptr, 512, 544, rs544);
      gemm_mfma<128,unsigned short,false,true,false><<<dim3(4, CHD/128), blk, 0, stream>>>(
          cbuf, 512, 512, nullptr, 0, wl1T + (size_t)layer*512*512, 512,
          xb + (size_t)c0*512, 512, cutb + c0, 512, 512, rs512);
    }
  }

  out_kernel<<<E/4, blk, 0, stream>>>(xb, wout, out, E);
}